// Round 2
// baseline (17715.094 us; speedup 1.0000x reference)
//
#include <hip/hip_runtime.h>

#define N_NODES 50000
#define N_EDGES 800000

#define HC_LD 132   // 64x128 h_cat tile, padded
#define HE_LD 68    // 64x64 h_e tile, padded
#define RBF_LD 52   // 64x50 rbf tile, padded

__device__ __forceinline__ float silu_f(float v) {
  return v / (1.0f + __expf(-v));
}
__device__ __forceinline__ unsigned short f2bf(float f) {
  union { float f; unsigned u; } a; a.f = f;
  unsigned r = a.u + 0x7fffu + ((a.u >> 16) & 1u);
  return (unsigned short)(r >> 16);
}
__device__ __forceinline__ float bf2f(unsigned short s) {
  union { unsigned u; float f; } a; a.u = ((unsigned)s) << 16;
  return a.f;
}

// ---------------- CSR build ----------------
__global__ void hist_kernel(const int* __restrict__ dst, int* __restrict__ deg) {
  int i = blockIdx.x * 256 + threadIdx.x;
  if (i < N_EDGES) atomicAdd(&deg[dst[i]], 1);
}

__global__ __launch_bounds__(1024) void scan_kernel(const int* __restrict__ deg,
                                                    int* __restrict__ off, int n) {
  __shared__ int wsum[16];
  __shared__ int s_carry;
  int t = threadIdx.x;
  int lane = t & 63, w = t >> 6;
  if (t == 0) { s_carry = 0; off[0] = 0; }
  __syncthreads();
  for (int base = 0; base < n; base += 1024) {
    int i = base + t;
    int v = (i < n) ? deg[i] : 0;
    int sv = v;
    #pragma unroll
    for (int o = 1; o < 64; o <<= 1) {
      int u = __shfl_up(sv, o, 64);
      if (lane >= o) sv += u;
    }
    if (lane == 63) wsum[w] = sv;
    __syncthreads();
    if (w == 0 && lane < 16) {
      int ws_ = wsum[lane];
      #pragma unroll
      for (int o = 1; o < 16; o <<= 1) {
        int u = __shfl_up(ws_, o, 64);
        if (lane >= o) ws_ += u;
      }
      wsum[lane] = ws_;
    }
    __syncthreads();
    int carry = s_carry;
    int prefix = (w > 0) ? wsum[w - 1] : 0;
    if (i < n) off[i + 1] = sv + prefix + carry;
    __syncthreads();
    if (t == 1023) s_carry = carry + wsum[15];
    __syncthreads();
  }
}

__global__ void scatter_kernel(const int* __restrict__ dst, const int* __restrict__ off,
                               int* __restrict__ cur, int* __restrict__ eperm) {
  int i = blockIdx.x * 256 + threadIdx.x;
  if (i < N_EDGES) {
    int dn = dst[i];
    int pos = atomicAdd(&cur[dn], 1);
    eperm[off[dn] + pos] = i;
  }
}

// ---------------- big per-edge kernel: 64 edges / block ----------------
__global__ __launch_bounds__(256) void edge_kernel(
    const float* __restrict__ h, const float* __restrict__ x,
    const int* __restrict__ src, const int* __restrict__ dst,
    const int* __restrict__ eperm,
    const float* __restrict__ W_cf_in, const float* __restrict__ b_cf_in,
    const float* __restrict__ W_cf_f, const float* __restrict__ b_cf_f,
    const float* __restrict__ W_sem,
    const float* __restrict__ W_ew, const float* __restrict__ b_ew,
    const float* __restrict__ W_c1, const float* __restrict__ b_c1,
    const float* __restrict__ W_c2, const float* __restrict__ b_c2,
    float* __restrict__ d_arr, float* __restrict__ xmx_arr,
    float* __restrict__ sl_arr, float* __restrict__ coef_arr,
    unsigned short* __restrict__ he_g, unsigned short* __restrict__ how_g)
{
  __shared__ float hcat[64][HC_LD];
  __shared__ float he_s[64][HE_LD];
  __shared__ float rbf_s[64][RBF_LD];
  __shared__ int s_src[64];
  __shared__ int s_dst[64];

  const int t = threadIdx.x;
  const int p0 = blockIdx.x * 64;

  if (t < 64) {
    int e = eperm[p0 + t];
    s_src[t] = src[e];
    s_dst[t] = dst[e];
  }
  __syncthreads();

  // stage h_cat[64][128] (src cols 0..63, dst cols 64..127)
  #pragma unroll
  for (int i = 0; i < 8; ++i) {
    int f4 = t + 256 * i;       // 0..2047 float4 slots
    int le = f4 >> 5;
    int k  = (f4 & 31) * 4;
    int node = (k < 64) ? s_src[le] : s_dst[le];
    int col  = (k < 64) ? k : (k - 64);
    float4 v = *reinterpret_cast<const float4*>(&h[(size_t)node * 64 + col]);
    *reinterpret_cast<float4*>(&hcat[le][k]) = v;
  }

  // per-edge geometry + RBF
  if (t < 64) {
    int p = p0 + t;
    int s = s_src[t], dn = s_dst[t];
    float mx0 = x[s * 3 + 0] - x[dn * 3 + 0];
    float mx1 = x[s * 3 + 1] - x[dn * 3 + 1];
    float mx2 = x[s * 3 + 2] - x[dn * 3 + 2];
    float d2 = mx0 * mx0 + mx1 * mx1 + mx2 * mx2 + 1e-5f;
    float d = sqrtf(d2);
    d_arr[p] = d;
    xmx_arr[p * 3 + 0] = mx0;
    xmx_arr[p * 3 + 1] = mx1;
    xmx_arr[p * 3 + 2] = mx2;
    #pragma unroll
    for (int k = 0; k < 50; ++k) {
      float mu = (float)k * (5.0f / 49.0f);
      float dd = d - mu;
      rbf_s[t][k] = __expf(-10.0f * dd * dd);
    }
  }
  __syncthreads();

  // sem logits: sl = silu(h_cat @ W_sem), wave-reduce per edge
  {
    int c = t & 63, g = t >> 6;
    for (int le = g; le < 64; le += 4) {
      float2 hv = *reinterpret_cast<const float2*>(&hcat[le][2 * c]);
      float v = hv.x * W_sem[2 * c] + hv.y * W_sem[2 * c + 1];
      #pragma unroll
      for (int o_ = 32; o_ > 0; o_ >>= 1) v += __shfl_xor(v, o_, 64);
      if (c == 0) sl_arr[p0 + le] = silu_f(v);
    }
  }

  // phase 1: h_e = (h_cat@W_cf_in + b) * silu(rbf@W_cf_f + b); 4x4 register block
  {
    const int c4 = t & 15, le4 = t >> 4;
    const int cb = c4 * 4, lb = le4 * 4;
    float acc[4][4], facc[4][4];
    #pragma unroll
    for (int j = 0; j < 4; ++j) {
      float bi = b_cf_in[cb + j], bf = b_cf_f[cb + j];
      #pragma unroll
      for (int i = 0; i < 4; ++i) { acc[i][j] = bi; facc[i][j] = bf; }
    }
    for (int k = 0; k < 128; k += 4) {
      float a[4][4];
      #pragma unroll
      for (int i = 0; i < 4; ++i) {
        float4 v = *reinterpret_cast<const float4*>(&hcat[lb + i][k]);
        a[i][0] = v.x; a[i][1] = v.y; a[i][2] = v.z; a[i][3] = v.w;
      }
      #pragma unroll
      for (int kk = 0; kk < 4; ++kk) {
        float4 w = *reinterpret_cast<const float4*>(&W_cf_in[(k + kk) * 64 + cb]);
        #pragma unroll
        for (int i = 0; i < 4; ++i) {
          acc[i][0] += a[i][kk] * w.x;
          acc[i][1] += a[i][kk] * w.y;
          acc[i][2] += a[i][kk] * w.z;
          acc[i][3] += a[i][kk] * w.w;
        }
      }
    }
    for (int k = 0; k < 50; ++k) {
      float4 w = *reinterpret_cast<const float4*>(&W_cf_f[k * 64 + cb]);
      #pragma unroll
      for (int i = 0; i < 4; ++i) {
        float r = rbf_s[lb + i][k];
        facc[i][0] += r * w.x;
        facc[i][1] += r * w.y;
        facc[i][2] += r * w.z;
        facc[i][3] += r * w.w;
      }
    }
    #pragma unroll
    for (int i = 0; i < 4; ++i) {
      int le = lb + i, p = p0 + le;
      float h0 = acc[i][0] * silu_f(facc[i][0]);
      float h1 = acc[i][1] * silu_f(facc[i][1]);
      float h2 = acc[i][2] * silu_f(facc[i][2]);
      float h3 = acc[i][3] * silu_f(facc[i][3]);
      *reinterpret_cast<float4*>(&he_s[le][cb]) = make_float4(h0, h1, h2, h3);
      ushort4 u;
      u.x = f2bf(h0); u.y = f2bf(h1); u.z = f2bf(h2); u.w = f2bf(h3);
      *reinterpret_cast<ushort4*>(&he_g[(size_t)p * 64 + cb]) = u;
    }
  }
  __syncthreads();

  // phase 2a: how = tanh([h_cat, h_e] @ W_ew + b); 2x4 register block
  {
    const int c8 = t & 7, le2 = t >> 3;
    const int cb = c8 * 4, lb = le2 * 2;
    float acc[2][4];
    #pragma unroll
    for (int j = 0; j < 4; ++j) { float b = b_ew[cb + j]; acc[0][j] = b; acc[1][j] = b; }
    for (int k = 0; k < 128; k += 4) {
      float a[2][4];
      #pragma unroll
      for (int i = 0; i < 2; ++i) {
        float4 v = *reinterpret_cast<const float4*>(&hcat[lb + i][k]);
        a[i][0] = v.x; a[i][1] = v.y; a[i][2] = v.z; a[i][3] = v.w;
      }
      #pragma unroll
      for (int kk = 0; kk < 4; ++kk) {
        float4 w = *reinterpret_cast<const float4*>(&W_ew[(k + kk) * 32 + cb]);
        #pragma unroll
        for (int i = 0; i < 2; ++i) {
          acc[i][0] += a[i][kk] * w.x;
          acc[i][1] += a[i][kk] * w.y;
          acc[i][2] += a[i][kk] * w.z;
          acc[i][3] += a[i][kk] * w.w;
        }
      }
    }
    for (int k = 0; k < 64; k += 4) {
      float a[2][4];
      #pragma unroll
      for (int i = 0; i < 2; ++i) {
        float4 v = *reinterpret_cast<const float4*>(&he_s[lb + i][k]);
        a[i][0] = v.x; a[i][1] = v.y; a[i][2] = v.z; a[i][3] = v.w;
      }
      #pragma unroll
      for (int kk = 0; kk < 4; ++kk) {
        float4 w = *reinterpret_cast<const float4*>(&W_ew[(128 + k + kk) * 32 + cb]);
        #pragma unroll
        for (int i = 0; i < 2; ++i) {
          acc[i][0] += a[i][kk] * w.x;
          acc[i][1] += a[i][kk] * w.y;
          acc[i][2] += a[i][kk] * w.z;
          acc[i][3] += a[i][kk] * w.w;
        }
      }
    }
    #pragma unroll
    for (int i = 0; i < 2; ++i) {
      int p = p0 + lb + i;
      ushort4 u;
      u.x = f2bf(tanhf(acc[i][0]));
      u.y = f2bf(tanhf(acc[i][1]));
      u.z = f2bf(tanhf(acc[i][2]));
      u.w = f2bf(tanhf(acc[i][3]));
      *reinterpret_cast<ushort4*>(&how_g[(size_t)p * 32 + cb]) = u;
    }
  }

  // phase 2b: coef = silu(h_e@W_c1 + b)@W_c2 + b; wave-reduce per edge
  {
    const int c = t & 63, g = t >> 6;
    for (int le = g; le < 64; le += 4) {
      float v = b_c1[c];
      for (int k = 0; k < 64; k += 4) {
        float4 a = *reinterpret_cast<const float4*>(&he_s[le][k]);
        v += a.x * W_c1[(k + 0) * 64 + c];
        v += a.y * W_c1[(k + 1) * 64 + c];
        v += a.z * W_c1[(k + 2) * 64 + c];
        v += a.w * W_c1[(k + 3) * 64 + c];
      }
      float r = silu_f(v) * W_c2[c];
      #pragma unroll
      for (int o_ = 32; o_ > 0; o_ >>= 1) r += __shfl_xor(r, o_, 64);
      if (c == 0) coef_arr[p0 + le] = r + b_c2[0];
    }
  }
}

// ---------------- per-node: dual softmax, h_agg, x_new ----------------
__global__ __launch_bounds__(256) void node_soft_kernel(
    const int* __restrict__ off, const float* __restrict__ d_arr,
    const float* __restrict__ sl_arr, const unsigned short* __restrict__ he_g,
    const float* __restrict__ coef_arr, const float* __restrict__ xmx_arr,
    const float* __restrict__ x, float* __restrict__ h_agg,
    float* __restrict__ x_out)
{
  int w = threadIdx.x >> 6, lane = threadIdx.x & 63;
  int n = blockIdx.x * 4 + w;
  if (n >= N_NODES) return;
  int b = off[n], e = off[n + 1];

  float s1 = 0.f, s2 = 0.f;
  for (int p = b + lane; p < e; p += 64) {
    s1 += __expf(-d_arr[p]);
    s2 += __expf(sl_arr[p]);
  }
  #pragma unroll
  for (int o = 32; o > 0; o >>= 1) { s1 += __shfl_xor(s1, o, 64); s2 += __shfl_xor(s2, o, 64); }

  float s3 = 0.f;
  for (int p = b + lane; p < e; p += 64) {
    float l3 = (__expf(-d_arr[p]) / s1) * (__expf(sl_arr[p]) / s2);
    s3 += __expf(l3);
  }
  #pragma unroll
  for (int o = 32; o > 0; o >>= 1) s3 += __shfl_xor(s3, o, 64);

  float acc = 0.f;
  for (int p = b; p < e; ++p) {
    float l3 = (__expf(-d_arr[p]) / s1) * (__expf(sl_arr[p]) / s2);
    float tot = __expf(l3) / s3;
    acc += tot * bf2f(he_g[(size_t)p * 64 + lane]);
  }
  h_agg[(size_t)n * 64 + lane] = acc;

  if (lane < 3) {
    float xv = x[n * 3 + lane];
    for (int p = b; p < e; ++p) xv += xmx_arr[p * 3 + lane] * coef_arr[p];
    x_out[n * 3 + lane] = xv;
  }
}

// ---------------- per-(node,c): x_att segment sum -> nrm ----------------
__global__ void xatt_kernel(const int* __restrict__ off,
                            const unsigned short* __restrict__ how_g,
                            const float* __restrict__ d_arr,
                            const float* __restrict__ xmx_arr,
                            float* __restrict__ nrm)
{
  int idx = blockIdx.x * 256 + threadIdx.x;
  if (idx >= N_NODES * 32) return;
  int n = idx >> 5, c = idx & 31;
  int b = off[n], e = off[n + 1];
  float a0 = 0.f, a1 = 0.f, a2 = 0.f;
  for (int p = b; p < e; ++p) {
    float wv = bf2f(how_g[(size_t)p * 32 + c]);
    float d = d_arr[p];
    float s = wv / (d * d);
    a0 += s * xmx_arr[p * 3 + 0];
    a1 += s * xmx_arr[p * 3 + 1];
    a2 += s * xmx_arr[p * 3 + 2];
  }
  nrm[idx] = sqrtf(fmaxf(a0 * a0 + a1 * a1 + a2 * a2, 0.f) + 1e-5f);
}

// ---------------- per-node MLPs: emb + h_new ----------------
__global__ __launch_bounds__(256) void node_mlp_kernel(
    const float* __restrict__ h, const float* __restrict__ h_agg,
    const float* __restrict__ nrm,
    const float* __restrict__ W_pn1, const float* __restrict__ b_pn1,
    const float* __restrict__ W_pn2, const float* __restrict__ b_pn2,
    const float* __restrict__ W_n1, const float* __restrict__ b_n1,
    const float* __restrict__ W_n2, const float* __restrict__ b_n2,
    float* __restrict__ h_out)
{
  __shared__ float s_t1[4][65];
  __shared__ float s_emb[4][65];
  __shared__ float s_t2[4][65];
  int t = threadIdx.x;
  int nl = t >> 6, c = t & 63;
  int n = blockIdx.x * 4 + nl;
  bool valid = n < N_NODES;

  float a = b_pn1[c];
  if (valid) {
    for (int k = 0; k < 32; ++k) a += nrm[(size_t)n * 32 + k] * W_pn1[k * 64 + c];
  }
  s_t1[nl][c] = silu_f(a);
  __syncthreads();

  a = b_pn2[c];
  for (int k = 0; k < 64; ++k) a += s_t1[nl][k] * W_pn2[k * 64 + c];
  s_emb[nl][c] = a;
  __syncthreads();

  a = b_n1[c];
  if (valid) {
    for (int k = 0; k < 64; ++k) a += h[(size_t)n * 64 + k] * W_n1[k * 64 + c];
    for (int k = 0; k < 64; ++k) a += h_agg[(size_t)n * 64 + k] * W_n1[(64 + k) * 64 + c];
  }
  for (int k = 0; k < 64; ++k) a += s_emb[nl][k] * W_n1[(128 + k) * 64 + c];
  s_t2[nl][c] = silu_f(a);
  __syncthreads();

  a = b_n2[c];
  for (int k = 0; k < 64; ++k) a += s_t2[nl][k] * W_n2[k * 64 + c];
  if (valid) h_out[(size_t)n * 64 + c] = a;
}

// ---------------- launch ----------------
extern "C" void kernel_launch(void* const* d_in, const int* in_sizes, int n_in,
                              void* d_out, int out_size, void* d_ws, size_t ws_size,
                              hipStream_t stream) {
  const float* h      = (const float*)d_in[0];
  const float* x      = (const float*)d_in[1];
  const int*   src    = (const int*)d_in[2];
  const int*   dst    = (const int*)d_in[3];
  const float* W_cf_in = (const float*)d_in[4];
  const float* b_cf_in = (const float*)d_in[5];
  const float* W_cf_f  = (const float*)d_in[6];
  const float* b_cf_f  = (const float*)d_in[7];
  const float* W_sem   = (const float*)d_in[8];
  const float* W_ew    = (const float*)d_in[9];
  const float* b_ew    = (const float*)d_in[10];
  const float* W_pn1   = (const float*)d_in[11];
  const float* b_pn1   = (const float*)d_in[12];
  const float* W_pn2   = (const float*)d_in[13];
  const float* b_pn2   = (const float*)d_in[14];
  const float* W_n1    = (const float*)d_in[15];
  const float* b_n1    = (const float*)d_in[16];
  const float* W_n2    = (const float*)d_in[17];
  const float* b_n2    = (const float*)d_in[18];
  const float* W_c1    = (const float*)d_in[19];
  const float* b_c1    = (const float*)d_in[20];
  const float* W_c2    = (const float*)d_in[21];
  const float* b_c2    = (const float*)d_in[22];

  char* ws = (char*)d_ws;
  size_t o = 0;
  auto take = [&](size_t bytes) {
    void* p = ws + o;
    o = (o + bytes + 255) & ~(size_t)255;
    return p;
  };
  int* deg    = (int*)take((size_t)N_NODES * 4);
  int* off    = (int*)take((size_t)(N_NODES + 1) * 4);
  int* cur    = (int*)take((size_t)N_NODES * 4);
  int* eperm  = (int*)take((size_t)N_EDGES * 4);
  float* d_arr = (float*)take((size_t)N_EDGES * 4);
  float* xmx   = (float*)take((size_t)N_EDGES * 12);
  float* sl    = (float*)take((size_t)N_EDGES * 4);
  float* coef  = (float*)take((size_t)N_EDGES * 4);
  unsigned short* he  = (unsigned short*)take((size_t)N_EDGES * 64 * 2);
  unsigned short* how = (unsigned short*)take((size_t)N_EDGES * 32 * 2);
  float* hagg = (float*)take((size_t)N_NODES * 64 * 4);
  float* nrm  = (float*)take((size_t)N_NODES * 32 * 4);

  float* h_out = (float*)d_out;
  float* x_out = h_out + (size_t)N_NODES * 64;

  hipMemsetAsync(deg, 0, (size_t)N_NODES * 4, stream);
  hipMemsetAsync(cur, 0, (size_t)N_NODES * 4, stream);

  hist_kernel<<<N_EDGES / 256, 256, 0, stream>>>(dst, deg);
  scan_kernel<<<1, 1024, 0, stream>>>(deg, off, N_NODES);
  scatter_kernel<<<N_EDGES / 256, 256, 0, stream>>>(dst, off, cur, eperm);

  edge_kernel<<<N_EDGES / 64, 256, 0, stream>>>(
      h, x, src, dst, eperm,
      W_cf_in, b_cf_in, W_cf_f, b_cf_f, W_sem,
      W_ew, b_ew, W_c1, b_c1, W_c2, b_c2,
      d_arr, xmx, sl, coef, he, how);

  node_soft_kernel<<<N_NODES / 4, 256, 0, stream>>>(
      off, d_arr, sl, he, coef, xmx, x, hagg, x_out);

  xatt_kernel<<<(N_NODES * 32) / 256, 256, 0, stream>>>(off, how, d_arr, xmx, nrm);

  node_mlp_kernel<<<N_NODES / 4, 256, 0, stream>>>(
      h, hagg, nrm,
      W_pn1, b_pn1, W_pn2, b_pn2,
      W_n1, b_n1, W_n2, b_n2,
      h_out);
}

// Round 3
// 1045.897 us; speedup vs baseline: 16.9377x; 16.9377x over previous
//
#include <hip/hip_runtime.h>

#define N_NODES 50000
#define N_EDGES 800000

typedef short s16x8 __attribute__((ext_vector_type(8)));
typedef float f32x4 __attribute__((ext_vector_type(4)));

__device__ __forceinline__ float silu_f(float v) {
  return v / (1.0f + __expf(-v));
}
__device__ __forceinline__ unsigned short f2bf(float f) {
  union { float f; unsigned u; } a; a.f = f;
  unsigned r = a.u + 0x7fffu + ((a.u >> 16) & 1u);
  return (unsigned short)(r >> 16);
}
__device__ __forceinline__ float bf2f(short s) {
  union { unsigned u; float f; } a; a.u = ((unsigned)(unsigned short)s) << 16;
  return a.f;
}

// ---------------- CSR build ----------------
__global__ void hist_kernel(const int* __restrict__ dst, int* __restrict__ deg) {
  int i = blockIdx.x * 256 + threadIdx.x;
  if (i < N_EDGES) atomicAdd(&deg[dst[i]], 1);
}

__global__ __launch_bounds__(1024) void scan_kernel(const int* __restrict__ deg,
                                                    int* __restrict__ off, int n) {
  __shared__ int wsum[16];
  __shared__ int s_carry;
  int t = threadIdx.x;
  int lane = t & 63, w = t >> 6;
  if (t == 0) { s_carry = 0; off[0] = 0; }
  __syncthreads();
  for (int base = 0; base < n; base += 1024) {
    int i = base + t;
    int v = (i < n) ? deg[i] : 0;
    int sv = v;
    #pragma unroll
    for (int o = 1; o < 64; o <<= 1) {
      int u = __shfl_up(sv, o, 64);
      if (lane >= o) sv += u;
    }
    if (lane == 63) wsum[w] = sv;
    __syncthreads();
    if (w == 0 && lane < 16) {
      int ws_ = wsum[lane];
      #pragma unroll
      for (int o = 1; o < 16; o <<= 1) {
        int u = __shfl_up(ws_, o, 64);
        if (lane >= o) ws_ += u;
      }
      wsum[lane] = ws_;
    }
    __syncthreads();
    int carry = s_carry;
    int prefix = (w > 0) ? wsum[w - 1] : 0;
    if (i < n) off[i + 1] = sv + prefix + carry;
    __syncthreads();
    if (t == 1023) s_carry = carry + wsum[15];
    __syncthreads();
  }
}

__global__ void scatter_kernel(const int* __restrict__ dst, const int* __restrict__ off,
                               int* __restrict__ cur, int* __restrict__ eperm) {
  int i = blockIdx.x * 256 + threadIdx.x;
  if (i < N_EDGES) {
    int dn = dst[i];
    int pos = atomicAdd(&cur[dn], 1);
    eperm[off[dn] + pos] = i;
  }
}

// ---------------- weight prep: f32 -> bf16 transposed [N][K] ----------------
__global__ void prep_kernel(const float* __restrict__ Wcfin, const float* __restrict__ Wcff,
                            const float* __restrict__ Wew, const float* __restrict__ Wc1,
                            short* __restrict__ WcfinT, short* __restrict__ WcffT,
                            short* __restrict__ WewT, short* __restrict__ Wc1T) {
  int t = blockIdx.x * 256 + threadIdx.x;
  int stride = gridDim.x * 256;
  for (int i = t; i < 64 * 128; i += stride) {
    int n = i >> 7, k = i & 127;
    WcfinT[i] = (short)f2bf(Wcfin[k * 64 + n]);
  }
  for (int i = t; i < 64 * 64; i += stride) {
    int n = i >> 6, k = i & 63;
    WcffT[i] = (k < 50) ? (short)f2bf(Wcff[k * 64 + n]) : (short)0;
  }
  for (int i = t; i < 32 * 192; i += stride) {
    int n = i / 192, k = i - n * 192;
    WewT[i] = (short)f2bf(Wew[k * 32 + n]);
  }
  for (int i = t; i < 64 * 64; i += stride) {
    int n = i >> 6, k = i & 63;
    Wc1T[i] = (short)f2bf(Wc1[k * 64 + n]);
  }
}

// ---------------- MFMA edge kernel: 64 edges / block, 4 waves ----------------
__global__ __launch_bounds__(256) void edge_kernel(
    const float* __restrict__ h, const float* __restrict__ x,
    const int* __restrict__ src, const int* __restrict__ dst,
    const int* __restrict__ eperm,
    const short* __restrict__ WcfinT, const float* __restrict__ b_cf_in,
    const short* __restrict__ WcffT, const float* __restrict__ b_cf_f,
    const float* __restrict__ W_sem,
    const short* __restrict__ WewT, const float* __restrict__ b_ew,
    const short* __restrict__ Wc1T, const float* __restrict__ b_c1,
    const float* __restrict__ W_c2, const float* __restrict__ b_c2,
    float* __restrict__ d_arr, float* __restrict__ xmx_arr,
    float* __restrict__ sl_arr, float* __restrict__ coef_arr,
    short* __restrict__ he_g, short* __restrict__ how_g)
{
  __shared__ short hcat[64][136];   // bf16, pad 128->136 (4-bank shift/row)
  __shared__ short rbf_s[64][72];   // bf16, K 50->64 zero-padded
  __shared__ short he_s[64][72];    // bf16
  __shared__ short how_s[64][40];   // bf16
  __shared__ int s_src[64], s_dst[64];
  __shared__ float s_d[64];

  const int t = threadIdx.x;
  const int p0 = blockIdx.x * 64;

  if (t < 64) {
    int e = eperm[p0 + t];
    s_src[t] = src[e];
    s_dst[t] = dst[e];
  }
  __syncthreads();

  // ---- stage h_cat (f32 -> bf16) + fused sem logit (f32) ----
  {
    int le = t >> 2, q = t & 3;
    int node = (q < 2) ? s_src[le] : s_dst[le];
    const float* hrow = h + (size_t)node * 64 + (q & 1) * 32;
    const float* wsm = W_sem + q * 32;
    float psem = 0.f;
    #pragma unroll
    for (int u = 0; u < 4; ++u) {
      float4 v0 = *reinterpret_cast<const float4*>(hrow + u * 8);
      float4 v1 = *reinterpret_cast<const float4*>(hrow + u * 8 + 4);
      psem += v0.x * wsm[u * 8 + 0] + v0.y * wsm[u * 8 + 1]
            + v0.z * wsm[u * 8 + 2] + v0.w * wsm[u * 8 + 3]
            + v1.x * wsm[u * 8 + 4] + v1.y * wsm[u * 8 + 5]
            + v1.z * wsm[u * 8 + 6] + v1.w * wsm[u * 8 + 7];
      s16x8 pk;
      pk[0] = (short)f2bf(v0.x); pk[1] = (short)f2bf(v0.y);
      pk[2] = (short)f2bf(v0.z); pk[3] = (short)f2bf(v0.w);
      pk[4] = (short)f2bf(v1.x); pk[5] = (short)f2bf(v1.y);
      pk[6] = (short)f2bf(v1.z); pk[7] = (short)f2bf(v1.w);
      *reinterpret_cast<s16x8*>(&hcat[le][q * 32 + u * 8]) = pk;
    }
    psem += __shfl_xor(psem, 1, 64);
    psem += __shfl_xor(psem, 2, 64);
    if (q == 0) sl_arr[p0 + le] = silu_f(psem);
  }

  // ---- geometry ----
  if (t < 64) {
    int p = p0 + t;
    int s = s_src[t], dn = s_dst[t];
    float mx0 = x[s * 3 + 0] - x[dn * 3 + 0];
    float mx1 = x[s * 3 + 1] - x[dn * 3 + 1];
    float mx2 = x[s * 3 + 2] - x[dn * 3 + 2];
    float d = sqrtf(mx0 * mx0 + mx1 * mx1 + mx2 * mx2 + 1e-5f);
    s_d[t] = d;
    d_arr[p] = d;
    xmx_arr[p * 3 + 0] = mx0;
    xmx_arr[p * 3 + 1] = mx1;
    xmx_arr[p * 3 + 2] = mx2;
  }
  __syncthreads();

  // ---- RBF (bf16), spread over all 256 threads ----
  {
    int le = t >> 2, kb = (t & 3) * 16;
    float d = s_d[le];
    s16x8 lo, hi;
    #pragma unroll 16
    for (int u = 0; u < 16; ++u) {
      int k = kb + u;
      float mu = (float)k * (5.0f / 49.0f);
      float dd = d - mu;
      float val = (k < 50) ? __expf(-10.0f * dd * dd) : 0.0f;
      short sv = (short)f2bf(val);
      if (u < 8) lo[u] = sv; else hi[u - 8] = sv;
    }
    *reinterpret_cast<s16x8*>(&rbf_s[le][kb]) = lo;
    *reinterpret_cast<s16x8*>(&rbf_s[le][kb + 8]) = hi;
  }
  __syncthreads();

  const int w = t >> 6, lane = t & 63;
  const int lr = lane & 15, lg = lane >> 4;
  const int arow = w * 16 + lr;   // A-row in LDS for this lane
  const int k8 = lg * 8;
  const f32x4 z = {0.f, 0.f, 0.f, 0.f};

  // ---- cf_in (K=128) and cf_f (K=64) MFMAs ----
  f32x4 acc[4] = {z, z, z, z};
  f32x4 fac[4] = {z, z, z, z};
  #pragma unroll
  for (int kb = 0; kb < 128; kb += 32) {
    s16x8 a = *reinterpret_cast<const s16x8*>(&hcat[arow][kb + k8]);
    #pragma unroll
    for (int j = 0; j < 4; ++j) {
      s16x8 b = *reinterpret_cast<const s16x8*>(&WcfinT[(j * 16 + lr) * 128 + kb + k8]);
      acc[j] = __builtin_amdgcn_mfma_f32_16x16x32_bf16(a, b, acc[j], 0, 0, 0);
    }
  }
  #pragma unroll
  for (int kb = 0; kb < 64; kb += 32) {
    s16x8 a = *reinterpret_cast<const s16x8*>(&rbf_s[arow][kb + k8]);
    #pragma unroll
    for (int j = 0; j < 4; ++j) {
      s16x8 b = *reinterpret_cast<const s16x8*>(&WcffT[(j * 16 + lr) * 64 + kb + k8]);
      fac[j] = __builtin_amdgcn_mfma_f32_16x16x32_bf16(a, b, fac[j], 0, 0, 0);
    }
  }
  // epilogue: h_e = (lin + b) * silu(filt + b)  -> he_s (bf16)
  #pragma unroll
  for (int j = 0; j < 4; ++j) {
    int col = j * 16 + lr;
    float bi = b_cf_in[col], bf_ = b_cf_f[col];
    #pragma unroll
    for (int r = 0; r < 4; ++r) {
      float he = (acc[j][r] + bi) * silu_f(fac[j][r] + bf_);
      he_s[w * 16 + lg * 4 + r][col] = (short)f2bf(he);
    }
  }
  __syncthreads();

  // ---- copy he_s -> global (coalesced) ----
  #pragma unroll
  for (int u = 0; u < 2; ++u) {
    int q2 = t + u * 256;                 // 0..511 chunks of 8
    int row = q2 >> 3, col8 = (q2 & 7) * 8;
    s16x8 v = *reinterpret_cast<const s16x8*>(&he_s[row][col8]);
    *reinterpret_cast<s16x8*>(&he_g[((size_t)(p0 + row)) * 64 + col8]) = v;
  }

  // ---- ew: [hcat | h_e] @ W_ew  (K=192, out 64x32) ----
  {
    f32x4 ew[2] = {z, z};
    #pragma unroll
    for (int kb = 0; kb < 128; kb += 32) {
      s16x8 a = *reinterpret_cast<const s16x8*>(&hcat[arow][kb + k8]);
      #pragma unroll
      for (int j = 0; j < 2; ++j) {
        s16x8 b = *reinterpret_cast<const s16x8*>(&WewT[(j * 16 + lr) * 192 + kb + k8]);
        ew[j] = __builtin_amdgcn_mfma_f32_16x16x32_bf16(a, b, ew[j], 0, 0, 0);
      }
    }
    #pragma unroll
    for (int kb = 0; kb < 64; kb += 32) {
      s16x8 a = *reinterpret_cast<const s16x8*>(&he_s[arow][kb + k8]);
      #pragma unroll
      for (int j = 0; j < 2; ++j) {
        s16x8 b = *reinterpret_cast<const s16x8*>(&WewT[(j * 16 + lr) * 192 + 128 + kb + k8]);
        ew[j] = __builtin_amdgcn_mfma_f32_16x16x32_bf16(a, b, ew[j], 0, 0, 0);
      }
    }
    #pragma unroll
    for (int j = 0; j < 2; ++j) {
      int col = j * 16 + lr;
      float be = b_ew[col];
      #pragma unroll
      for (int r = 0; r < 4; ++r)
        how_s[w * 16 + lg * 4 + r][col] = (short)f2bf(tanhf(ew[j][r] + be));
    }
  }

  // ---- coef: silu(h_e @ W_c1 + b) @ W_c2 + b ----
  {
    f32x4 c[4] = {z, z, z, z};
    #pragma unroll
    for (int kb = 0; kb < 64; kb += 32) {
      s16x8 a = *reinterpret_cast<const s16x8*>(&he_s[arow][kb + k8]);
      #pragma unroll
      for (int j = 0; j < 4; ++j) {
        s16x8 b = *reinterpret_cast<const s16x8*>(&Wc1T[(j * 16 + lr) * 64 + kb + k8]);
        c[j] = __builtin_amdgcn_mfma_f32_16x16x32_bf16(a, b, c[j], 0, 0, 0);
      }
    }
    float p[4] = {0.f, 0.f, 0.f, 0.f};
    #pragma unroll
    for (int j = 0; j < 4; ++j) {
      int col = j * 16 + lr;
      float bc = b_c1[col], wc = W_c2[col];
      #pragma unroll
      for (int r = 0; r < 4; ++r) p[r] += silu_f(c[j][r] + bc) * wc;
    }
    #pragma unroll
    for (int r = 0; r < 4; ++r) {
      p[r] += __shfl_xor(p[r], 1, 64);
      p[r] += __shfl_xor(p[r], 2, 64);
      p[r] += __shfl_xor(p[r], 4, 64);
      p[r] += __shfl_xor(p[r], 8, 64);
    }
    if (lr == 0) {
      float bc2 = b_c2[0];
      #pragma unroll
      for (int r = 0; r < 4; ++r)
        coef_arr[p0 + w * 16 + lg * 4 + r] = p[r] + bc2;
    }
  }
  __syncthreads();

  // ---- copy how_s -> global (coalesced) ----
  {
    int row = t >> 2, col8 = (t & 3) * 8;
    s16x8 v = *reinterpret_cast<const s16x8*>(&how_s[row][col8]);
    *reinterpret_cast<s16x8*>(&how_g[((size_t)(p0 + row)) * 32 + col8]) = v;
  }
}

// ---------------- per-node: dual softmax, h_agg, x_new ----------------
__global__ __launch_bounds__(256) void node_soft_kernel(
    const int* __restrict__ off, const float* __restrict__ d_arr,
    const float* __restrict__ sl_arr, const short* __restrict__ he_g,
    const float* __restrict__ coef_arr, const float* __restrict__ xmx_arr,
    const float* __restrict__ x, float* __restrict__ h_agg,
    float* __restrict__ x_out)
{
  int w = threadIdx.x >> 6, lane = threadIdx.x & 63;
  int n = blockIdx.x * 4 + w;
  if (n >= N_NODES) return;
  int b = off[n], e = off[n + 1];

  float s1 = 0.f, s2 = 0.f;
  for (int p = b + lane; p < e; p += 64) {
    s1 += __expf(-d_arr[p]);
    s2 += __expf(sl_arr[p]);
  }
  #pragma unroll
  for (int o = 32; o > 0; o >>= 1) { s1 += __shfl_xor(s1, o, 64); s2 += __shfl_xor(s2, o, 64); }

  float s3 = 0.f;
  for (int p = b + lane; p < e; p += 64) {
    float l3 = (__expf(-d_arr[p]) / s1) * (__expf(sl_arr[p]) / s2);
    s3 += __expf(l3);
  }
  #pragma unroll
  for (int o = 32; o > 0; o >>= 1) s3 += __shfl_xor(s3, o, 64);

  float acc = 0.f;
  for (int p = b; p < e; ++p) {
    float l3 = (__expf(-d_arr[p]) / s1) * (__expf(sl_arr[p]) / s2);
    float tot = __expf(l3) / s3;
    acc += tot * bf2f(he_g[(size_t)p * 64 + lane]);
  }
  h_agg[(size_t)n * 64 + lane] = acc;

  if (lane < 3) {
    float xv = x[n * 3 + lane];
    for (int p = b; p < e; ++p) xv += xmx_arr[p * 3 + lane] * coef_arr[p];
    x_out[n * 3 + lane] = xv;
  }
}

// ---------------- per-(node,c): x_att segment sum -> nrm ----------------
__global__ void xatt_kernel(const int* __restrict__ off,
                            const short* __restrict__ how_g,
                            const float* __restrict__ d_arr,
                            const float* __restrict__ xmx_arr,
                            float* __restrict__ nrm)
{
  int idx = blockIdx.x * 256 + threadIdx.x;
  if (idx >= N_NODES * 32) return;
  int n = idx >> 5, c = idx & 31;
  int b = off[n], e = off[n + 1];
  float a0 = 0.f, a1 = 0.f, a2 = 0.f;
  for (int p = b; p < e; ++p) {
    float wv = bf2f(how_g[(size_t)p * 32 + c]);
    float d = d_arr[p];
    float s = wv / (d * d);
    a0 += s * xmx_arr[p * 3 + 0];
    a1 += s * xmx_arr[p * 3 + 1];
    a2 += s * xmx_arr[p * 3 + 2];
  }
  nrm[idx] = sqrtf(fmaxf(a0 * a0 + a1 * a1 + a2 * a2, 0.f) + 1e-5f);
}

// ---------------- per-node MLPs: emb + h_new ----------------
__global__ __launch_bounds__(256) void node_mlp_kernel(
    const float* __restrict__ h, const float* __restrict__ h_agg,
    const float* __restrict__ nrm,
    const float* __restrict__ W_pn1, const float* __restrict__ b_pn1,
    const float* __restrict__ W_pn2, const float* __restrict__ b_pn2,
    const float* __restrict__ W_n1, const float* __restrict__ b_n1,
    const float* __restrict__ W_n2, const float* __restrict__ b_n2,
    float* __restrict__ h_out)
{
  __shared__ float s_t1[4][65];
  __shared__ float s_emb[4][65];
  __shared__ float s_t2[4][65];
  int t = threadIdx.x;
  int nl = t >> 6, c = t & 63;
  int n = blockIdx.x * 4 + nl;
  bool valid = n < N_NODES;

  float a = b_pn1[c];
  if (valid) {
    for (int k = 0; k < 32; ++k) a += nrm[(size_t)n * 32 + k] * W_pn1[k * 64 + c];
  }
  s_t1[nl][c] = silu_f(a);
  __syncthreads();

  a = b_pn2[c];
  for (int k = 0; k < 64; ++k) a += s_t1[nl][k] * W_pn2[k * 64 + c];
  s_emb[nl][c] = a;
  __syncthreads();

  a = b_n1[c];
  if (valid) {
    for (int k = 0; k < 64; ++k) a += h[(size_t)n * 64 + k] * W_n1[k * 64 + c];
    for (int k = 0; k < 64; ++k) a += h_agg[(size_t)n * 64 + k] * W_n1[(64 + k) * 64 + c];
  }
  for (int k = 0; k < 64; ++k) a += s_emb[nl][k] * W_n1[(128 + k) * 64 + c];
  s_t2[nl][c] = silu_f(a);
  __syncthreads();

  a = b_n2[c];
  for (int k = 0; k < 64; ++k) a += s_t2[nl][k] * W_n2[k * 64 + c];
  if (valid) h_out[(size_t)n * 64 + c] = a;
}

// ---------------- launch ----------------
extern "C" void kernel_launch(void* const* d_in, const int* in_sizes, int n_in,
                              void* d_out, int out_size, void* d_ws, size_t ws_size,
                              hipStream_t stream) {
  const float* h      = (const float*)d_in[0];
  const float* x      = (const float*)d_in[1];
  const int*   src    = (const int*)d_in[2];
  const int*   dst    = (const int*)d_in[3];
  const float* W_cf_in = (const float*)d_in[4];
  const float* b_cf_in = (const float*)d_in[5];
  const float* W_cf_f  = (const float*)d_in[6];
  const float* b_cf_f  = (const float*)d_in[7];
  const float* W_sem   = (const float*)d_in[8];
  const float* W_ew    = (const float*)d_in[9];
  const float* b_ew    = (const float*)d_in[10];
  const float* W_pn1   = (const float*)d_in[11];
  const float* b_pn1   = (const float*)d_in[12];
  const float* W_pn2   = (const float*)d_in[13];
  const float* b_pn2   = (const float*)d_in[14];
  const float* W_n1    = (const float*)d_in[15];
  const float* b_n1    = (const float*)d_in[16];
  const float* W_n2    = (const float*)d_in[17];
  const float* b_n2    = (const float*)d_in[18];
  const float* W_c1    = (const float*)d_in[19];
  const float* b_c1    = (const float*)d_in[20];
  const float* W_c2    = (const float*)d_in[21];
  const float* b_c2    = (const float*)d_in[22];

  char* ws = (char*)d_ws;
  size_t o = 0;
  auto take = [&](size_t bytes) {
    void* p = ws + o;
    o = (o + bytes + 255) & ~(size_t)255;
    return p;
  };
  int* deg    = (int*)take((size_t)N_NODES * 4);
  int* off    = (int*)take((size_t)(N_NODES + 1) * 4);
  int* cur    = (int*)take((size_t)N_NODES * 4);
  int* eperm  = (int*)take((size_t)N_EDGES * 4);
  float* d_arr = (float*)take((size_t)N_EDGES * 4);
  float* xmx   = (float*)take((size_t)N_EDGES * 12);
  float* sl    = (float*)take((size_t)N_EDGES * 4);
  float* coef  = (float*)take((size_t)N_EDGES * 4);
  short* he   = (short*)take((size_t)N_EDGES * 64 * 2);
  short* how  = (short*)take((size_t)N_EDGES * 32 * 2);
  float* hagg = (float*)take((size_t)N_NODES * 64 * 4);
  float* nrm  = (float*)take((size_t)N_NODES * 32 * 4);
  short* WcfinT = (short*)take((size_t)64 * 128 * 2);
  short* WcffT  = (short*)take((size_t)64 * 64 * 2);
  short* WewT   = (short*)take((size_t)32 * 192 * 2);
  short* Wc1T   = (short*)take((size_t)64 * 64 * 2);

  float* h_out = (float*)d_out;
  float* x_out = h_out + (size_t)N_NODES * 64;

  hipMemsetAsync(deg, 0, (size_t)N_NODES * 4, stream);
  hipMemsetAsync(cur, 0, (size_t)N_NODES * 4, stream);

  hist_kernel<<<N_EDGES / 256, 256, 0, stream>>>(dst, deg);
  scan_kernel<<<1, 1024, 0, stream>>>(deg, off, N_NODES);
  scatter_kernel<<<N_EDGES / 256, 256, 0, stream>>>(dst, off, cur, eperm);
  prep_kernel<<<32, 256, 0, stream>>>(W_cf_in, W_cf_f, W_ew, W_c1,
                                      WcfinT, WcffT, WewT, Wc1T);

  edge_kernel<<<N_EDGES / 64, 256, 0, stream>>>(
      h, x, src, dst, eperm,
      WcfinT, b_cf_in, WcffT, b_cf_f, W_sem,
      WewT, b_ew, Wc1T, b_c1, W_c2, b_c2,
      d_arr, xmx, sl, coef, he, how);

  node_soft_kernel<<<N_NODES / 4, 256, 0, stream>>>(
      off, d_arr, sl, he, coef, xmx, x, hagg, x_out);

  xatt_kernel<<<(N_NODES * 32) / 256, 256, 0, stream>>>(off, how, d_arr, xmx, nrm);

  node_mlp_kernel<<<N_NODES / 4, 256, 0, stream>>>(
      h, hagg, nrm,
      W_pn1, b_pn1, W_pn2, b_pn2,
      W_n1, b_n1, W_n2, b_n2,
      h_out);
}

// Round 5
// 974.562 us; speedup vs baseline: 18.1775x; 1.0732x over previous
//
#include <hip/hip_runtime.h>

#define N_NODES 50000
#define N_EDGES 800000

typedef short s16x8 __attribute__((ext_vector_type(8)));
typedef float f32x4 __attribute__((ext_vector_type(4)));

__device__ __forceinline__ float silu_f(float v) {
  return v / (1.0f + __expf(-v));
}
__device__ __forceinline__ unsigned short f2bf(float f) {
  union { float f; unsigned u; } a; a.f = f;
  unsigned r = a.u + 0x7fffu + ((a.u >> 16) & 1u);
  return (unsigned short)(r >> 16);
}
__device__ __forceinline__ float bf2f(short s) {
  union { unsigned u; float f; } a; a.u = ((unsigned)(unsigned short)s) << 16;
  return a.f;
}

// ---------------- CSR build ----------------
__global__ void hist_kernel(const int* __restrict__ dst, int* __restrict__ deg) {
  int i = blockIdx.x * 256 + threadIdx.x;
  if (i < N_EDGES) atomicAdd(&deg[dst[i]], 1);
}

__global__ __launch_bounds__(1024) void scan_kernel(const int* __restrict__ deg,
                                                    int* __restrict__ off, int n) {
  __shared__ int wsum[16];
  __shared__ int s_carry;
  int t = threadIdx.x;
  int lane = t & 63, w = t >> 6;
  if (t == 0) { s_carry = 0; off[0] = 0; }
  __syncthreads();
  for (int base = 0; base < n; base += 1024) {
    int i = base + t;
    int v = (i < n) ? deg[i] : 0;
    int sv = v;
    #pragma unroll
    for (int o = 1; o < 64; o <<= 1) {
      int u = __shfl_up(sv, o, 64);
      if (lane >= o) sv += u;
    }
    if (lane == 63) wsum[w] = sv;
    __syncthreads();
    if (w == 0 && lane < 16) {
      int ws_ = wsum[lane];
      #pragma unroll
      for (int o = 1; o < 16; o <<= 1) {
        int u = __shfl_up(ws_, o, 64);
        if (lane >= o) ws_ += u;
      }
      wsum[lane] = ws_;
    }
    __syncthreads();
    int carry = s_carry;
    int prefix = (w > 0) ? wsum[w - 1] : 0;
    if (i < n) off[i + 1] = sv + prefix + carry;
    __syncthreads();
    if (t == 1023) s_carry = carry + wsum[15];
    __syncthreads();
  }
}

__global__ void scatter_kernel(const int* __restrict__ dst, const int* __restrict__ off,
                               int* __restrict__ cur, int* __restrict__ eperm) {
  int i = blockIdx.x * 256 + threadIdx.x;
  if (i < N_EDGES) {
    int dn = dst[i];
    int pos = atomicAdd(&cur[dn], 1);
    eperm[off[dn] + pos] = i;
  }
}

// -------- weight prep: f32 -> bf16 transposed [N][K]; h -> bf16 rows --------
__global__ void prep_kernel(const float* __restrict__ Wcfin, const float* __restrict__ Wcff,
                            const float* __restrict__ Wew, const float* __restrict__ Wc1,
                            const float* __restrict__ h,
                            short* __restrict__ WcfinT, short* __restrict__ WcffT,
                            short* __restrict__ WewT, short* __restrict__ Wc1T,
                            short* __restrict__ h_bf) {
  int t = blockIdx.x * 256 + threadIdx.x;
  int stride = gridDim.x * 256;
  for (int i = t; i < 64 * 128; i += stride) {
    int n = i >> 7, k = i & 127;
    WcfinT[i] = (short)f2bf(Wcfin[k * 64 + n]);
  }
  for (int i = t; i < 64 * 64; i += stride) {
    int n = i >> 6, k = i & 63;
    WcffT[i] = (k < 50) ? (short)f2bf(Wcff[k * 64 + n]) : (short)0;
  }
  for (int i = t; i < 32 * 192; i += stride) {
    int n = i / 192, k = i - n * 192;
    WewT[i] = (short)f2bf(Wew[k * 32 + n]);
  }
  for (int i = t; i < 64 * 64; i += stride) {
    int n = i >> 6, k = i & 63;
    Wc1T[i] = (short)f2bf(Wc1[k * 64 + n]);
  }
  // h -> bf16 (N*64 elements, via float4)
  for (int i = t; i < (N_NODES * 64) / 4; i += stride) {
    float4 v = reinterpret_cast<const float4*>(h)[i];
    ushort4 u;
    u.x = f2bf(v.x); u.y = f2bf(v.y); u.z = f2bf(v.z); u.w = f2bf(v.w);
    reinterpret_cast<ushort4*>(h_bf)[i] = u;
  }
}

// ------- MFMA edge kernel: 64 edges / block, 4 independent waves, no barriers -------
__global__ __launch_bounds__(256) void edge_kernel(
    const short* __restrict__ h_bf, const float* __restrict__ x,
    const int* __restrict__ src, const int* __restrict__ dst,
    const int* __restrict__ eperm,
    const short* __restrict__ WcfinT, const float* __restrict__ b_cf_in,
    const short* __restrict__ WcffT, const float* __restrict__ b_cf_f,
    const float* __restrict__ W_sem,
    const short* __restrict__ WewT, const float* __restrict__ b_ew,
    const short* __restrict__ Wc1T, const float* __restrict__ b_c1,
    const float* __restrict__ W_c2, const float* __restrict__ b_c2,
    float* __restrict__ d_arr, float* __restrict__ xmx_arr,
    float* __restrict__ sl_arr, float* __restrict__ coef_arr,
    short* __restrict__ he_g, short* __restrict__ how_g)
{
  // All LDS traffic is wave-local: wave w owns rows [16w, 16w+16).
  __shared__ short hcat[64][136];     // bf16 h_cat
  __shared__ short rbf_how[64][72];   // rbf in phase 1; 'how' aliased into the
                                      // same wave slice in phase 2 (rbf dead)
  __shared__ short he_s[64][72];      // bf16 h_e

  const int t = threadIdx.x;
  const int p0 = blockIdx.x * 64;
  const int le = t >> 2, q = t & 3;   // 4 threads per edge
  const int p_edge = p0 + le;

  const int e = eperm[p_edge];
  const int sn = src[e], dn = dst[e];

  // ---- geometry (all 4 threads of group compute; q==0 writes) ----
  float mx0 = x[sn * 3 + 0] - x[dn * 3 + 0];
  float mx1 = x[sn * 3 + 1] - x[dn * 3 + 1];
  float mx2 = x[sn * 3 + 2] - x[dn * 3 + 2];
  float d = sqrtf(mx0 * mx0 + mx1 * mx1 + mx2 * mx2 + 1e-5f);
  if (q == 0) {
    d_arr[p_edge] = d;
    xmx_arr[p_edge * 3 + 0] = mx0;
    xmx_arr[p_edge * 3 + 1] = mx1;
    xmx_arr[p_edge * 3 + 2] = mx2;
  }

  // ---- stage h_cat (bf16 gather) + fused sem logit ----
  {
    int node = (q < 2) ? sn : dn;
    const s16x8* hrow = reinterpret_cast<const s16x8*>(h_bf + (size_t)node * 64 + (q & 1) * 32);
    const float* wsm = W_sem + q * 32;
    float psem = 0.f;
    #pragma unroll
    for (int u = 0; u < 4; ++u) {
      s16x8 v = hrow[u];
      *reinterpret_cast<s16x8*>(&hcat[le][q * 32 + u * 8]) = v;
      float4 w0 = *reinterpret_cast<const float4*>(wsm + u * 8);
      float4 w1 = *reinterpret_cast<const float4*>(wsm + u * 8 + 4);
      psem += bf2f(v[0]) * w0.x + bf2f(v[1]) * w0.y + bf2f(v[2]) * w0.z + bf2f(v[3]) * w0.w
            + bf2f(v[4]) * w1.x + bf2f(v[5]) * w1.y + bf2f(v[6]) * w1.z + bf2f(v[7]) * w1.w;
    }
    psem += __shfl_xor(psem, 1, 64);
    psem += __shfl_xor(psem, 2, 64);
    if (q == 0) sl_arr[p_edge] = silu_f(psem);
  }

  // ---- RBF (bf16): q covers k = q*16 .. q*16+15 ----
  {
    int kb = q * 16;
    s16x8 lo, hi;
    #pragma unroll 16
    for (int u = 0; u < 16; ++u) {
      int k = kb + u;
      float mu = (float)k * (5.0f / 49.0f);
      float dd = d - mu;
      float val = (k < 50) ? __expf(-10.0f * dd * dd) : 0.0f;
      short sv = (short)f2bf(val);
      if (u < 8) lo[u] = sv; else hi[u - 8] = sv;
    }
    *reinterpret_cast<s16x8*>(&rbf_how[le][kb]) = lo;
    *reinterpret_cast<s16x8*>(&rbf_how[le][kb + 8]) = hi;
  }
  // no __syncthreads: wave-local LDS, in-order DS per wave

  const int w = t >> 6, lane = t & 63;
  const int lr = lane & 15, lg = lane >> 4;
  const int arow = w * 16 + lr;
  const int k8 = lg * 8;
  const f32x4 z = {0.f, 0.f, 0.f, 0.f};

  // ---- cf_in (K=128) and cf_f (K=64) MFMAs ----
  f32x4 acc[4] = {z, z, z, z};
  f32x4 fac[4] = {z, z, z, z};
  #pragma unroll
  for (int kb = 0; kb < 128; kb += 32) {
    s16x8 a = *reinterpret_cast<const s16x8*>(&hcat[arow][kb + k8]);
    #pragma unroll
    for (int j = 0; j < 4; ++j) {
      s16x8 b = *reinterpret_cast<const s16x8*>(&WcfinT[(j * 16 + lr) * 128 + kb + k8]);
      acc[j] = __builtin_amdgcn_mfma_f32_16x16x32_bf16(a, b, acc[j], 0, 0, 0);
    }
  }
  #pragma unroll
  for (int kb = 0; kb < 64; kb += 32) {
    s16x8 a = *reinterpret_cast<const s16x8*>(&rbf_how[arow][kb + k8]);
    #pragma unroll
    for (int j = 0; j < 4; ++j) {
      s16x8 b = *reinterpret_cast<const s16x8*>(&WcffT[(j * 16 + lr) * 64 + kb + k8]);
      fac[j] = __builtin_amdgcn_mfma_f32_16x16x32_bf16(a, b, fac[j], 0, 0, 0);
    }
  }
  // epilogue: h_e = (lin + b) * silu(filt + b)  -> he_s (bf16)
  #pragma unroll
  for (int j = 0; j < 4; ++j) {
    int col = j * 16 + lr;
    float bi = b_cf_in[col], bf_ = b_cf_f[col];
    #pragma unroll
    for (int r = 0; r < 4; ++r) {
      float he = (acc[j][r] + bi) * silu_f(fac[j][r] + bf_);
      he_s[w * 16 + lg * 4 + r][col] = (short)f2bf(he);
    }
  }

  // ---- copy he_s -> global (own-wave rows, coalesced) ----
  #pragma unroll
  for (int u = 0; u < 2; ++u) {
    int chunk = lane + u * 64;                  // 0..127
    int row = w * 16 + (chunk >> 3), col8 = (chunk & 7) * 8;
    s16x8 v = *reinterpret_cast<const s16x8*>(&he_s[row][col8]);
    *reinterpret_cast<s16x8*>(&he_g[((size_t)(p0 + row)) * 64 + col8]) = v;
  }

  // 'how' lives inside this wave's (now dead) rbf slice
  short* how_base = &rbf_how[w * 16][0];        // 16*72 shorts per wave slice
  #define HOWP(row_in_wave) (how_base + (row_in_wave) * 40)

  // ---- ew: [hcat | h_e] @ W_ew  (K=192, out 64x32) ----
  {
    f32x4 ew[2] = {z, z};
    #pragma unroll
    for (int kb = 0; kb < 128; kb += 32) {
      s16x8 a = *reinterpret_cast<const s16x8*>(&hcat[arow][kb + k8]);
      #pragma unroll
      for (int j = 0; j < 2; ++j) {
        s16x8 b = *reinterpret_cast<const s16x8*>(&WewT[(j * 16 + lr) * 192 + kb + k8]);
        ew[j] = __builtin_amdgcn_mfma_f32_16x16x32_bf16(a, b, ew[j], 0, 0, 0);
      }
    }
    #pragma unroll
    for (int kb = 0; kb < 64; kb += 32) {
      s16x8 a = *reinterpret_cast<const s16x8*>(&he_s[arow][kb + k8]);
      #pragma unroll
      for (int j = 0; j < 2; ++j) {
        s16x8 b = *reinterpret_cast<const s16x8*>(&WewT[(j * 16 + lr) * 192 + 128 + kb + k8]);
        ew[j] = __builtin_amdgcn_mfma_f32_16x16x32_bf16(a, b, ew[j], 0, 0, 0);
      }
    }
    #pragma unroll
    for (int j = 0; j < 2; ++j) {
      int col = j * 16 + lr;
      float be = b_ew[col];
      #pragma unroll
      for (int r = 0; r < 4; ++r)
        HOWP(lg * 4 + r)[col] = (short)f2bf(tanhf(ew[j][r] + be));
    }
  }

  // ---- coef: silu(h_e @ W_c1 + b) @ W_c2 + b ----
  {
    f32x4 c[4] = {z, z, z, z};
    #pragma unroll
    for (int kb = 0; kb < 64; kb += 32) {
      s16x8 a = *reinterpret_cast<const s16x8*>(&he_s[arow][kb + k8]);
      #pragma unroll
      for (int j = 0; j < 4; ++j) {
        s16x8 b = *reinterpret_cast<const s16x8*>(&Wc1T[(j * 16 + lr) * 64 + kb + k8]);
        c[j] = __builtin_amdgcn_mfma_f32_16x16x32_bf16(a, b, c[j], 0, 0, 0);
      }
    }
    float p[4] = {0.f, 0.f, 0.f, 0.f};
    #pragma unroll
    for (int j = 0; j < 4; ++j) {
      int col = j * 16 + lr;
      float bc = b_c1[col], wc = W_c2[col];
      #pragma unroll
      for (int r = 0; r < 4; ++r) p[r] += silu_f(c[j][r] + bc) * wc;
    }
    #pragma unroll
    for (int r = 0; r < 4; ++r) {
      p[r] += __shfl_xor(p[r], 1, 64);
      p[r] += __shfl_xor(p[r], 2, 64);
      p[r] += __shfl_xor(p[r], 4, 64);
      p[r] += __shfl_xor(p[r], 8, 64);
    }
    if (lr == 0) {
      float bc2 = b_c2[0];
      #pragma unroll
      for (int r = 0; r < 4; ++r)
        coef_arr[p0 + w * 16 + lg * 4 + r] = p[r] + bc2;
    }
  }

  // ---- copy how -> global (own-wave rows, coalesced) ----
  {
    int riw = lane >> 2, col8 = (lane & 3) * 8;
    s16x8 v = *reinterpret_cast<const s16x8*>(HOWP(riw) + col8);
    *reinterpret_cast<s16x8*>(&how_g[((size_t)(p0 + w * 16 + riw)) * 32 + col8]) = v;
  }
  #undef HOWP
}

// ------- fused per-node kernel: dual softmax, h_agg, x_new, x_att nrm -------
__global__ __launch_bounds__(256) void node_agg_kernel(
    const int* __restrict__ off, const float* __restrict__ d_arr,
    const float* __restrict__ sl_arr, const short* __restrict__ he_g,
    const float* __restrict__ coef_arr, const float* __restrict__ xmx_arr,
    const short* __restrict__ how_g, const float* __restrict__ x,
    float* __restrict__ h_agg, float* __restrict__ nrm,
    float* __restrict__ x_out)
{
  int w = threadIdx.x >> 6, lane = threadIdx.x & 63;
  int n = blockIdx.x * 4 + w;
  if (n >= N_NODES) return;
  int b = off[n], e = off[n + 1];

  float s1 = 0.f, s2 = 0.f;
  for (int p = b + lane; p < e; p += 64) {
    s1 += __expf(-d_arr[p]);
    s2 += __expf(sl_arr[p]);
  }
  #pragma unroll
  for (int o = 32; o > 0; o >>= 1) { s1 += __shfl_xor(s1, o, 64); s2 += __shfl_xor(s2, o, 64); }
  float r1 = 1.f / s1, r2 = 1.f / s2;

  float s3 = 0.f;
  for (int p = b + lane; p < e; p += 64) {
    float l3 = (__expf(-d_arr[p]) * r1) * (__expf(sl_arr[p]) * r2);
    s3 += __expf(l3);
  }
  #pragma unroll
  for (int o = 32; o > 0; o >>= 1) s3 += __shfl_xor(s3, o, 64);
  float inv3 = 1.f / s3;

  // pass 3: h_agg (lane = feature), x_new folded in for lanes 0..2
  float acc = 0.f;
  float xv = (lane < 3) ? x[n * 3 + lane] : 0.f;
  for (int p = b; p < e; ++p) {
    float l3 = (__expf(-d_arr[p]) * r1) * (__expf(sl_arr[p]) * r2);
    float tot = __expf(l3) * inv3;
    acc += tot * bf2f(he_g[(size_t)p * 64 + lane]);
    if (lane < 3) xv += xmx_arr[p * 3 + lane] * coef_arr[p];
  }
  h_agg[(size_t)n * 64 + lane] = acc;
  if (lane < 3) x_out[n * 3 + lane] = xv;

  // pass 4: x_att segment sum -> nrm; 2 edges/iter across lane halves
  int c = lane & 31, par = lane >> 5;
  float a0 = 0.f, a1 = 0.f, a2 = 0.f;
  for (int p = b + par; p < e; p += 2) {
    float wv = bf2f(how_g[(size_t)p * 32 + c]);
    float dd = d_arr[p];
    float s = wv / (dd * dd);
    a0 += s * xmx_arr[p * 3 + 0];
    a1 += s * xmx_arr[p * 3 + 1];
    a2 += s * xmx_arr[p * 3 + 2];
  }
  a0 += __shfl_xor(a0, 32, 64);
  a1 += __shfl_xor(a1, 32, 64);
  a2 += __shfl_xor(a2, 32, 64);
  if (lane < 32)
    nrm[(size_t)n * 32 + c] = sqrtf(fmaxf(a0 * a0 + a1 * a1 + a2 * a2, 0.f) + 1e-5f);
}

// ---------------- per-node MLPs: emb + h_new ----------------
__global__ __launch_bounds__(256) void node_mlp_kernel(
    const float* __restrict__ h, const float* __restrict__ h_agg,
    const float* __restrict__ nrm,
    const float* __restrict__ W_pn1, const float* __restrict__ b_pn1,
    const float* __restrict__ W_pn2, const float* __restrict__ b_pn2,
    const float* __restrict__ W_n1, const float* __restrict__ b_n1,
    const float* __restrict__ W_n2, const float* __restrict__ b_n2,
    float* __restrict__ h_out)
{
  __shared__ float s_t1[4][65];
  __shared__ float s_emb[4][65];
  __shared__ float s_t2[4][65];
  int t = threadIdx.x;
  int nl = t >> 6, c = t & 63;
  int n = blockIdx.x * 4 + nl;
  bool valid = n < N_NODES;

  float a = b_pn1[c];
  if (valid) {
    for (int k = 0; k < 32; ++k) a += nrm[(size_t)n * 32 + k] * W_pn1[k * 64 + c];
  }
  s_t1[nl][c] = silu_f(a);
  __syncthreads();

  a = b_pn2[c];
  for (int k = 0; k < 64; ++k) a += s_t1[nl][k] * W_pn2[k * 64 + c];
  s_emb[nl][c] = a;
  __syncthreads();

  a = b_n1[c];
  if (valid) {
    for (int k = 0; k < 64; ++k) a += h[(size_t)n * 64 + k] * W_n1[k * 64 + c];
    for (int k = 0; k < 64; ++k) a += h_agg[(size_t)n * 64 + k] * W_n1[(64 + k) * 64 + c];
  }
  for (int k = 0; k < 64; ++k) a += s_emb[nl][k] * W_n1[(128 + k) * 64 + c];
  s_t2[nl][c] = silu_f(a);
  __syncthreads();

  a = b_n2[c];
  for (int k = 0; k < 64; ++k) a += s_t2[nl][k] * W_n2[k * 64 + c];
  if (valid) h_out[(size_t)n * 64 + c] = a;
}

// ---------------- launch ----------------
extern "C" void kernel_launch(void* const* d_in, const int* in_sizes, int n_in,
                              void* d_out, int out_size, void* d_ws, size_t ws_size,
                              hipStream_t stream) {
  const float* h      = (const float*)d_in[0];
  const float* x      = (const float*)d_in[1];
  const int*   src    = (const int*)d_in[2];
  const int*   dst    = (const int*)d_in[3];
  const float* W_cf_in = (const float*)d_in[4];
  const float* b_cf_in = (const float*)d_in[5];
  const float* W_cf_f  = (const float*)d_in[6];
  const float* b_cf_f  = (const float*)d_in[7];
  const float* W_sem   = (const float*)d_in[8];
  const float* W_ew    = (const float*)d_in[9];
  const float* b_ew    = (const float*)d_in[10];
  const float* W_pn1   = (const float*)d_in[11];
  const float* b_pn1   = (const float*)d_in[12];
  const float* W_pn2   = (const float*)d_in[13];
  const float* b_pn2   = (const float*)d_in[14];
  const float* W_n1    = (const float*)d_in[15];
  const float* b_n1    = (const float*)d_in[16];
  const float* W_n2    = (const float*)d_in[17];
  const float* b_n2    = (const float*)d_in[18];
  const float* W_c1    = (const float*)d_in[19];
  const float* b_c1    = (const float*)d_in[20];
  const float* W_c2    = (const float*)d_in[21];
  const float* b_c2    = (const float*)d_in[22];

  char* ws = (char*)d_ws;
  size_t o = 0;
  auto take = [&](size_t bytes) {
    void* p = ws + o;
    o = (o + bytes + 255) & ~(size_t)255;
    return p;
  };
  int* deg    = (int*)take((size_t)N_NODES * 4);
  int* off    = (int*)take((size_t)(N_NODES + 1) * 4);
  int* cur    = (int*)take((size_t)N_NODES * 4);
  int* eperm  = (int*)take((size_t)N_EDGES * 4);
  float* d_arr = (float*)take((size_t)N_EDGES * 4);
  float* xmx   = (float*)take((size_t)N_EDGES * 12);
  float* sl    = (float*)take((size_t)N_EDGES * 4);
  float* coef  = (float*)take((size_t)N_EDGES * 4);
  short* he   = (short*)take((size_t)N_EDGES * 64 * 2);
  short* how  = (short*)take((size_t)N_EDGES * 32 * 2);
  float* hagg = (float*)take((size_t)N_NODES * 64 * 4);
  float* nrm  = (float*)take((size_t)N_NODES * 32 * 4);
  short* WcfinT = (short*)take((size_t)64 * 128 * 2);
  short* WcffT  = (short*)take((size_t)64 * 64 * 2);
  short* WewT   = (short*)take((size_t)32 * 192 * 2);
  short* Wc1T   = (short*)take((size_t)64 * 64 * 2);
  short* h_bf   = (short*)take((size_t)N_NODES * 64 * 2);

  float* h_out = (float*)d_out;
  float* x_out = h_out + (size_t)N_NODES * 64;

  hipMemsetAsync(deg, 0, (size_t)N_NODES * 4, stream);
  hipMemsetAsync(cur, 0, (size_t)N_NODES * 4, stream);

  hist_kernel<<<N_EDGES / 256, 256, 0, stream>>>(dst, deg);
  scan_kernel<<<1, 1024, 0, stream>>>(deg, off, N_NODES);
  scatter_kernel<<<N_EDGES / 256, 256, 0, stream>>>(dst, off, cur, eperm);
  prep_kernel<<<32, 256, 0, stream>>>(W_cf_in, W_cf_f, W_ew, W_c1, h,
                                      WcfinT, WcffT, WewT, Wc1T, h_bf);

  edge_kernel<<<N_EDGES / 64, 256, 0, stream>>>(
      h_bf, x, src, dst, eperm,
      WcfinT, b_cf_in, WcffT, b_cf_f, W_sem,
      WewT, b_ew, Wc1T, b_c1, W_c2, b_c2,
      d_arr, xmx, sl, coef, he, how);

  node_agg_kernel<<<N_NODES / 4, 256, 0, stream>>>(
      off, d_arr, sl, he, coef, xmx, how, x, hagg, nrm, x_out);

  node_mlp_kernel<<<N_NODES / 4, 256, 0, stream>>>(
      h, hagg, nrm,
      W_pn1, b_pn1, W_pn2, b_pn2,
      W_n1, b_n1, W_n2, b_n2,
      h_out);
}

// Round 7
// 659.171 us; speedup vs baseline: 26.8748x; 1.4785x over previous
//
#include <hip/hip_runtime.h>
#include <hip/hip_bf16.h>

#define N_NODES 50000
#define N_EDGES 800000
#define SCAN_B 196

typedef short s16x8 __attribute__((ext_vector_type(8)));
typedef float f32x4 __attribute__((ext_vector_type(4)));

__device__ __forceinline__ float silu_f(float v) {
  return v / (1.0f + __expf(-v));
}
__device__ __forceinline__ float tanh_f(float v) {
  // 1 - 2/(e^{2v}+1): robust at +-large (inf -> 1, 0 -> -1)
  return 1.0f - 2.0f / (__expf(2.0f * v) + 1.0f);
}
__device__ __forceinline__ unsigned short f2bf(float f) {
  union { __hip_bfloat16 b; unsigned short u; } cv;
  cv.b = __float2bfloat16(f);
  return cv.u;
}
__device__ __forceinline__ float bf2f(short s) {
  union { unsigned u; float f; } a; a.u = ((unsigned)(unsigned short)s) << 16;
  return a.f;
}

// ---------------- CSR build ----------------
__global__ void hist_kernel(const int* __restrict__ dst, int* __restrict__ deg) {
  int i = blockIdx.x * 256 + threadIdx.x;
  if (i < N_EDGES) atomicAdd(&deg[dst[i]], 1);
}

__global__ __launch_bounds__(256) void scanA_kernel(const int* __restrict__ deg,
                                                    int* __restrict__ bsum) {
  int i = blockIdx.x * 256 + threadIdx.x;
  int lane = threadIdx.x & 63, w = threadIdx.x >> 6;
  int v = (i < N_NODES) ? deg[i] : 0;
  #pragma unroll
  for (int o = 32; o > 0; o >>= 1) v += __shfl_xor(v, o, 64);
  __shared__ int ws_[4];
  if (lane == 0) ws_[w] = v;
  __syncthreads();
  if (threadIdx.x == 0) bsum[blockIdx.x] = ws_[0] + ws_[1] + ws_[2] + ws_[3];
}

__global__ void scanB_kernel(const int* __restrict__ bsum, int* __restrict__ bpre) {
  int lane = threadIdx.x;   // one wave of 64
  int carry = 0;
  for (int base = 0; base < SCAN_B; base += 64) {
    int i = base + lane;
    int v = (i < SCAN_B) ? bsum[i] : 0;
    int sv = v;
    #pragma unroll
    for (int o = 1; o < 64; o <<= 1) {
      int u = __shfl_up(sv, o, 64);
      if (lane >= o) sv += u;
    }
    if (i < SCAN_B) bpre[i] = carry + sv - v;   // exclusive prefix
    carry += __shfl(sv, 63, 64);
  }
}

__global__ __launch_bounds__(256) void scanC_kernel(const int* __restrict__ deg,
                                                    const int* __restrict__ bpre,
                                                    int* __restrict__ off) {
  int i = blockIdx.x * 256 + threadIdx.x;
  int lane = threadIdx.x & 63, w = threadIdx.x >> 6;
  int v = (i < N_NODES) ? deg[i] : 0;
  int sv = v;
  #pragma unroll
  for (int o = 1; o < 64; o <<= 1) {
    int u = __shfl_up(sv, o, 64);
    if (lane >= o) sv += u;
  }
  __shared__ int ws_[4], wp_[4];
  if (lane == 63) ws_[w] = sv;
  __syncthreads();
  if (threadIdx.x == 0) {
    int s = 0;
    #pragma unroll
    for (int j = 0; j < 4; ++j) { wp_[j] = s; s += ws_[j]; }
  }
  __syncthreads();
  if (i < N_NODES) off[i + 1] = bpre[blockIdx.x] + wp_[w] + sv;
  if (i == 0) off[0] = 0;
}

__global__ void scatter_kernel(const int* __restrict__ dst, const int* __restrict__ off,
                               int* __restrict__ cur, int* __restrict__ eperm) {
  int i = blockIdx.x * 256 + threadIdx.x;
  if (i < N_EDGES) {
    int dn = dst[i];
    int pos = atomicAdd(&cur[dn], 1);
    eperm[off[dn] + pos] = i;
  }
}

// -------- weight prep: f32 -> bf16 transposed [N][K]; h -> bf16 rows --------
__global__ void prep_kernel(const float* __restrict__ Wcfin, const float* __restrict__ Wcff,
                            const float* __restrict__ Wew, const float* __restrict__ Wc1,
                            const float* __restrict__ Wpn1, const float* __restrict__ Wpn2,
                            const float* __restrict__ Wn1, const float* __restrict__ Wn2,
                            const float* __restrict__ h,
                            short* __restrict__ WcfinT, short* __restrict__ WcffT,
                            short* __restrict__ WewT, short* __restrict__ Wc1T,
                            short* __restrict__ Wpn1T, short* __restrict__ Wpn2T,
                            short* __restrict__ Wn1T, short* __restrict__ Wn2T,
                            short* __restrict__ h_bf) {
  int t = blockIdx.x * 256 + threadIdx.x;
  int stride = gridDim.x * 256;
  for (int i = t; i < 64 * 128; i += stride) {
    int n = i >> 7, k = i & 127;
    WcfinT[i] = (short)f2bf(Wcfin[k * 64 + n]);
  }
  for (int i = t; i < 64 * 64; i += stride) {
    int n = i >> 6, k = i & 63;
    WcffT[i] = (k < 50) ? (short)f2bf(Wcff[k * 64 + n]) : (short)0;
  }
  for (int i = t; i < 32 * 192; i += stride) {
    int n = i / 192, k = i - n * 192;
    WewT[i] = (short)f2bf(Wew[k * 32 + n]);
  }
  for (int i = t; i < 64 * 64; i += stride) {
    int n = i >> 6, k = i & 63;
    Wc1T[i] = (short)f2bf(Wc1[k * 64 + n]);
  }
  for (int i = t; i < 64 * 32; i += stride) {
    int n = i >> 5, k = i & 31;
    Wpn1T[i] = (short)f2bf(Wpn1[k * 64 + n]);
  }
  for (int i = t; i < 64 * 64; i += stride) {
    int n = i >> 6, k = i & 63;
    Wpn2T[i] = (short)f2bf(Wpn2[k * 64 + n]);
  }
  for (int i = t; i < 64 * 192; i += stride) {
    int n = i / 192, k = i - n * 192;
    Wn1T[i] = (short)f2bf(Wn1[k * 64 + n]);
  }
  for (int i = t; i < 64 * 64; i += stride) {
    int n = i >> 6, k = i & 63;
    Wn2T[i] = (short)f2bf(Wn2[k * 64 + n]);
  }
  for (int i = t; i < (N_NODES * 64) / 4; i += stride) {
    float4 v = reinterpret_cast<const float4*>(h)[i];
    ushort4 u;
    u.x = f2bf(v.x); u.y = f2bf(v.y); u.z = f2bf(v.z); u.w = f2bf(v.w);
    reinterpret_cast<ushort4*>(h_bf)[i] = u;
  }
}

// ------- MFMA edge kernel: 64 edges / block, 4 independent waves, no barriers -------
// LDS 26624 B -> 6 blocks/CU. he_s aliased into hcat's dead wave-slice,
// 'how' aliased into rbf's dead wave-slice (all wave-local, DS in-order per wave).
__global__ __launch_bounds__(256) void edge_kernel(
    const short* __restrict__ h_bf, const float* __restrict__ x,
    const int* __restrict__ src, const int* __restrict__ dst,
    const int* __restrict__ eperm,
    const short* __restrict__ WcfinT, const float* __restrict__ b_cf_in,
    const short* __restrict__ WcffT, const float* __restrict__ b_cf_f,
    const float* __restrict__ W_sem,
    const short* __restrict__ WewT, const float* __restrict__ b_ew,
    const short* __restrict__ Wc1T, const float* __restrict__ b_c1,
    const float* __restrict__ W_c2, const float* __restrict__ b_c2,
    float* __restrict__ d_arr, float* __restrict__ xmx_arr,
    float* __restrict__ sl_arr, float* __restrict__ coef_arr,
    short* __restrict__ he_g, short* __restrict__ how_g)
{
  __shared__ short hcat[64][136];   // phase A: h_cat; phase B: per-wave he_s alias
  __shared__ short rbf_s[64][72];   // phase A: rbf;   phase B: per-wave how alias

  const int t = threadIdx.x;
  const int p0 = blockIdx.x * 64;
  const int le = t >> 2, q = t & 3;   // 4 threads per edge
  const int p_edge = p0 + le;

  const int e = eperm[p_edge];
  const int sn = src[e], dn = dst[e];

  // ---- geometry ----
  float mx0 = x[sn * 3 + 0] - x[dn * 3 + 0];
  float mx1 = x[sn * 3 + 1] - x[dn * 3 + 1];
  float mx2 = x[sn * 3 + 2] - x[dn * 3 + 2];
  float d = sqrtf(mx0 * mx0 + mx1 * mx1 + mx2 * mx2 + 1e-5f);
  if (q == 0) {
    d_arr[p_edge] = d;
    xmx_arr[p_edge * 3 + 0] = mx0;
    xmx_arr[p_edge * 3 + 1] = mx1;
    xmx_arr[p_edge * 3 + 2] = mx2;
  }

  // ---- stage h_cat (bf16 gather) + fused sem logit ----
  {
    int node = (q < 2) ? sn : dn;
    const s16x8* hrow = reinterpret_cast<const s16x8*>(h_bf + (size_t)node * 64 + (q & 1) * 32);
    const float* wsm = W_sem + q * 32;
    float psem = 0.f;
    #pragma unroll
    for (int u = 0; u < 4; ++u) {
      s16x8 v = hrow[u];
      *reinterpret_cast<s16x8*>(&hcat[le][q * 32 + u * 8]) = v;
      float4 w0 = *reinterpret_cast<const float4*>(wsm + u * 8);
      float4 w1 = *reinterpret_cast<const float4*>(wsm + u * 8 + 4);
      psem += bf2f(v[0]) * w0.x + bf2f(v[1]) * w0.y + bf2f(v[2]) * w0.z + bf2f(v[3]) * w0.w
            + bf2f(v[4]) * w1.x + bf2f(v[5]) * w1.y + bf2f(v[6]) * w1.z + bf2f(v[7]) * w1.w;
    }
    psem += __shfl_xor(psem, 1, 64);
    psem += __shfl_xor(psem, 2, 64);
    if (q == 0) sl_arr[p_edge] = silu_f(psem);
  }

  // ---- RBF (bf16): q covers k = q*16 .. q*16+15 ----
  {
    int kb = q * 16;
    s16x8 lo, hi;
    #pragma unroll 16
    for (int u = 0; u < 16; ++u) {
      int k = kb + u;
      float mu = (float)k * (5.0f / 49.0f);
      float dd = d - mu;
      float val = (k < 50) ? __expf(-10.0f * dd * dd) : 0.0f;
      short sv = (short)f2bf(val);
      if (u < 8) lo[u] = sv; else hi[u - 8] = sv;
    }
    *reinterpret_cast<s16x8*>(&rbf_s[le][kb]) = lo;
    *reinterpret_cast<s16x8*>(&rbf_s[le][kb + 8]) = hi;
  }

  const int w = t >> 6, lane = t & 63;
  const int lr = lane & 15, lg = lane >> 4;
  const int arow = w * 16 + lr;
  const int k8 = lg * 8;
  const f32x4 z = {0.f, 0.f, 0.f, 0.f};

  // ---- phase A: all hcat/rbf-consuming MFMAs ----
  f32x4 acc[4] = {z, z, z, z};
  f32x4 fac[4] = {z, z, z, z};
  f32x4 ew[2] = {z, z};
  #pragma unroll
  for (int kb = 0; kb < 128; kb += 32) {
    s16x8 a = *reinterpret_cast<const s16x8*>(&hcat[arow][kb + k8]);
    #pragma unroll
    for (int j = 0; j < 4; ++j) {
      s16x8 b = *reinterpret_cast<const s16x8*>(&WcfinT[(j * 16 + lr) * 128 + kb + k8]);
      acc[j] = __builtin_amdgcn_mfma_f32_16x16x32_bf16(a, b, acc[j], 0, 0, 0);
    }
    #pragma unroll
    for (int j = 0; j < 2; ++j) {
      s16x8 b = *reinterpret_cast<const s16x8*>(&WewT[(j * 16 + lr) * 192 + kb + k8]);
      ew[j] = __builtin_amdgcn_mfma_f32_16x16x32_bf16(a, b, ew[j], 0, 0, 0);
    }
  }
  #pragma unroll
  for (int kb = 0; kb < 64; kb += 32) {
    s16x8 a = *reinterpret_cast<const s16x8*>(&rbf_s[arow][kb + k8]);
    #pragma unroll
    for (int j = 0; j < 4; ++j) {
      s16x8 b = *reinterpret_cast<const s16x8*>(&WcffT[(j * 16 + lr) * 64 + kb + k8]);
      fac[j] = __builtin_amdgcn_mfma_f32_16x16x32_bf16(a, b, fac[j], 0, 0, 0);
    }
  }

  // he_s alias: inside this wave's dead hcat slice (16 rows x 72 shorts)
  short* he_base = &hcat[w * 16][0];
  #define HEP(riw) (he_base + (riw) * 72)
  // how alias: inside this wave's dead rbf slice (16 rows x 40 shorts)
  short* how_base = &rbf_s[w * 16][0];
  #define HOWP(riw) (how_base + (riw) * 40)

  // ---- epilogue: h_e = (lin + b) * silu(filt + b) -> he alias ----
  #pragma unroll
  for (int j = 0; j < 4; ++j) {
    int col = j * 16 + lr;
    float bi = b_cf_in[col], bf_ = b_cf_f[col];
    #pragma unroll
    for (int r = 0; r < 4; ++r) {
      float he = (acc[j][r] + bi) * silu_f(fac[j][r] + bf_);
      HEP(lg * 4 + r)[col] = (short)f2bf(he);
    }
  }

  // ---- copy he -> global (own-wave rows, coalesced) ----
  #pragma unroll
  for (int u = 0; u < 2; ++u) {
    int chunk = lane + u * 64;                  // 0..127
    int riw = chunk >> 3, col8 = (chunk & 7) * 8;
    s16x8 v = *reinterpret_cast<const s16x8*>(HEP(riw) + col8);
    *reinterpret_cast<s16x8*>(&he_g[((size_t)(p0 + w * 16 + riw)) * 64 + col8]) = v;
  }

  // ---- ew part 2 (he columns of W_ew) + tanh -> how alias ----
  #pragma unroll
  for (int kb = 0; kb < 64; kb += 32) {
    s16x8 a = *reinterpret_cast<const s16x8*>(HEP(lr) + kb + k8);
    #pragma unroll
    for (int j = 0; j < 2; ++j) {
      s16x8 b = *reinterpret_cast<const s16x8*>(&WewT[(j * 16 + lr) * 192 + 128 + kb + k8]);
      ew[j] = __builtin_amdgcn_mfma_f32_16x16x32_bf16(a, b, ew[j], 0, 0, 0);
    }
  }
  #pragma unroll
  for (int j = 0; j < 2; ++j) {
    int col = j * 16 + lr;
    float be = b_ew[col];
    #pragma unroll
    for (int r = 0; r < 4; ++r)
      HOWP(lg * 4 + r)[col] = (short)f2bf(tanh_f(ew[j][r] + be));
  }

  // ---- coef: silu(h_e @ W_c1 + b) @ W_c2 + b ----
  {
    f32x4 c[4] = {z, z, z, z};
    #pragma unroll
    for (int kb = 0; kb < 64; kb += 32) {
      s16x8 a = *reinterpret_cast<const s16x8*>(HEP(lr) + kb + k8);
      #pragma unroll
      for (int j = 0; j < 4; ++j) {
        s16x8 b = *reinterpret_cast<const s16x8*>(&Wc1T[(j * 16 + lr) * 64 + kb + k8]);
        c[j] = __builtin_amdgcn_mfma_f32_16x16x32_bf16(a, b, c[j], 0, 0, 0);
      }
    }
    float p[4] = {0.f, 0.f, 0.f, 0.f};
    #pragma unroll
    for (int j = 0; j < 4; ++j) {
      int col = j * 16 + lr;
      float bc = b_c1[col], wc = W_c2[col];
      #pragma unroll
      for (int r = 0; r < 4; ++r) p[r] += silu_f(c[j][r] + bc) * wc;
    }
    #pragma unroll
    for (int r = 0; r < 4; ++r) {
      p[r] += __shfl_xor(p[r], 1, 64);
      p[r] += __shfl_xor(p[r], 2, 64);
      p[r] += __shfl_xor(p[r], 4, 64);
      p[r] += __shfl_xor(p[r], 8, 64);
    }
    if (lr == 0) {
      float bc2 = b_c2[0];
      #pragma unroll
      for (int r = 0; r < 4; ++r)
        coef_arr[p0 + w * 16 + lg * 4 + r] = p[r] + bc2;
    }
  }

  // ---- copy how -> global (own-wave rows, coalesced) ----
  {
    int riw = lane >> 2, col8 = (lane & 3) * 8;
    s16x8 v = *reinterpret_cast<const s16x8*>(HOWP(riw) + col8);
    *reinterpret_cast<s16x8*>(&how_g[((size_t)(p0 + w * 16 + riw)) * 32 + col8]) = v;
  }
  #undef HEP
  #undef HOWP
}

// ------- fused per-node kernel: dual softmax, h_agg(bf16), x_new, nrm(bf16) -------
__global__ __launch_bounds__(256) void node_agg_kernel(
    const int* __restrict__ off, const float* __restrict__ d_arr,
    const float* __restrict__ sl_arr, const short* __restrict__ he_g,
    const float* __restrict__ coef_arr, const float* __restrict__ xmx_arr,
    const short* __restrict__ how_g, const float* __restrict__ x,
    short* __restrict__ hagg_bf, short* __restrict__ nrm_bf,
    float* __restrict__ x_out)
{
  int w = threadIdx.x >> 6, lane = threadIdx.x & 63;
  int n = blockIdx.x * 4 + w;
  if (n >= N_NODES) return;
  int b = off[n], e = off[n + 1];

  float s1 = 0.f, s2 = 0.f;
  for (int p = b + lane; p < e; p += 64) {
    s1 += __expf(-d_arr[p]);
    s2 += __expf(sl_arr[p]);
  }
  #pragma unroll
  for (int o = 32; o > 0; o >>= 1) { s1 += __shfl_xor(s1, o, 64); s2 += __shfl_xor(s2, o, 64); }
  float r1 = 1.f / s1, r2 = 1.f / s2;

  float s3 = 0.f;
  for (int p = b + lane; p < e; p += 64) {
    float l3 = (__expf(-d_arr[p]) * r1) * (__expf(sl_arr[p]) * r2);
    s3 += __expf(l3);
  }
  #pragma unroll
  for (int o = 32; o > 0; o >>= 1) s3 += __shfl_xor(s3, o, 64);
  float inv3 = 1.f / s3;

  float acc = 0.f;
  float xv = (lane < 3) ? x[n * 3 + lane] : 0.f;
  for (int p = b; p < e; ++p) {
    float l3 = (__expf(-d_arr[p]) * r1) * (__expf(sl_arr[p]) * r2);
    float tot = __expf(l3) * inv3;
    acc += tot * bf2f(he_g[(size_t)p * 64 + lane]);
    if (lane < 3) xv += xmx_arr[p * 3 + lane] * coef_arr[p];
  }
  hagg_bf[(size_t)n * 64 + lane] = (short)f2bf(acc);
  if (lane < 3) x_out[n * 3 + lane] = xv;

  int c = lane & 31, par = lane >> 5;
  float a0 = 0.f, a1 = 0.f, a2 = 0.f;
  for (int p = b + par; p < e; p += 2) {
    float wv = bf2f(how_g[(size_t)p * 32 + c]);
    float dd = d_arr[p];
    float s = wv / (dd * dd);
    a0 += s * xmx_arr[p * 3 + 0];
    a1 += s * xmx_arr[p * 3 + 1];
    a2 += s * xmx_arr[p * 3 + 2];
  }
  a0 += __shfl_xor(a0, 32, 64);
  a1 += __shfl_xor(a1, 32, 64);
  a2 += __shfl_xor(a2, 32, 64);
  if (lane < 32)
    nrm_bf[(size_t)n * 32 + c] =
        (short)f2bf(sqrtf(fmaxf(a0 * a0 + a1 * a1 + a2 * a2, 0.f) + 1e-5f));
}

// ---------- MFMA node MLP: 64 nodes / block, 4 waves, wave-local ----------
__global__ __launch_bounds__(256) void node_mlp_kernel(
    const short* __restrict__ h_bf, const short* __restrict__ hagg_bf,
    const short* __restrict__ nrm_bf,
    const short* __restrict__ Wpn1T, const float* __restrict__ b_pn1,
    const short* __restrict__ Wpn2T, const float* __restrict__ b_pn2,
    const short* __restrict__ Wn1T, const float* __restrict__ b_n1,
    const short* __restrict__ Wn2T, const float* __restrict__ b_n2,
    float* __restrict__ h_out)
{
  __shared__ short cat[64][200];   // [h | hagg | emb], +8 pad
  __shared__ short tbuf[64][72];   // nrm(cols 0..31) -> t1 -> t2 (wave-local alias)

  const int t = threadIdx.x;
  const int w = t >> 6, lane = t & 63;
  const int n0 = blockIdx.x * 64;
  const int rbase = w * 16;

  // ---- wave-local staging ----
  #pragma unroll
  for (int u = 0; u < 2; ++u) {
    int c = lane + u * 64;            // 0..127 -> 16 rows x 8 chunks
    int riw = c >> 3, col8 = (c & 7) * 8;
    int node = n0 + rbase + riw; if (node >= N_NODES) node = N_NODES - 1;
    *reinterpret_cast<s16x8*>(&cat[rbase + riw][col8]) =
        *reinterpret_cast<const s16x8*>(&h_bf[(size_t)node * 64 + col8]);
    *reinterpret_cast<s16x8*>(&cat[rbase + riw][64 + col8]) =
        *reinterpret_cast<const s16x8*>(&hagg_bf[(size_t)node * 64 + col8]);
  }
  {
    int riw = lane >> 2, col8 = (lane & 3) * 8;
    int node = n0 + rbase + riw; if (node >= N_NODES) node = N_NODES - 1;
    *reinterpret_cast<s16x8*>(&tbuf[rbase + riw][col8]) =
        *reinterpret_cast<const s16x8*>(&nrm_bf[(size_t)node * 32 + col8]);
  }

  const int lr = lane & 15, lg = lane >> 4;
  const int arow = rbase + lr;
  const int k8 = lg * 8;
  const f32x4 z = {0.f, 0.f, 0.f, 0.f};

  // GEMM1: t1 = silu(nrm @ W_pn1 + b), K=32
  {
    f32x4 c1[4] = {z, z, z, z};
    s16x8 a = *reinterpret_cast<const s16x8*>(&tbuf[arow][k8]);
    #pragma unroll
    for (int j = 0; j < 4; ++j) {
      s16x8 b = *reinterpret_cast<const s16x8*>(&Wpn1T[(j * 16 + lr) * 32 + k8]);
      c1[j] = __builtin_amdgcn_mfma_f32_16x16x32_bf16(a, b, c1[j], 0, 0, 0);
    }
    #pragma unroll
    for (int j = 0; j < 4; ++j) {
      int col = j * 16 + lr; float bb = b_pn1[col];
      #pragma unroll
      for (int r = 0; r < 4; ++r)
        tbuf[rbase + lg * 4 + r][col] = (short)f2bf(silu_f(c1[j][r] + bb));
    }
  }
  // GEMM2: emb = t1 @ W_pn2 + b, K=64 -> cat cols 128..191
  {
    f32x4 c2[4] = {z, z, z, z};
    #pragma unroll
    for (int kb = 0; kb < 64; kb += 32) {
      s16x8 a = *reinterpret_cast<const s16x8*>(&tbuf[arow][kb + k8]);
      #pragma unroll
      for (int j = 0; j < 4; ++j) {
        s16x8 b = *reinterpret_cast<const s16x8*>(&Wpn2T[(j * 16 + lr) * 64 + kb + k8]);
        c2[j] = __builtin_amdgcn_mfma_f32_16x16x32_bf16(a, b, c2[j], 0, 0, 0);
      }
    }
    #pragma unroll
    for (int j = 0; j < 4; ++j) {
      int col = j * 16 + lr; float bb = b_pn2[col];
      #pragma unroll
      for (int r = 0; r < 4; ++r)
        cat[rbase + lg * 4 + r][128 + col] = (short)f2bf(c2[j][r] + bb);
    }
  }
  // GEMM3: t2 = silu([h|hagg|emb] @ W_n1 + b), K=192
  {
    f32x4 c3[4] = {z, z, z, z};
    #pragma unroll
    for (int kb = 0; kb < 192; kb += 32) {
      s16x8 a = *reinterpret_cast<const s16x8*>(&cat[arow][kb + k8]);
      #pragma unroll
      for (int j = 0; j < 4; ++j) {
        s16x8 b = *reinterpret_cast<const s16x8*>(&Wn1T[(j * 16 + lr) * 192 + kb + k8]);
        c3[j] = __builtin_amdgcn_mfma_f32_16x16x32_bf16(a, b, c3[j], 0, 0, 0);
      }
    }
    #pragma unroll
    for (int j = 0; j < 4; ++j) {
      int col = j * 16 + lr; float bb = b_n1[col];
      #pragma unroll
      for (int r = 0; r < 4; ++r)
        tbuf[rbase + lg * 4 + r][col] = (short)f2bf(silu_f(c3[j][r] + bb));
    }
  }
  // GEMM4: h_out = t2 @ W_n2 + b, K=64, f32 store
  {
    f32x4 c4[4] = {z, z, z, z};
    #pragma unroll
    for (int kb = 0; kb < 64; kb += 32) {
      s16x8 a = *reinterpret_cast<const s16x8*>(&tbuf[arow][kb + k8]);
      #pragma unroll
      for (int j = 0; j < 4; ++j) {
        s16x8 b = *reinterpret_cast<const s16x8*>(&Wn2T[(j * 16 + lr) * 64 + kb + k8]);
        c4[j] = __builtin_amdgcn_mfma_f32_16x16x32_bf16(a, b, c4[j], 0, 0, 0);
      }
    }
    #pragma unroll
    for (int j = 0; j < 4; ++j) {
      int col = j * 16 + lr; float bb = b_n2[col];
      #pragma unroll
      for (int r = 0; r < 4; ++r) {
        int node = n0 + rbase + lg * 4 + r;
        if (node < N_NODES) h_out[(size_t)node * 64 + col] = c4[j][r] + bb;
      }
    }
  }
}

// ---------------- launch ----------------
extern "C" void kernel_launch(void* const* d_in, const int* in_sizes, int n_in,
                              void* d_out, int out_size, void* d_ws, size_t ws_size,
                              hipStream_t stream) {
  const float* h      = (const float*)d_in[0];
  const float* x      = (const float*)d_in[1];
  const int*   src    = (const int*)d_in[2];
  const int*   dst    = (const int*)d_in[3];
  const float* W_cf_in = (const float*)d_in[4];
  const float* b_cf_in = (const float*)d_in[5];
  const float* W_cf_f  = (const float*)d_in[6];
  const float* b_cf_f  = (const float*)d_in[7];
  const float* W_sem   = (const float*)d_in[8];
  const float* W_ew    = (const float*)d_in[9];
  const float* b_ew    = (const float*)d_in[10];
  const float* W_pn1   = (const float*)d_in[11];
  const float* b_pn1   = (const float*)d_in[12];
  const float* W_pn2   = (const float*)d_in[13];
  const float* b_pn2   = (const float*)d_in[14];
  const float* W_n1    = (const float*)d_in[15];
  const float* b_n1    = (const float*)d_in[16];
  const float* W_n2    = (const float*)d_in[17];
  const float* b_n2    = (const float*)d_in[18];
  const float* W_c1    = (const float*)d_in[19];
  const float* b_c1    = (const float*)d_in[20];
  const float* W_c2    = (const float*)d_in[21];
  const float* b_c2    = (const float*)d_in[22];

  char* ws = (char*)d_ws;
  size_t o = 0;
  auto take = [&](size_t bytes) {
    void* p = ws + o;
    o = (o + bytes + 255) & ~(size_t)255;
    return p;
  };
  int* deg    = (int*)take((size_t)N_NODES * 4);
  int* off    = (int*)take((size_t)(N_NODES + 1) * 4);
  int* cur    = (int*)take((size_t)N_NODES * 4);
  int* eperm  = (int*)take((size_t)N_EDGES * 4);
  int* bsum   = (int*)take((size_t)SCAN_B * 4);
  int* bpre   = (int*)take((size_t)SCAN_B * 4);
  float* d_arr = (float*)take((size_t)N_EDGES * 4);
  float* xmx   = (float*)take((size_t)N_EDGES * 12);
  float* sl    = (float*)take((size_t)N_EDGES * 4);
  float* coef  = (float*)take((size_t)N_EDGES * 4);
  short* he   = (short*)take((size_t)N_EDGES * 64 * 2);
  short* how  = (short*)take((size_t)N_EDGES * 32 * 2);
  short* hagg_bf = (short*)take((size_t)N_NODES * 64 * 2);
  short* nrm_bf  = (short*)take((size_t)N_NODES * 32 * 2);
  short* WcfinT = (short*)take((size_t)64 * 128 * 2);
  short* WcffT  = (short*)take((size_t)64 * 64 * 2);
  short* WewT   = (short*)take((size_t)32 * 192 * 2);
  short* Wc1T   = (short*)take((size_t)64 * 64 * 2);
  short* Wpn1T  = (short*)take((size_t)64 * 32 * 2);
  short* Wpn2T  = (short*)take((size_t)64 * 64 * 2);
  short* Wn1T   = (short*)take((size_t)64 * 192 * 2);
  short* Wn2T   = (short*)take((size_t)64 * 64 * 2);
  short* h_bf   = (short*)take((size_t)N_NODES * 64 * 2);

  float* h_out = (float*)d_out;
  float* x_out = h_out + (size_t)N_NODES * 64;

  hipMemsetAsync(deg, 0, (size_t)N_NODES * 4, stream);
  hipMemsetAsync(cur, 0, (size_t)N_NODES * 4, stream);

  hist_kernel<<<N_EDGES / 256, 256, 0, stream>>>(dst, deg);
  scanA_kernel<<<SCAN_B, 256, 0, stream>>>(deg, bsum);
  scanB_kernel<<<1, 64, 0, stream>>>(bsum, bpre);
  scanC_kernel<<<SCAN_B, 256, 0, stream>>>(deg, bpre, off);
  scatter_kernel<<<N_EDGES / 256, 256, 0, stream>>>(dst, off, cur, eperm);
  prep_kernel<<<32, 256, 0, stream>>>(W_cf_in, W_cf_f, W_ew, W_c1,
                                      W_pn1, W_pn2, W_n1, W_n2, h,
                                      WcfinT, WcffT, WewT, Wc1T,
                                      Wpn1T, Wpn2T, Wn1T, Wn2T, h_bf);

  edge_kernel<<<N_EDGES / 64, 256, 0, stream>>>(
      h_bf, x, src, dst, eperm,
      WcfinT, b_cf_in, WcffT, b_cf_f, W_sem,
      WewT, b_ew, Wc1T, b_c1, W_c2, b_c2,
      d_arr, xmx, sl, coef, he, how);

  node_agg_kernel<<<N_NODES / 4, 256, 0, stream>>>(
      off, d_arr, sl, he, coef, xmx, how, x, hagg_bf, nrm_bf, x_out);

  node_mlp_kernel<<<(N_NODES + 63) / 64, 256, 0, stream>>>(
      h_bf, hagg_bf, nrm_bf,
      Wpn1T, b_pn1, Wpn2T, b_pn2,
      Wn1T, b_n1, Wn2T, b_n2,
      h_out);
}

// Round 8
// 513.872 us; speedup vs baseline: 34.4737x; 1.2828x over previous
//
#include <hip/hip_runtime.h>
#include <hip/hip_bf16.h>

#define N_NODES 50000
#define N_EDGES 800000
#define SCAN_B 196

typedef short s16x8 __attribute__((ext_vector_type(8)));
typedef float f32x4 __attribute__((ext_vector_type(4)));

__device__ __forceinline__ float silu_f(float v) {
  return v / (1.0f + __expf(-v));
}
__device__ __forceinline__ float tanh_f(float v) {
  return 1.0f - 2.0f / (__expf(2.0f * v) + 1.0f);
}
__device__ __forceinline__ unsigned short f2bf(float f) {
  union { __hip_bfloat16 b; unsigned short u; } cv;
  cv.b = __float2bfloat16(f);
  return cv.u;
}
__device__ __forceinline__ float bf2f(short s) {
  union { unsigned u; float f; } a; a.u = ((unsigned)(unsigned short)s) << 16;
  return a.f;
}

// ---------------- CSR build ----------------
__global__ void hist_kernel(const int* __restrict__ dst, int* __restrict__ deg) {
  int i = blockIdx.x * 256 + threadIdx.x;
  if (i < N_EDGES) atomicAdd(&deg[dst[i]], 1);
}

__global__ __launch_bounds__(256) void scanA_kernel(const int* __restrict__ deg,
                                                    int* __restrict__ bsum) {
  int i = blockIdx.x * 256 + threadIdx.x;
  int lane = threadIdx.x & 63, w = threadIdx.x >> 6;
  int v = (i < N_NODES) ? deg[i] : 0;
  #pragma unroll
  for (int o = 32; o > 0; o >>= 1) v += __shfl_xor(v, o, 64);
  __shared__ int ws_[4];
  if (lane == 0) ws_[w] = v;
  __syncthreads();
  if (threadIdx.x == 0) bsum[blockIdx.x] = ws_[0] + ws_[1] + ws_[2] + ws_[3];
}

__global__ void scanB_kernel(const int* __restrict__ bsum, int* __restrict__ bpre) {
  int lane = threadIdx.x;   // one wave of 64
  int carry = 0;
  for (int base = 0; base < SCAN_B; base += 64) {
    int i = base + lane;
    int v = (i < SCAN_B) ? bsum[i] : 0;
    int sv = v;
    #pragma unroll
    for (int o = 1; o < 64; o <<= 1) {
      int u = __shfl_up(sv, o, 64);
      if (lane >= o) sv += u;
    }
    if (i < SCAN_B) bpre[i] = carry + sv - v;   // exclusive prefix
    carry += __shfl(sv, 63, 64);
  }
}

__global__ __launch_bounds__(256) void scanC_kernel(const int* __restrict__ deg,
                                                    const int* __restrict__ bpre,
                                                    int* __restrict__ off) {
  int i = blockIdx.x * 256 + threadIdx.x;
  int lane = threadIdx.x & 63, w = threadIdx.x >> 6;
  int v = (i < N_NODES) ? deg[i] : 0;
  int sv = v;
  #pragma unroll
  for (int o = 1; o < 64; o <<= 1) {
    int u = __shfl_up(sv, o, 64);
    if (lane >= o) sv += u;
  }
  __shared__ int ws_[4], wp_[4];
  if (lane == 63) ws_[w] = sv;
  __syncthreads();
  if (threadIdx.x == 0) {
    int s = 0;
    #pragma unroll
    for (int j = 0; j < 4; ++j) { wp_[j] = s; s += ws_[j]; }
  }
  __syncthreads();
  if (i < N_NODES) off[i + 1] = bpre[blockIdx.x] + wp_[w] + sv;
  if (i == 0) off[0] = 0;
}

__global__ void scatter_kernel(const int* __restrict__ dst, const int* __restrict__ off,
                               int* __restrict__ cur, int* __restrict__ eperm) {
  int i = blockIdx.x * 256 + threadIdx.x;
  if (i < N_EDGES) {
    int dn = dst[i];
    int pos = atomicAdd(&cur[dn], 1);
    eperm[off[dn] + pos] = i;
  }
}

// -------- weight prep: bf16 transposed weights; h -> bf16 rows --------
// WpreT[224][64]: rows 0-111 = S-half [Wcfin_top | Wew_top | Wsem_top | 0],
//                 rows 112-223 = D-half [Wcfin_bot | Wew_bot | Wsem_bot | 0]
__global__ void prep_kernel(const float* __restrict__ Wcfin, const float* __restrict__ Wcff,
                            const float* __restrict__ Wew, const float* __restrict__ Wsem,
                            const float* __restrict__ Wc1,
                            const float* __restrict__ Wpn1, const float* __restrict__ Wpn2,
                            const float* __restrict__ Wn1, const float* __restrict__ Wn2,
                            const float* __restrict__ h,
                            short* __restrict__ WpreT, short* __restrict__ WcffT,
                            short* __restrict__ WewBT, short* __restrict__ Wc1T,
                            short* __restrict__ Wpn1T, short* __restrict__ Wpn2T,
                            short* __restrict__ Wn1T, short* __restrict__ Wn2T,
                            short* __restrict__ h_bf) {
  int t = blockIdx.x * 256 + threadIdx.x;
  int stride = gridDim.x * 256;
  for (int i = t; i < 224 * 64; i += stride) {
    int n = i >> 6, k = i & 63;
    int half = (n >= 112) ? 1 : 0;
    int c = n - half * 112;
    float v = 0.f;
    if (c < 64)       v = Wcfin[(half * 64 + k) * 64 + c];
    else if (c < 96)  v = Wew[(half * 64 + k) * 32 + (c - 64)];
    else if (c == 96) v = Wsem[half * 64 + k];
    WpreT[i] = (short)f2bf(v);
  }
  for (int i = t; i < 64 * 64; i += stride) {
    int n = i >> 6, k = i & 63;
    WcffT[i] = (k < 50) ? (short)f2bf(Wcff[k * 64 + n]) : (short)0;
  }
  for (int i = t; i < 32 * 64; i += stride) {
    int n = i >> 6, k = i & 63;
    WewBT[i] = (short)f2bf(Wew[(128 + k) * 32 + n]);
  }
  for (int i = t; i < 64 * 64; i += stride) {
    int n = i >> 6, k = i & 63;
    Wc1T[i] = (short)f2bf(Wc1[k * 64 + n]);
  }
  for (int i = t; i < 64 * 32; i += stride) {
    int n = i >> 5, k = i & 31;
    Wpn1T[i] = (short)f2bf(Wpn1[k * 64 + n]);
  }
  for (int i = t; i < 64 * 64; i += stride) {
    int n = i >> 6, k = i & 63;
    Wpn2T[i] = (short)f2bf(Wpn2[k * 64 + n]);
  }
  for (int i = t; i < 64 * 192; i += stride) {
    int n = i / 192, k = i - n * 192;
    Wn1T[i] = (short)f2bf(Wn1[k * 64 + n]);
  }
  for (int i = t; i < 64 * 64; i += stride) {
    int n = i >> 6, k = i & 63;
    Wn2T[i] = (short)f2bf(Wn2[k * 64 + n]);
  }
  for (int i = t; i < (N_NODES * 64) / 4; i += stride) {
    float4 v = reinterpret_cast<const float4*>(h)[i];
    ushort4 u;
    u.x = f2bf(v.x); u.y = f2bf(v.y); u.z = f2bf(v.z); u.w = f2bf(v.w);
    reinterpret_cast<ushort4*>(h_bf)[i] = u;
  }
}

// ---- per-node precompute: preS/preD[n][112] = h[n] @ [lin(64)|ew(32)|sem(1)|0] ----
__global__ __launch_bounds__(256) void pre_node_kernel(
    const short* __restrict__ h_bf, const short* __restrict__ WpreT,
    short* __restrict__ preS, short* __restrict__ preD)
{
  __shared__ short hs[64][72];
  const int t = threadIdx.x;
  const int w = t >> 6, lane = t & 63;
  const int n0 = blockIdx.x * 64;
  const int rbase = w * 16;

  #pragma unroll
  for (int u = 0; u < 2; ++u) {
    int c = lane + u * 64;            // 0..127
    int riw = c >> 3, col8 = (c & 7) * 8;
    int node = n0 + rbase + riw; if (node >= N_NODES) node = N_NODES - 1;
    *reinterpret_cast<s16x8*>(&hs[rbase + riw][col8]) =
        *reinterpret_cast<const s16x8*>(&h_bf[(size_t)node * 64 + col8]);
  }

  const int lr = lane & 15, lg = lane >> 4;
  const int arow = rbase + lr;
  const int k8 = lg * 8;
  const f32x4 z = {0.f, 0.f, 0.f, 0.f};

  #pragma unroll
  for (int half = 0; half < 2; ++half) {
    short* out = half ? preD : preS;
    #pragma unroll
    for (int j = 0; j < 7; ++j) {
      f32x4 acc = z;
      #pragma unroll
      for (int kb = 0; kb < 64; kb += 32) {
        s16x8 a = *reinterpret_cast<const s16x8*>(&hs[arow][kb + k8]);
        s16x8 b = *reinterpret_cast<const s16x8*>(&WpreT[(half * 112 + j * 16 + lr) * 64 + kb + k8]);
        acc = __builtin_amdgcn_mfma_f32_16x16x32_bf16(a, b, acc, 0, 0, 0);
      }
      #pragma unroll
      for (int r = 0; r < 4; ++r) {
        int node = n0 + rbase + lg * 4 + r;
        if (node < N_NODES) out[(size_t)node * 112 + j * 16 + lr] = (short)f2bf(acc[r]);
      }
    }
  }
}

// ------- MFMA edge kernel: 64 edges / block, 4 independent waves, no barriers -------
// Per-edge linear parts come from preS[src]+preD[dst] gathers; only the
// rbf-filter (K=64), ew-part2 (K=64) and c1 (K=64) GEMMs remain. LDS 23552 B.
__global__ __launch_bounds__(256) void edge_kernel(
    const float* __restrict__ x,
    const int* __restrict__ src, const int* __restrict__ dst,
    const int* __restrict__ eperm,
    const short* __restrict__ preS, const short* __restrict__ preD,
    const float* __restrict__ b_cf_in,
    const short* __restrict__ WcffT, const float* __restrict__ b_cf_f,
    const short* __restrict__ WewBT, const float* __restrict__ b_ew,
    const short* __restrict__ Wc1T, const float* __restrict__ b_c1,
    const float* __restrict__ W_c2, const float* __restrict__ b_c2,
    float* __restrict__ d_arr, float* __restrict__ xmx_arr,
    float* __restrict__ sl_arr, float* __restrict__ coef_arr,
    short* __restrict__ he_g, short* __restrict__ how_g)
{
  __shared__ short hlin[64][72];   // lin sums -> h_e written in place
  __shared__ short rbf_s[64][72];  // rbf
  __shared__ short ewsum[64][40];  // ew sums -> how written in place

  const int t = threadIdx.x;
  const int p0 = blockIdx.x * 64;
  const int le = t >> 2, q = t & 3;   // 4 threads per edge
  const int p_edge = p0 + le;

  const int e = eperm[p_edge];
  const int sn = src[e], dn = dst[e];

  // ---- geometry ----
  float mx0 = x[sn * 3 + 0] - x[dn * 3 + 0];
  float mx1 = x[sn * 3 + 1] - x[dn * 3 + 1];
  float mx2 = x[sn * 3 + 2] - x[dn * 3 + 2];
  float d = sqrtf(mx0 * mx0 + mx1 * mx1 + mx2 * mx2 + 1e-5f);
  if (q == 0) {
    d_arr[p_edge] = d;
    xmx_arr[p_edge * 3 + 0] = mx0;
    xmx_arr[p_edge * 3 + 1] = mx1;
    xmx_arr[p_edge * 3 + 2] = mx2;
  }

  // ---- gather preS[src]+preD[dst]: chunks 0-7 -> hlin, 8-11 -> ewsum, sem ----
  {
    const short* ps = preS + (size_t)sn * 112;
    const short* pd = preD + (size_t)dn * 112;
    #pragma unroll
    for (int ci = 0; ci < 3; ++ci) {
      int c = q * 3 + ci;               // 0..11
      s16x8 a = *reinterpret_cast<const s16x8*>(ps + c * 8);
      s16x8 b = *reinterpret_cast<const s16x8*>(pd + c * 8);
      s16x8 r;
      #pragma unroll
      for (int u = 0; u < 8; ++u) r[u] = (short)f2bf(bf2f(a[u]) + bf2f(b[u]));
      short* dstp = (c < 8) ? &hlin[le][c * 8] : &ewsum[le][(c - 8) * 8];
      *reinterpret_cast<s16x8*>(dstp) = r;
    }
    if (q == 3) {
      float sem = bf2f(ps[96]) + bf2f(pd[96]);
      sl_arr[p_edge] = silu_f(sem);
    }
  }

  // ---- RBF (bf16): q covers k = q*16 .. q*16+15 ----
  {
    int kb = q * 16;
    s16x8 lo, hi;
    #pragma unroll 16
    for (int u = 0; u < 16; ++u) {
      int k = kb + u;
      float mu = (float)k * (5.0f / 49.0f);
      float dd = d - mu;
      float val = (k < 50) ? __expf(-10.0f * dd * dd) : 0.0f;
      short sv = (short)f2bf(val);
      if (u < 8) lo[u] = sv; else hi[u - 8] = sv;
    }
    *reinterpret_cast<s16x8*>(&rbf_s[le][kb]) = lo;
    *reinterpret_cast<s16x8*>(&rbf_s[le][kb + 8]) = hi;
  }
  // no __syncthreads: all LDS producer/consumer pairs are wave-local

  const int w = t >> 6, lane = t & 63;
  const int lr = lane & 15, lg = lane >> 4;
  const int arow = w * 16 + lr;
  const int k8 = lg * 8;
  const f32x4 z = {0.f, 0.f, 0.f, 0.f};

  // ---- cf_f: filt = rbf @ W_cf_f (8 MFMAs) ----
  f32x4 fac[4] = {z, z, z, z};
  #pragma unroll
  for (int kb = 0; kb < 64; kb += 32) {
    s16x8 a = *reinterpret_cast<const s16x8*>(&rbf_s[arow][kb + k8]);
    #pragma unroll
    for (int j = 0; j < 4; ++j) {
      s16x8 b = *reinterpret_cast<const s16x8*>(&WcffT[(j * 16 + lr) * 64 + kb + k8]);
      fac[j] = __builtin_amdgcn_mfma_f32_16x16x32_bf16(a, b, fac[j], 0, 0, 0);
    }
  }

  // ---- h_e = (lin + b) * silu(filt + b), written in place into hlin ----
  #pragma unroll
  for (int j = 0; j < 4; ++j) {
    int col = j * 16 + lr;
    float bi = b_cf_in[col], bf_ = b_cf_f[col];
    #pragma unroll
    for (int r = 0; r < 4; ++r) {
      int row = w * 16 + lg * 4 + r;
      float lin = bf2f(hlin[row][col]);
      float he = (lin + bi) * silu_f(fac[j][r] + bf_);
      hlin[row][col] = (short)f2bf(he);
    }
  }

  // ---- copy h_e -> global (own-wave rows, coalesced) ----
  #pragma unroll
  for (int u = 0; u < 2; ++u) {
    int chunk = lane + u * 64;                  // 0..127
    int riw = chunk >> 3, col8 = (chunk & 7) * 8;
    s16x8 v = *reinterpret_cast<const s16x8*>(&hlin[w * 16 + riw][col8]);
    *reinterpret_cast<s16x8*>(&he_g[((size_t)(p0 + w * 16 + riw)) * 64 + col8]) = v;
  }

  // ---- ew: C-init from gathered sums, + h_e @ W_ew_bot (4 MFMAs), tanh ----
  {
    f32x4 ew[2];
    #pragma unroll
    for (int j = 0; j < 2; ++j) {
      #pragma unroll
      for (int r = 0; r < 4; ++r)
        ew[j][r] = bf2f(ewsum[w * 16 + lg * 4 + r][j * 16 + lr]);
    }
    #pragma unroll
    for (int kb = 0; kb < 64; kb += 32) {
      s16x8 a = *reinterpret_cast<const s16x8*>(&hlin[arow][kb + k8]);
      #pragma unroll
      for (int j = 0; j < 2; ++j) {
        s16x8 b = *reinterpret_cast<const s16x8*>(&WewBT[(j * 16 + lr) * 64 + kb + k8]);
        ew[j] = __builtin_amdgcn_mfma_f32_16x16x32_bf16(a, b, ew[j], 0, 0, 0);
      }
    }
    #pragma unroll
    for (int j = 0; j < 2; ++j) {
      int col = j * 16 + lr;
      float be = b_ew[col];
      #pragma unroll
      for (int r = 0; r < 4; ++r)
        ewsum[w * 16 + lg * 4 + r][col] = (short)f2bf(tanh_f(ew[j][r] + be));
    }
  }

  // ---- coef: silu(h_e @ W_c1 + b) @ W_c2 + b (8 MFMAs + reduce) ----
  {
    f32x4 c[4] = {z, z, z, z};
    #pragma unroll
    for (int kb = 0; kb < 64; kb += 32) {
      s16x8 a = *reinterpret_cast<const s16x8*>(&hlin[arow][kb + k8]);
      #pragma unroll
      for (int j = 0; j < 4; ++j) {
        s16x8 b = *reinterpret_cast<const s16x8*>(&Wc1T[(j * 16 + lr) * 64 + kb + k8]);
        c[j] = __builtin_amdgcn_mfma_f32_16x16x32_bf16(a, b, c[j], 0, 0, 0);
      }
    }
    float p[4] = {0.f, 0.f, 0.f, 0.f};
    #pragma unroll
    for (int j = 0; j < 4; ++j) {
      int col = j * 16 + lr;
      float bc = b_c1[col], wc = W_c2[col];
      #pragma unroll
      for (int r = 0; r < 4; ++r) p[r] += silu_f(c[j][r] + bc) * wc;
    }
    #pragma unroll
    for (int r = 0; r < 4; ++r) {
      p[r] += __shfl_xor(p[r], 1, 64);
      p[r] += __shfl_xor(p[r], 2, 64);
      p[r] += __shfl_xor(p[r], 4, 64);
      p[r] += __shfl_xor(p[r], 8, 64);
    }
    if (lr == 0) {
      float bc2 = b_c2[0];
      #pragma unroll
      for (int r = 0; r < 4; ++r)
        coef_arr[p0 + w * 16 + lg * 4 + r] = p[r] + bc2;
    }
  }

  // ---- copy how -> global (own-wave rows, coalesced) ----
  {
    int riw = lane >> 2, col8 = (lane & 3) * 8;
    s16x8 v = *reinterpret_cast<const s16x8*>(&ewsum[w * 16 + riw][col8]);
    *reinterpret_cast<s16x8*>(&how_g[((size_t)(p0 + w * 16 + riw)) * 32 + col8]) = v;
  }
}

// ------- fused per-node kernel: dual softmax, h_agg(bf16), x_new, nrm(bf16) -------
__global__ __launch_bounds__(256) void node_agg_kernel(
    const int* __restrict__ off, const float* __restrict__ d_arr,
    const float* __restrict__ sl_arr, const short* __restrict__ he_g,
    const float* __restrict__ coef_arr, const float* __restrict__ xmx_arr,
    const short* __restrict__ how_g, const float* __restrict__ x,
    float* __restrict__ tot_un,
    short* __restrict__ hagg_bf, short* __restrict__ nrm_bf,
    float* __restrict__ x_out)
{
  int w = threadIdx.x >> 6, lane = threadIdx.x & 63;
  int n = blockIdx.x * 4 + w;
  if (n >= N_NODES) return;
  int b = off[n], e = off[n + 1];

  // pass 1: sums of eu, sem; stash unnormalized product
  float s1 = 0.f, s2 = 0.f;
  for (int p = b + lane; p < e; p += 64) {
    float e1 = __expf(-d_arr[p]);
    float e2 = __expf(sl_arr[p]);
    s1 += e1; s2 += e2;
    tot_un[p] = e1 * e2;
  }
  #pragma unroll
  for (int o = 32; o > 0; o >>= 1) { s1 += __shfl_xor(s1, o, 64); s2 += __shfl_xor(s2, o, 64); }
  float r12 = (1.f / s1) * (1.f / s2);

  // pass 2: third softmax denominator; rewrite tot_un with exp(l3)
  float s3 = 0.f;
  for (int p = b + lane; p < e; p += 64) {
    float ex = __expf(tot_un[p] * r12);
    s3 += ex;
    tot_un[p] = ex;
  }
  #pragma unroll
  for (int o = 32; o > 0; o >>= 1) s3 += __shfl_xor(s3, o, 64);
  float inv3 = 1.f / s3;
  __threadfence_block();   // make lane-strided tot_un writes visible to all lanes

  // pass 3: h_agg (lane = feature), x_new folded in for lanes 0..2
  float acc = 0.f;
  float xv = (lane < 3) ? x[n * 3 + lane] : 0.f;
  for (int p = b; p < e; ++p) {
    float tot = tot_un[p] * inv3;
    acc += tot * bf2f(he_g[(size_t)p * 64 + lane]);
    if (lane < 3) xv += xmx_arr[p * 3 + lane] * coef_arr[p];
  }
  hagg_bf[(size_t)n * 64 + lane] = (short)f2bf(acc);
  if (lane < 3) x_out[n * 3 + lane] = xv;

  // pass 4: x_att segment sum -> nrm; 2 edges/iter across lane halves
  int c = lane & 31, par = lane >> 5;
  float a0 = 0.f, a1 = 0.f, a2 = 0.f;
  for (int p = b + par; p < e; p += 2) {
    float wv = bf2f(how_g[(size_t)p * 32 + c]);
    float dd = d_arr[p];
    float s = wv / (dd * dd);
    a0 += s * xmx_arr[p * 3 + 0];
    a1 += s * xmx_arr[p * 3 + 1];
    a2 += s * xmx_arr[p * 3 + 2];
  }
  a0 += __shfl_xor(a0, 32, 64);
  a1 += __shfl_xor(a1, 32, 64);
  a2 += __shfl_xor(a2, 32, 64);
  if (lane < 32)
    nrm_bf[(size_t)n * 32 + c] =
        (short)f2bf(sqrtf(fmaxf(a0 * a0 + a1 * a1 + a2 * a2, 0.f) + 1e-5f));
}

// ---------- MFMA node MLP: 64 nodes / block, 4 waves, wave-local ----------
__global__ __launch_bounds__(256) void node_mlp_kernel(
    const short* __restrict__ h_bf, const short* __restrict__ hagg_bf,
    const short* __restrict__ nrm_bf,
    const short* __restrict__ Wpn1T, const float* __restrict__ b_pn1,
    const short* __restrict__ Wpn2T, const float* __restrict__ b_pn2,
    const short* __restrict__ Wn1T, const float* __restrict__ b_n1,
    const short* __restrict__ Wn2T, const float* __restrict__ b_n2,
    float* __restrict__ h_out)
{
  __shared__ short cat[64][200];   // [h | hagg | emb], +8 pad
  __shared__ short tbuf[64][72];   // nrm(cols 0..31) -> t1 -> t2 (wave-local alias)

  const int t = threadIdx.x;
  const int w = t >> 6, lane = t & 63;
  const int n0 = blockIdx.x * 64;
  const int rbase = w * 16;

  #pragma unroll
  for (int u = 0; u < 2; ++u) {
    int c = lane + u * 64;            // 0..127 -> 16 rows x 8 chunks
    int riw = c >> 3, col8 = (c & 7) * 8;
    int node = n0 + rbase + riw; if (node >= N_NODES) node = N_NODES - 1;
    *reinterpret_cast<s16x8*>(&cat[rbase + riw][col8]) =
        *reinterpret_cast<const s16x8*>(&h_bf[(size_t)node * 64 + col8]);
    *reinterpret_cast<s16x8*>(&cat[rbase + riw][64 + col8]) =
        *reinterpret_cast<const s16x8*>(&hagg_bf[(size_t)node * 64 + col8]);
  }
  {
    int riw = lane >> 2, col8 = (lane & 3) * 8;
    int node = n0 + rbase + riw; if (node >= N_NODES) node = N_NODES - 1;
    *reinterpret_cast<s16x8*>(&tbuf[rbase + riw][col8]) =
        *reinterpret_cast<const s16x8*>(&nrm_bf[(size_t)node * 32 + col8]);
  }

  const int lr = lane & 15, lg = lane >> 4;
  const int arow = rbase + lr;
  const int k8 = lg * 8;
  const f32x4 z = {0.f, 0.f, 0.f, 0.f};

  // GEMM1: t1 = silu(nrm @ W_pn1 + b), K=32
  {
    f32x4 c1[4] = {z, z, z, z};
    s16x8 a = *reinterpret_cast<const s16x8*>(&tbuf[arow][k8]);
    #pragma unroll
    for (int j = 0; j < 4; ++j) {
      s16x8 b = *reinterpret_cast<const s16x8*>(&Wpn1T[(j * 16 + lr) * 32 + k8]);
      c1[j] = __builtin_amdgcn_mfma_f32_16x16x32_bf16(a, b, c1[j], 0, 0, 0);
    }
    #pragma unroll
    for (int j = 0; j < 4; ++j) {
      int col = j * 16 + lr; float bb = b_pn1[col];
      #pragma unroll
      for (int r = 0; r < 4; ++r)
        tbuf[rbase + lg * 4 + r][col] = (short)f2bf(silu_f(c1[j][r] + bb));
    }
  }
  // GEMM2: emb = t1 @ W_pn2 + b, K=64 -> cat cols 128..191
  {
    f32x4 c2[4] = {z, z, z, z};
    #pragma unroll
    for (int kb = 0; kb < 64; kb += 32) {
      s16x8 a = *reinterpret_cast<const s16x8*>(&tbuf[arow][kb + k8]);
      #pragma unroll
      for (int j = 0; j < 4; ++j) {
        s16x8 b = *reinterpret_cast<const s16x8*>(&Wpn2T[(j * 16 + lr) * 64 + kb + k8]);
        c2[j] = __builtin_amdgcn_mfma_f32_16x16x32_bf16(a, b, c2[j], 0, 0, 0);
      }
    }
    #pragma unroll
    for (int j = 0; j < 4; ++j) {
      int col = j * 16 + lr; float bb = b_pn2[col];
      #pragma unroll
      for (int r = 0; r < 4; ++r)
        cat[rbase + lg * 4 + r][128 + col] = (short)f2bf(c2[j][r] + bb);
    }
  }
  // GEMM3: t2 = silu([h|hagg|emb] @ W_n1 + b), K=192
  {
    f32x4 c3[4] = {z, z, z, z};
    #pragma unroll
    for (int kb = 0; kb < 192; kb += 32) {
      s16x8 a = *reinterpret_cast<const s16x8*>(&cat[arow][kb + k8]);
      #pragma unroll
      for (int j = 0; j < 4; ++j) {
        s16x8 b = *reinterpret_cast<const s16x8*>(&Wn1T[(j * 16 + lr) * 192 + kb + k8]);
        c3[j] = __builtin_amdgcn_mfma_f32_16x16x32_bf16(a, b, c3[j], 0, 0, 0);
      }
    }
    #pragma unroll
    for (int j = 0; j < 4; ++j) {
      int col = j * 16 + lr; float bb = b_n1[col];
      #pragma unroll
      for (int r = 0; r < 4; ++r)
        tbuf[rbase + lg * 4 + r][col] = (short)f2bf(silu_f(c3[j][r] + bb));
    }
  }
  // GEMM4: h_out = t2 @ W_n2 + b, K=64, f32 store
  {
    f32x4 c4[4] = {z, z, z, z};
    #pragma unroll
    for (int kb = 0; kb < 64; kb += 32) {
      s16x8 a = *reinterpret_cast<const s16x8*>(&tbuf[arow][kb + k8]);
      #pragma unroll
      for (int j = 0; j < 4; ++j) {
        s16x8 b = *reinterpret_cast<const s16x8*>(&Wn2T[(j * 16 + lr) * 64 + kb + k8]);
        c4[j] = __builtin_amdgcn_mfma_f32_16x16x32_bf16(a, b, c4[j], 0, 0, 0);
      }
    }
    #pragma unroll
    for (int j = 0; j < 4; ++j) {
      int col = j * 16 + lr; float bb = b_n2[col];
      #pragma unroll
      for (int r = 0; r < 4; ++r) {
        int node = n0 + rbase + lg * 4 + r;
        if (node < N_NODES) h_out[(size_t)node * 64 + col] = c4[j][r] + bb;
      }
    }
  }
}

// ---------------- launch ----------------
extern "C" void kernel_launch(void* const* d_in, const int* in_sizes, int n_in,
                              void* d_out, int out_size, void* d_ws, size_t ws_size,
                              hipStream_t stream) {
  const float* h      = (const float*)d_in[0];
  const float* x      = (const float*)d_in[1];
  const int*   src    = (const int*)d_in[2];
  const int*   dst    = (const int*)d_in[3];
  const float* W_cf_in = (const float*)d_in[4];
  const float* b_cf_in = (const float*)d_in[5];
  const float* W_cf_f  = (const float*)d_in[6];
  const float* b_cf_f  = (const float*)d_in[7];
  const float* W_sem   = (const float*)d_in[8];
  const float* W_ew    = (const float*)d_in[9];
  const float* b_ew    = (const float*)d_in[10];
  const float* W_pn1   = (const float*)d_in[11];
  const float* b_pn1   = (const float*)d_in[12];
  const float* W_pn2   = (const float*)d_in[13];
  const float* b_pn2   = (const float*)d_in[14];
  const float* W_n1    = (const float*)d_in[15];
  const float* b_n1    = (const float*)d_in[16];
  const float* W_n2    = (const float*)d_in[17];
  const float* b_n2    = (const float*)d_in[18];
  const float* W_c1    = (const float*)d_in[19];
  const float* b_c1    = (const float*)d_in[20];
  const float* W_c2    = (const float*)d_in[21];
  const float* b_c2    = (const float*)d_in[22];

  char* ws = (char*)d_ws;
  size_t o = 0;
  auto take = [&](size_t bytes) {
    void* p = ws + o;
    o = (o + bytes + 255) & ~(size_t)255;
    return p;
  };
  int* deg    = (int*)take((size_t)N_NODES * 4);
  int* off    = (int*)take((size_t)(N_NODES + 1) * 4);
  int* cur    = (int*)take((size_t)N_NODES * 4);
  int* eperm  = (int*)take((size_t)N_EDGES * 4);
  int* bsum   = (int*)take((size_t)SCAN_B * 4);
  int* bpre   = (int*)take((size_t)SCAN_B * 4);
  float* d_arr = (float*)take((size_t)N_EDGES * 4);
  float* xmx   = (float*)take((size_t)N_EDGES * 12);
  float* sl    = (float*)take((size_t)N_EDGES * 4);
  float* coef  = (float*)take((size_t)N_EDGES * 4);
  float* tot_un = (float*)take((size_t)N_EDGES * 4);
  short* he   = (short*)take((size_t)N_EDGES * 64 * 2);
  short* how  = (short*)take((size_t)N_EDGES * 32 * 2);
  short* hagg_bf = (short*)take((size_t)N_NODES * 64 * 2);
  short* nrm_bf  = (short*)take((size_t)N_NODES * 32 * 2);
  short* WpreT  = (short*)take((size_t)224 * 64 * 2);
  short* WcffT  = (short*)take((size_t)64 * 64 * 2);
  short* WewBT  = (short*)take((size_t)32 * 64 * 2);
  short* Wc1T   = (short*)take((size_t)64 * 64 * 2);
  short* Wpn1T  = (short*)take((size_t)64 * 32 * 2);
  short* Wpn2T  = (short*)take((size_t)64 * 64 * 2);
  short* Wn1T   = (short*)take((size_t)64 * 192 * 2);
  short* Wn2T   = (short*)take((size_t)64 * 64 * 2);
  short* h_bf   = (short*)take((size_t)N_NODES * 64 * 2);
  short* preS   = (short*)take((size_t)N_NODES * 112 * 2);
  short* preD   = (short*)take((size_t)N_NODES * 112 * 2);

  float* h_out = (float*)d_out;
  float* x_out = h_out + (size_t)N_NODES * 64;

  hipMemsetAsync(deg, 0, (size_t)N_NODES * 4, stream);
  hipMemsetAsync(cur, 0, (size_t)N_NODES * 4, stream);

  hist_kernel<<<N_EDGES / 256, 256, 0, stream>>>(dst, deg);
  scanA_kernel<<<SCAN_B, 256, 0, stream>>>(deg, bsum);
  scanB_kernel<<<1, 64, 0, stream>>>(bsum, bpre);
  scanC_kernel<<<SCAN_B, 256, 0, stream>>>(deg, bpre, off);
  scatter_kernel<<<N_EDGES / 256, 256, 0, stream>>>(dst, off, cur, eperm);
  prep_kernel<<<32, 256, 0, stream>>>(W_cf_in, W_cf_f, W_ew, W_sem, W_c1,
                                      W_pn1, W_pn2, W_n1, W_n2, h,
                                      WpreT, WcffT, WewBT, Wc1T,
                                      Wpn1T, Wpn2T, Wn1T, Wn2T, h_bf);
  pre_node_kernel<<<(N_NODES + 63) / 64, 256, 0, stream>>>(h_bf, WpreT, preS, preD);

  edge_kernel<<<N_EDGES / 64, 256, 0, stream>>>(
      x, src, dst, eperm, preS, preD,
      b_cf_in, WcffT, b_cf_f,
      WewBT, b_ew, Wc1T, b_c1, W_c2, b_c2,
      d_arr, xmx, sl, coef, he, how);

  node_agg_kernel<<<N_NODES / 4, 256, 0, stream>>>(
      off, d_arr, sl, he, coef, xmx, how, x, tot_un, hagg_bf, nrm_bf, x_out);

  node_mlp_kernel<<<(N_NODES + 63) / 64, 256, 0, stream>>>(
      h_bf, hagg_bf, nrm_bf,
      Wpn1T, b_pn1, Wpn2T, b_pn2,
      Wn1T, b_n1, Wn2T, b_n2,
      h_out);
}

// Round 10
// 490.915 us; speedup vs baseline: 36.0858x; 1.0468x over previous
//
#include <hip/hip_runtime.h>
#include <hip/hip_bf16.h>

#define N_NODES 50000
#define N_EDGES 800000
#define SCAN_B 196
#define MAX_DEG 512

typedef short s16x8 __attribute__((ext_vector_type(8)));
typedef float f32x4 __attribute__((ext_vector_type(4)));

__device__ __forceinline__ float silu_f(float v) {
  return v / (1.0f + __expf(-v));
}
__device__ __forceinline__ float tanh_f(float v) {
  return 1.0f - 2.0f / (__expf(2.0f * v) + 1.0f);
}
__device__ __forceinline__ unsigned short f2bf(float f) {
  union { __hip_bfloat16 b; unsigned short u; } cv;
  cv.b = __float2bfloat16(f);
  return cv.u;
}
__device__ __forceinline__ float bf2f(short s) {
  union { unsigned u; float f; } a; a.u = ((unsigned)(unsigned short)s) << 16;
  return a.f;
}

// ---------------- CSR build ----------------
__global__ void hist_kernel(const int* __restrict__ dst, int* __restrict__ deg) {
  int i = blockIdx.x * 256 + threadIdx.x;
  if (i < N_EDGES) atomicAdd(&deg[dst[i]], 1);
}

__global__ __launch_bounds__(256) void scanA_kernel(const int* __restrict__ deg,
                                                    int* __restrict__ bsum) {
  int i = blockIdx.x * 256 + threadIdx.x;
  int lane = threadIdx.x & 63, w = threadIdx.x >> 6;
  int v = (i < N_NODES) ? deg[i] : 0;
  #pragma unroll
  for (int o = 32; o > 0; o >>= 1) v += __shfl_xor(v, o, 64);
  __shared__ int ws_[4];
  if (lane == 0) ws_[w] = v;
  __syncthreads();
  if (threadIdx.x == 0) bsum[blockIdx.x] = ws_[0] + ws_[1] + ws_[2] + ws_[3];
}

__global__ void scanB_kernel(const int* __restrict__ bsum, int* __restrict__ bpre) {
  int lane = threadIdx.x;   // one wave of 64
  int carry = 0;
  for (int base = 0; base < SCAN_B; base += 64) {
    int i = base + lane;
    int v = (i < SCAN_B) ? bsum[i] : 0;
    int sv = v;
    #pragma unroll
    for (int o = 1; o < 64; o <<= 1) {
      int u = __shfl_up(sv, o, 64);
      if (lane >= o) sv += u;
    }
    if (i < SCAN_B) bpre[i] = carry + sv - v;   // exclusive prefix
    carry += __shfl(sv, 63, 64);
  }
}

__global__ __launch_bounds__(256) void scanC_kernel(const int* __restrict__ deg,
                                                    const int* __restrict__ bpre,
                                                    int* __restrict__ off) {
  int i = blockIdx.x * 256 + threadIdx.x;
  int lane = threadIdx.x & 63, w = threadIdx.x >> 6;
  int v = (i < N_NODES) ? deg[i] : 0;
  int sv = v;
  #pragma unroll
  for (int o = 1; o < 64; o <<= 1) {
    int u = __shfl_up(sv, o, 64);
    if (lane >= o) sv += u;
  }
  __shared__ int ws_[4], wp_[4];
  if (lane == 63) ws_[w] = sv;
  __syncthreads();
  if (threadIdx.x == 0) {
    int s = 0;
    #pragma unroll
    for (int j = 0; j < 4; ++j) { wp_[j] = s; s += ws_[j]; }
  }
  __syncthreads();
  if (i < N_NODES) off[i + 1] = bpre[blockIdx.x] + wp_[w] + sv;
  if (i == 0) off[0] = 0;
}

__global__ void scatter_kernel(const int* __restrict__ dst, const int* __restrict__ off,
                               int* __restrict__ cur, int* __restrict__ eperm) {
  int i = blockIdx.x * 256 + threadIdx.x;
  if (i < N_EDGES) {
    int dn = dst[i];
    int pos = atomicAdd(&cur[dn], 1);
    eperm[off[dn] + pos] = i;
  }
}

// -------- weight prep: bf16 transposed weights; h -> bf16 rows --------
// WpreT[224][64]: rows 0-111 = S-half [Wcfin_top | Wew_top | Wsem_top | 0],
//                 rows 112-223 = D-half [Wcfin_bot | Wew_bot | Wsem_bot | 0]
__global__ void prep_kernel(const float* __restrict__ Wcfin, const float* __restrict__ Wcff,
                            const float* __restrict__ Wew, const float* __restrict__ Wsem,
                            const float* __restrict__ Wc1,
                            const float* __restrict__ Wpn1, const float* __restrict__ Wpn2,
                            const float* __restrict__ Wn1, const float* __restrict__ Wn2,
                            const float* __restrict__ h,
                            short* __restrict__ WpreT, short* __restrict__ WcffT,
                            short* __restrict__ WewBT, short* __restrict__ Wc1T,
                            short* __restrict__ Wpn1T, short* __restrict__ Wpn2T,
                            short* __restrict__ Wn1T, short* __restrict__ Wn2T,
                            short* __restrict__ h_bf) {
  int t = blockIdx.x * 256 + threadIdx.x;
  int stride = gridDim.x * 256;
  for (int i = t; i < 224 * 64; i += stride) {
    int n = i >> 6, k = i & 63;
    int half = (n >= 112) ? 1 : 0;
    int c = n - half * 112;
    float v = 0.f;
    if (c < 64)       v = Wcfin[(half * 64 + k) * 64 + c];
    else if (c < 96)  v = Wew[(half * 64 + k) * 32 + (c - 64)];
    else if (c == 96) v = Wsem[half * 64 + k];
    WpreT[i] = (short)f2bf(v);
  }
  for (int i = t; i < 64 * 64; i += stride) {
    int n = i >> 6, k = i & 63;
    WcffT[i] = (k < 50) ? (short)f2bf(Wcff[k * 64 + n]) : (short)0;
  }
  for (int i = t; i < 32 * 64; i += stride) {
    int n = i >> 6, k = i & 63;
    WewBT[i] = (short)f2bf(Wew[(128 + k) * 32 + n]);
  }
  for (int i = t; i < 64 * 64; i += stride) {
    int n = i >> 6, k = i & 63;
    Wc1T[i] = (short)f2bf(Wc1[k * 64 + n]);
  }
  for (int i = t; i < 64 * 32; i += stride) {
    int n = i >> 5, k = i & 31;
    Wpn1T[i] = (short)f2bf(Wpn1[k * 64 + n]);
  }
  for (int i = t; i < 64 * 64; i += stride) {
    int n = i >> 6, k = i & 63;
    Wpn2T[i] = (short)f2bf(Wpn2[k * 64 + n]);
  }
  for (int i = t; i < 64 * 192; i += stride) {
    int n = i / 192, k = i - n * 192;
    Wn1T[i] = (short)f2bf(Wn1[k * 64 + n]);
  }
  for (int i = t; i < 64 * 64; i += stride) {
    int n = i >> 6, k = i & 63;
    Wn2T[i] = (short)f2bf(Wn2[k * 64 + n]);
  }
  for (int i = t; i < (N_NODES * 64) / 4; i += stride) {
    float4 v = reinterpret_cast<const float4*>(h)[i];
    ushort4 u;
    u.x = f2bf(v.x); u.y = f2bf(v.y); u.z = f2bf(v.z); u.w = f2bf(v.w);
    reinterpret_cast<ushort4*>(h_bf)[i] = u;
  }
}

// ---- per-node precompute: preS/preD[n][112] = h[n] @ [lin(64)|ew(32)|sem(1)|0] ----
__global__ __launch_bounds__(256) void pre_node_kernel(
    const short* __restrict__ h_bf, const short* __restrict__ WpreT,
    short* __restrict__ preS, short* __restrict__ preD)
{
  __shared__ short hs[64][72];
  const int t = threadIdx.x;
  const int w = t >> 6, lane = t & 63;
  const int n0 = blockIdx.x * 64;
  const int rbase = w * 16;

  #pragma unroll
  for (int u = 0; u < 2; ++u) {
    int c = lane + u * 64;            // 0..127
    int riw = c >> 3, col8 = (c & 7) * 8;
    int node = n0 + rbase + riw; if (node >= N_NODES) node = N_NODES - 1;
    *reinterpret_cast<s16x8*>(&hs[rbase + riw][col8]) =
        *reinterpret_cast<const s16x8*>(&h_bf[(size_t)node * 64 + col8]);
  }

  const int lr = lane & 15, lg = lane >> 4;
  const int arow = rbase + lr;
  const int k8 = lg * 8;
  const f32x4 z = {0.f, 0.f, 0.f, 0.f};

  #pragma unroll
  for (int half = 0; half < 2; ++half) {
    short* out = half ? preD : preS;
    #pragma unroll
    for (int j = 0; j < 7; ++j) {
      f32x4 acc = z;
      #pragma unroll
      for (int kb = 0; kb < 64; kb += 32) {
        s16x8 a = *reinterpret_cast<const s16x8*>(&hs[arow][kb + k8]);
        s16x8 b = *reinterpret_cast<const s16x8*>(&WpreT[(half * 112 + j * 16 + lr) * 64 + kb + k8]);
        acc = __builtin_amdgcn_mfma_f32_16x16x32_bf16(a, b, acc, 0, 0, 0);
      }
      #pragma unroll
      for (int r = 0; r < 4; ++r) {
        int node = n0 + rbase + lg * 4 + r;
        if (node < N_NODES) out[(size_t)node * 112 + j * 16 + lr] = (short)f2bf(acc[r]);
      }
    }
  }
}

// ------- MFMA edge kernel: 64 edges / block, 4 independent waves, no barriers -------
// Per-edge linear parts come from preS[src]+preD[dst] gathers; only the
// rbf-filter (K=64), ew-part2 (K=64) and c1 (K=64) GEMMs remain. LDS 23552 B.
__global__ __launch_bounds__(256, 6) void edge_kernel(
    const float* __restrict__ x,
    const int* __restrict__ src, const int* __restrict__ dst,
    const int* __restrict__ eperm,
    const short* __restrict__ preS, const short* __restrict__ preD,
    const float* __restrict__ b_cf_in,
    const short* __restrict__ WcffT, const float* __restrict__ b_cf_f,
    const short* __restrict__ WewBT, const float* __restrict__ b_ew,
    const short* __restrict__ Wc1T, const float* __restrict__ b_c1,
    const float* __restrict__ W_c2, const float* __restrict__ b_c2,
    float* __restrict__ d_arr, float* __restrict__ xmx_arr,
    float2* __restrict__ e12_arr, float* __restrict__ coef_arr,
    short* __restrict__ he_g, short* __restrict__ how_g)
{
  __shared__ short hlin[64][72];   // lin sums -> h_e written in place
  __shared__ short rbf_s[64][72];  // rbf
  __shared__ short ewsum[64][40];  // ew sums -> how written in place

  const int t = threadIdx.x;
  const int p0 = blockIdx.x * 64;
  const int le = t >> 2, q = t & 3;   // 4 threads per edge
  const int p_edge = p0 + le;

  const int e = eperm[p_edge];
  const int sn = src[e], dn = dst[e];

  // ---- geometry ----
  float mx0 = x[sn * 3 + 0] - x[dn * 3 + 0];
  float mx1 = x[sn * 3 + 1] - x[dn * 3 + 1];
  float mx2 = x[sn * 3 + 2] - x[dn * 3 + 2];
  float d = sqrtf(mx0 * mx0 + mx1 * mx1 + mx2 * mx2 + 1e-5f);
  if (q == 0) {
    d_arr[p_edge] = d;
    xmx_arr[p_edge * 3 + 0] = mx0;
    xmx_arr[p_edge * 3 + 1] = mx1;
    xmx_arr[p_edge * 3 + 2] = mx2;
  }

  // ---- gather preS[src]+preD[dst]: chunks 0-7 -> hlin, 8-11 -> ewsum, sem ----
  {
    const short* ps = preS + (size_t)sn * 112;
    const short* pd = preD + (size_t)dn * 112;
    #pragma unroll
    for (int ci = 0; ci < 3; ++ci) {
      int c = q * 3 + ci;               // 0..11
      s16x8 a = *reinterpret_cast<const s16x8*>(ps + c * 8);
      s16x8 b = *reinterpret_cast<const s16x8*>(pd + c * 8);
      s16x8 r;
      #pragma unroll
      for (int u = 0; u < 8; ++u) r[u] = (short)f2bf(bf2f(a[u]) + bf2f(b[u]));
      short* dstp = (c < 8) ? &hlin[le][c * 8] : &ewsum[le][(c - 8) * 8];
      *reinterpret_cast<s16x8*>(dstp) = r;
    }
    if (q == 3) {
      float sem = bf2f(ps[96]) + bf2f(pd[96]);
      float2 ee;
      ee.x = __expf(-d);
      ee.y = __expf(silu_f(sem));
      e12_arr[p_edge] = ee;
    }
  }

  // ---- RBF (bf16): q covers k = q*16 .. q*16+15 ----
  {
    int kb = q * 16;
    s16x8 lo, hi;
    #pragma unroll 16
    for (int u = 0; u < 16; ++u) {
      int k = kb + u;
      float mu = (float)k * (5.0f / 49.0f);
      float dd = d - mu;
      float val = (k < 50) ? __expf(-10.0f * dd * dd) : 0.0f;
      short sv = (short)f2bf(val);
      if (u < 8) lo[u] = sv; else hi[u - 8] = sv;
    }
    *reinterpret_cast<s16x8*>(&rbf_s[le][kb]) = lo;
    *reinterpret_cast<s16x8*>(&rbf_s[le][kb + 8]) = hi;
  }
  // no __syncthreads: all LDS producer/consumer pairs are wave-local

  const int w = t >> 6, lane = t & 63;
  const int lr = lane & 15, lg = lane >> 4;
  const int arow = w * 16 + lr;
  const int k8 = lg * 8;
  const f32x4 z = {0.f, 0.f, 0.f, 0.f};

  // ---- cf_f: filt = rbf @ W_cf_f (8 MFMAs) ----
  f32x4 fac[4] = {z, z, z, z};
  #pragma unroll
  for (int kb = 0; kb < 64; kb += 32) {
    s16x8 a = *reinterpret_cast<const s16x8*>(&rbf_s[arow][kb + k8]);
    #pragma unroll
    for (int j = 0; j < 4; ++j) {
      s16x8 b = *reinterpret_cast<const s16x8*>(&WcffT[(j * 16 + lr) * 64 + kb + k8]);
      fac[j] = __builtin_amdgcn_mfma_f32_16x16x32_bf16(a, b, fac[j], 0, 0, 0);
    }
  }

  // ---- h_e = (lin + b) * silu(filt + b), written in place into hlin ----
  #pragma unroll
  for (int j = 0; j < 4; ++j) {
    int col = j * 16 + lr;
    float bi = b_cf_in[col], bf_ = b_cf_f[col];
    #pragma unroll
    for (int r = 0; r < 4; ++r) {
      int row = w * 16 + lg * 4 + r;
      float lin = bf2f(hlin[row][col]);
      float he = (lin + bi) * silu_f(fac[j][r] + bf_);
      hlin[row][col] = (short)f2bf(he);
    }
  }

  // ---- copy h_e -> global (own-wave rows, coalesced) ----
  #pragma unroll
  for (int u = 0; u < 2; ++u) {
    int chunk = lane + u * 64;                  // 0..127
    int riw = chunk >> 3, col8 = (chunk & 7) * 8;
    s16x8 v = *reinterpret_cast<const s16x8*>(&hlin[w * 16 + riw][col8]);
    *reinterpret_cast<s16x8*>(&he_g[((size_t)(p0 + w * 16 + riw)) * 64 + col8]) = v;
  }

  // ---- ew: C-init from gathered sums, + h_e @ W_ew_bot (4 MFMAs), tanh ----
  {
    f32x4 ew[2];
    #pragma unroll
    for (int j = 0; j < 2; ++j) {
      #pragma unroll
      for (int r = 0; r < 4; ++r)
        ew[j][r] = bf2f(ewsum[w * 16 + lg * 4 + r][j * 16 + lr]);
    }
    #pragma unroll
    for (int kb = 0; kb < 64; kb += 32) {
      s16x8 a = *reinterpret_cast<const s16x8*>(&hlin[arow][kb + k8]);
      #pragma unroll
      for (int j = 0; j < 2; ++j) {
        s16x8 b = *reinterpret_cast<const s16x8*>(&WewBT[(j * 16 + lr) * 64 + kb + k8]);
        ew[j] = __builtin_amdgcn_mfma_f32_16x16x32_bf16(a, b, ew[j], 0, 0, 0);
      }
    }
    #pragma unroll
    for (int j = 0; j < 2; ++j) {
      int col = j * 16 + lr;
      float be = b_ew[col];
      #pragma unroll
      for (int r = 0; r < 4; ++r)
        ewsum[w * 16 + lg * 4 + r][col] = (short)f2bf(tanh_f(ew[j][r] + be));
    }
  }

  // ---- coef: silu(h_e @ W_c1 + b) @ W_c2 + b (8 MFMAs + reduce) ----
  {
    f32x4 c[4] = {z, z, z, z};
    #pragma unroll
    for (int kb = 0; kb < 64; kb += 32) {
      s16x8 a = *reinterpret_cast<const s16x8*>(&hlin[arow][kb + k8]);
      #pragma unroll
      for (int j = 0; j < 4; ++j) {
        s16x8 b = *reinterpret_cast<const s16x8*>(&Wc1T[(j * 16 + lr) * 64 + kb + k8]);
        c[j] = __builtin_amdgcn_mfma_f32_16x16x32_bf16(a, b, c[j], 0, 0, 0);
      }
    }
    float p[4] = {0.f, 0.f, 0.f, 0.f};
    #pragma unroll
    for (int j = 0; j < 4; ++j) {
      int col = j * 16 + lr;
      float bc = b_c1[col], wc = W_c2[col];
      #pragma unroll
      for (int r = 0; r < 4; ++r) p[r] += silu_f(c[j][r] + bc) * wc;
    }
    #pragma unroll
    for (int r = 0; r < 4; ++r) {
      p[r] += __shfl_xor(p[r], 1, 64);
      p[r] += __shfl_xor(p[r], 2, 64);
      p[r] += __shfl_xor(p[r], 4, 64);
      p[r] += __shfl_xor(p[r], 8, 64);
    }
    if (lr == 0) {
      float bc2 = b_c2[0];
      #pragma unroll
      for (int r = 0; r < 4; ++r)
        coef_arr[p0 + w * 16 + lg * 4 + r] = p[r] + bc2;
    }
  }

  // ---- copy how -> global (own-wave rows, coalesced) ----
  {
    int riw = lane >> 2, col8 = (lane & 3) * 8;
    s16x8 v = *reinterpret_cast<const s16x8*>(&ewsum[w * 16 + riw][col8]);
    *reinterpret_cast<s16x8*>(&how_g[((size_t)(p0 + w * 16 + riw)) * 32 + col8]) = v;
  }
}

// ------- fused per-node kernel: dual softmax, h_agg(bf16), x_new, nrm(bf16) -------
// LDS caches the per-node softmax products (deg <= MAX_DEG fast path).
__global__ __launch_bounds__(256) void node_agg_kernel(
    const int* __restrict__ off, const float* __restrict__ d_arr,
    const float2* __restrict__ e12_arr, const short* __restrict__ he_g,
    const float* __restrict__ coef_arr, const float* __restrict__ xmx_arr,
    const short* __restrict__ how_g, const float* __restrict__ x,
    float* __restrict__ tot_un,
    short* __restrict__ hagg_bf, short* __restrict__ nrm_bf,
    float* __restrict__ x_out)
{
  __shared__ float tot_s[4][MAX_DEG];
  int w = threadIdx.x >> 6, lane = threadIdx.x & 63;
  int n = blockIdx.x * 4 + w;
  if (n >= N_NODES) return;
  int b = off[n], e = off[n + 1];
  const bool fits = (e - b) <= MAX_DEG;   // wave-uniform

  // pass 1: sums of e1, e2; stash unnormalized product
  float s1 = 0.f, s2 = 0.f;
  for (int p = b + lane; p < e; p += 64) {
    float2 ee = e12_arr[p];
    s1 += ee.x; s2 += ee.y;
    float pr = ee.x * ee.y;
    if (fits) tot_s[w][p - b] = pr; else tot_un[p] = pr;
  }
  #pragma unroll
  for (int o = 32; o > 0; o >>= 1) { s1 += __shfl_xor(s1, o, 64); s2 += __shfl_xor(s2, o, 64); }
  float r12 = (1.f / s1) * (1.f / s2);

  // pass 2: third softmax denominator; rewrite with exp(l3)
  float s3 = 0.f;
  for (int p = b + lane; p < e; p += 64) {
    float pr = fits ? tot_s[w][p - b] : tot_un[p];
    float ex = __expf(pr * r12);
    s3 += ex;
    if (fits) tot_s[w][p - b] = ex; else tot_un[p] = ex;
  }
  #pragma unroll
  for (int o = 32; o > 0; o >>= 1) s3 += __shfl_xor(s3, o, 64);
  float inv3 = 1.f / s3;
  __threadfence_block();   // order fallback-path global writes

  // pass 3: h_agg (lane = feature), x_new folded in for lanes 0..2
  float acc = 0.f;
  float xv = (lane < 3) ? x[n * 3 + lane] : 0.f;
  for (int p = b; p < e; ++p) {
    float tot = (fits ? tot_s[w][p - b] : tot_un[p]) * inv3;
    acc += tot * bf2f(he_g[(size_t)p * 64 + lane]);
    if (lane < 3) xv += xmx_arr[p * 3 + lane] * coef_arr[p];
  }
  hagg_bf[(size_t)n * 64 + lane] = (short)f2bf(acc);
  if (lane < 3) x_out[n * 3 + lane] = xv;

  // pass 4: x_att segment sum -> nrm; 2 edges/iter across lane halves
  int c = lane & 31, par = lane >> 5;
  float a0 = 0.f, a1 = 0.f, a2 = 0.f;
  for (int p = b + par; p < e; p += 2) {
    float wv = bf2f(how_g[(size_t)p * 32 + c]);
    float dd = d_arr[p];
    float s = wv / (dd * dd);
    a0 += s * xmx_arr[p * 3 + 0];
    a1 += s * xmx_arr[p * 3 + 1];
    a2 += s * xmx_arr[p * 3 + 2];
  }
  a0 += __shfl_xor(a0, 32, 64);
  a1 += __shfl_xor(a1, 32, 64);
  a2 += __shfl_xor(a2, 32, 64);
  if (lane < 32)
    nrm_bf[(size_t)n * 32 + c] =
        (short)f2bf(sqrtf(fmaxf(a0 * a0 + a1 * a1 + a2 * a2, 0.f) + 1e-5f));
}

// ---------- MFMA node MLP: 64 nodes / block, 4 waves, wave-local ----------
__global__ __launch_bounds__(256) void node_mlp_kernel(
    const short* __restrict__ h_bf, const short* __restrict__ hagg_bf,
    const short* __restrict__ nrm_bf,
    const short* __restrict__ Wpn1T, const float* __restrict__ b_pn1,
    const short* __restrict__ Wpn2T, const float* __restrict__ b_pn2,
    const short* __restrict__ Wn1T, const float* __restrict__ b_n1,
    const short* __restrict__ Wn2T, const float* __restrict__ b_n2,
    float* __restrict__ h_out)
{
  __shared__ short cat[64][200];   // [h | hagg | emb], +8 pad
  __shared__ short tbuf[64][72];   // nrm(cols 0..31) -> t1 -> t2 (wave-local alias)

  const int t = threadIdx.x;
  const int w = t >> 6, lane = t & 63;
  const int n0 = blockIdx.x * 64;
  const int rbase = w * 16;

  #pragma unroll
  for (int u = 0; u < 2; ++u) {
    int c = lane + u * 64;            // 0..127 -> 16 rows x 8 chunks
    int riw = c >> 3, col8 = (c & 7) * 8;
    int node = n0 + rbase + riw; if (node >= N_NODES) node = N_NODES - 1;
    *reinterpret_cast<s16x8*>(&cat[rbase + riw][col8]) =
        *reinterpret_cast<const s16x8*>(&h_bf[(size_t)node * 64 + col8]);
    *reinterpret_cast<s16x8*>(&cat[rbase + riw][64 + col8]) =
        *reinterpret_cast<const s16x8*>(&hagg_bf[(size_t)node * 64 + col8]);
  }
  {
    int riw = lane >> 2, col8 = (lane & 3) * 8;
    int node = n0 + rbase + riw; if (node >= N_NODES) node = N_NODES - 1;
    *reinterpret_cast<s16x8*>(&tbuf[rbase + riw][col8]) =
        *reinterpret_cast<const s16x8*>(&nrm_bf[(size_t)node * 32 + col8]);
  }

  const int lr = lane & 15, lg = lane >> 4;
  const int arow = rbase + lr;
  const int k8 = lg * 8;
  const f32x4 z = {0.f, 0.f, 0.f, 0.f};

  // GEMM1: t1 = silu(nrm @ W_pn1 + b), K=32
  {
    f32x4 c1[4] = {z, z, z, z};
    s16x8 a = *reinterpret_cast<const s16x8*>(&tbuf[arow][k8]);
    #pragma unroll
    for (int j = 0; j < 4; ++j) {
      s16x8 b = *reinterpret_cast<const s16x8*>(&Wpn1T[(j * 16 + lr) * 32 + k8]);
      c1[j] = __builtin_amdgcn_mfma_f32_16x16x32_bf16(a, b, c1[j], 0, 0, 0);
    }
    #pragma unroll
    for (int j = 0; j < 4; ++j) {
      int col = j * 16 + lr; float bb = b_pn1[col];
      #pragma unroll
      for (int r = 0; r < 4; ++r)
        tbuf[rbase + lg * 4 + r][col] = (short)f2bf(silu_f(c1[j][r] + bb));
    }
  }
  // GEMM2: emb = t1 @ W_pn2 + b, K=64 -> cat cols 128..191
  {
    f32x4 c2[4] = {z, z, z, z};
    #pragma unroll
    for (int kb = 0; kb < 64; kb += 32) {
      s16x8 a = *reinterpret_cast<const s16x8*>(&tbuf[arow][kb + k8]);
      #pragma unroll
      for (int j = 0; j < 4; ++j) {
        s16x8 b = *reinterpret_cast<const s16x8*>(&Wpn2T[(j * 16 + lr) * 64 + kb + k8]);
        c2[j] = __builtin_amdgcn_mfma_f32_16x16x32_bf16(a, b, c2[j], 0, 0, 0);
      }
    }
    #pragma unroll
    for (int j = 0; j < 4; ++j) {
      int col = j * 16 + lr; float bb = b_pn2[col];
      #pragma unroll
      for (int r = 0; r < 4; ++r)
        cat[rbase + lg * 4 + r][128 + col] = (short)f2bf(c2[j][r] + bb);
    }
  }
  // GEMM3: t2 = silu([h|hagg|emb] @ W_n1 + b), K=192
  {
    f32x4 c3[4] = {z, z, z, z};
    #pragma unroll
    for (int kb = 0; kb < 192; kb += 32) {
      s16x8 a = *reinterpret_cast<const s16x8*>(&cat[arow][kb + k8]);
      #pragma unroll
      for (int j = 0; j < 4; ++j) {
        s16x8 b = *reinterpret_cast<const s16x8*>(&Wn1T[(j * 16 + lr) * 192 + kb + k8]);
        c3[j] = __builtin_amdgcn_mfma_f32_16x16x32_bf16(a, b, c3[j], 0, 0, 0);
      }
    }
    #pragma unroll
    for (int j = 0; j < 4; ++j) {
      int col = j * 16 + lr; float bb = b_n1[col];
      #pragma unroll
      for (int r = 0; r < 4; ++r)
        tbuf[rbase + lg * 4 + r][col] = (short)f2bf(silu_f(c3[j][r] + bb));
    }
  }
  // GEMM4: h_out = t2 @ W_n2 + b, K=64, f32 store
  {
    f32x4 c4[4] = {z, z, z, z};
    #pragma unroll
    for (int kb = 0; kb < 64; kb += 32) {
      s16x8 a = *reinterpret_cast<const s16x8*>(&tbuf[arow][kb + k8]);
      #pragma unroll
      for (int j = 0; j < 4; ++j) {
        s16x8 b = *reinterpret_cast<const s16x8*>(&Wn2T[(j * 16 + lr) * 64 + kb + k8]);
        c4[j] = __builtin_amdgcn_mfma_f32_16x16x32_bf16(a, b, c4[j], 0, 0, 0);
      }
    }
    #pragma unroll
    for (int j = 0; j < 4; ++j) {
      int col = j * 16 + lr; float bb = b_n2[col];
      #pragma unroll
      for (int r = 0; r < 4; ++r) {
        int node = n0 + rbase + lg * 4 + r;
        if (node < N_NODES) h_out[(size_t)node * 64 + col] = c4[j][r] + bb;
      }
    }
  }
}

// ---------------- launch ----------------
extern "C" void kernel_launch(void* const* d_in, const int* in_sizes, int n_in,
                              void* d_out, int out_size, void* d_ws, size_t ws_size,
                              hipStream_t stream) {
  const float* h      = (const float*)d_in[0];
  const float* x      = (const float*)d_in[1];
  const int*   src    = (const int*)d_in[2];
  const int*   dst    = (const int*)d_in[3];
  const float* W_cf_in = (const float*)d_in[4];
  const float* b_cf_in = (const float*)d_in[5];
  const float* W_cf_f  = (const float*)d_in[6];
  const float* b_cf_f  = (const float*)d_in[7];
  const float* W_sem   = (const float*)d_in[8];
  const float* W_ew    = (const float*)d_in[9];
  const float* b_ew    = (const float*)d_in[10];
  const float* W_pn1   = (const float*)d_in[11];
  const float* b_pn1   = (const float*)d_in[12];
  const float* W_pn2   = (const float*)d_in[13];
  const float* b_pn2   = (const float*)d_in[14];
  const float* W_n1    = (const float*)d_in[15];
  const float* b_n1    = (const float*)d_in[16];
  const float* W_n2    = (const float*)d_in[17];
  const float* b_n2    = (const float*)d_in[18];
  const float* W_c1    = (const float*)d_in[19];
  const float* b_c1    = (const float*)d_in[20];
  const float* W_c2    = (const float*)d_in[21];
  const float* b_c2    = (const float*)d_in[22];

  char* ws = (char*)d_ws;
  size_t o = 0;
  auto take = [&](size_t bytes) {
    void* p = ws + o;
    o = (o + bytes + 255) & ~(size_t)255;
    return p;
  };
  int* deg    = (int*)take((size_t)N_NODES * 4);
  int* off    = (int*)take((size_t)(N_NODES + 1) * 4);
  int* cur    = (int*)take((size_t)N_NODES * 4);
  int* eperm  = (int*)take((size_t)N_EDGES * 4);
  int* bsum   = (int*)take((size_t)SCAN_B * 4);
  int* bpre   = (int*)take((size_t)SCAN_B * 4);
  float* d_arr = (float*)take((size_t)N_EDGES * 4);
  float* xmx   = (float*)take((size_t)N_EDGES * 12);
  float2* e12  = (float2*)take((size_t)N_EDGES * 8);
  float* coef  = (float*)take((size_t)N_EDGES * 4);
  float* tot_un = (float*)take((size_t)N_EDGES * 4);
  short* he   = (short*)take((size_t)N_EDGES * 64 * 2);
  short* how  = (short*)take((size_t)N_EDGES * 32 * 2);
  short* hagg_bf = (short*)take((size_t)N_NODES * 64 * 2);
  short* nrm_bf  = (short*)take((size_t)N_NODES * 32 * 2);
  short* WpreT  = (short*)take((size_t)224 * 64 * 2);
  short* WcffT  = (short*)take((size_t)64 * 64 * 2);
  short* WewBT  = (short*)take((size_t)32 * 64 * 2);
  short* Wc1T   = (short*)take((size_t)64 * 64 * 2);
  short* Wpn1T  = (short*)take((size_t)64 * 32 * 2);
  short* Wpn2T  = (short*)take((size_t)64 * 64 * 2);
  short* Wn1T   = (short*)take((size_t)64 * 192 * 2);
  short* Wn2T   = (short*)take((size_t)64 * 64 * 2);
  short* h_bf   = (short*)take((size_t)N_NODES * 64 * 2);
  short* preS   = (short*)take((size_t)N_NODES * 112 * 2);
  short* preD   = (short*)take((size_t)N_NODES * 112 * 2);

  float* h_out = (float*)d_out;
  float* x_out = h_out + (size_t)N_NODES * 64;

  hipMemsetAsync(deg, 0, (size_t)N_NODES * 4, stream);
  hipMemsetAsync(cur, 0, (size_t)N_NODES * 4, stream);

  hist_kernel<<<N_EDGES / 256, 256, 0, stream>>>(dst, deg);
  scanA_kernel<<<SCAN_B, 256, 0, stream>>>(deg, bsum);
  scanB_kernel<<<1, 64, 0, stream>>>(bsum, bpre);
  scanC_kernel<<<SCAN_B, 256, 0, stream>>>(deg, bpre, off);
  scatter_kernel<<<N_EDGES / 256, 256, 0, stream>>>(dst, off, cur, eperm);
  prep_kernel<<<128, 256, 0, stream>>>(W_cf_in, W_cf_f, W_ew, W_sem, W_c1,
                                       W_pn1, W_pn2, W_n1, W_n2, h,
                                       WpreT, WcffT, WewBT, Wc1T,
                                       Wpn1T, Wpn2T, Wn1T, Wn2T, h_bf);
  pre_node_kernel<<<(N_NODES + 63) / 64, 256, 0, stream>>>(h_bf, WpreT, preS, preD);

  edge_kernel<<<N_EDGES / 64, 256, 0, stream>>>(
      x, src, dst, eperm, preS, preD,
      b_cf_in, WcffT, b_cf_f,
      WewBT, b_ew, Wc1T, b_c1, W_c2, b_c2,
      d_arr, xmx, e12, coef, he, how);

  node_agg_kernel<<<N_NODES / 4, 256, 0, stream>>>(
      off, d_arr, e12, he, coef, xmx, how, x, tot_un, hagg_bf, nrm_bf, x_out);

  node_mlp_kernel<<<(N_NODES + 63) / 64, 256, 0, stream>>>(
      h_bf, hagg_bf, nrm_bf,
      Wpn1T, b_pn1, Wpn2T, b_pn2,
      Wn1T, b_n1, Wn2T, b_n2,
      h_out);
}

// Round 11
// 428.950 us; speedup vs baseline: 41.2988x; 1.1445x over previous
//
#include <hip/hip_runtime.h>
#include <hip/hip_bf16.h>

#define N_NODES 50000
#define N_EDGES 800000
#define SCAN_B 196
#define MAX_DEG 512

typedef short s16x8 __attribute__((ext_vector_type(8)));
typedef float f32x4 __attribute__((ext_vector_type(4)));

__device__ __forceinline__ float silu_f(float v) {
  return v / (1.0f + __expf(-v));
}
__device__ __forceinline__ float tanh_f(float v) {
  return 1.0f - 2.0f / (__expf(2.0f * v) + 1.0f);
}
__device__ __forceinline__ unsigned short f2bf(float f) {
  union { __hip_bfloat16 b; unsigned short u; } cv;
  cv.b = __float2bfloat16(f);
  return cv.u;
}
__device__ __forceinline__ float bf2f(short s) {
  union { unsigned u; float f; } a; a.u = ((unsigned)(unsigned short)s) << 16;
  return a.f;
}
__device__ __forceinline__ void atomAdd(float* p, float v) {
  __hip_atomic_fetch_add(p, v, __ATOMIC_RELAXED, __HIP_MEMORY_SCOPE_AGENT);
}

// ---------------- CSR build ----------------
__global__ void hist_kernel(const int* __restrict__ dst, int* __restrict__ deg) {
  int i = blockIdx.x * 256 + threadIdx.x;
  if (i < N_EDGES) atomicAdd(&deg[dst[i]], 1);
}

__global__ __launch_bounds__(256) void scanA_kernel(const int* __restrict__ deg,
                                                    int* __restrict__ bsum) {
  int i = blockIdx.x * 256 + threadIdx.x;
  int lane = threadIdx.x & 63, w = threadIdx.x >> 6;
  int v = (i < N_NODES) ? deg[i] : 0;
  #pragma unroll
  for (int o = 32; o > 0; o >>= 1) v += __shfl_xor(v, o, 64);
  __shared__ int ws_[4];
  if (lane == 0) ws_[w] = v;
  __syncthreads();
  if (threadIdx.x == 0) bsum[blockIdx.x] = ws_[0] + ws_[1] + ws_[2] + ws_[3];
}

__global__ void scanB_kernel(const int* __restrict__ bsum, int* __restrict__ bpre) {
  int lane = threadIdx.x;   // one wave of 64
  int carry = 0;
  for (int base = 0; base < SCAN_B; base += 64) {
    int i = base + lane;
    int v = (i < SCAN_B) ? bsum[i] : 0;
    int sv = v;
    #pragma unroll
    for (int o = 1; o < 64; o <<= 1) {
      int u = __shfl_up(sv, o, 64);
      if (lane >= o) sv += u;
    }
    if (i < SCAN_B) bpre[i] = carry + sv - v;   // exclusive prefix
    carry += __shfl(sv, 63, 64);
  }
}

__global__ __launch_bounds__(256) void scanC_kernel(const int* __restrict__ deg,
                                                    const int* __restrict__ bpre,
                                                    int* __restrict__ off) {
  int i = blockIdx.x * 256 + threadIdx.x;
  int lane = threadIdx.x & 63, w = threadIdx.x >> 6;
  int v = (i < N_NODES) ? deg[i] : 0;
  int sv = v;
  #pragma unroll
  for (int o = 1; o < 64; o <<= 1) {
    int u = __shfl_up(sv, o, 64);
    if (lane >= o) sv += u;
  }
  __shared__ int ws_[4], wp_[4];
  if (lane == 63) ws_[w] = sv;
  __syncthreads();
  if (threadIdx.x == 0) {
    int s = 0;
    #pragma unroll
    for (int j = 0; j < 4; ++j) { wp_[j] = s; s += ws_[j]; }
  }
  __syncthreads();
  if (i < N_NODES) off[i + 1] = bpre[blockIdx.x] + wp_[w] + sv;
  if (i == 0) off[0] = 0;
}

__global__ void scatter_kernel(const int* __restrict__ dst, const int* __restrict__ off,
                               int* __restrict__ cur, int* __restrict__ eperm) {
  int i = blockIdx.x * 256 + threadIdx.x;
  if (i < N_EDGES) {
    int dn = dst[i];
    int pos = atomicAdd(&cur[dn], 1);
    eperm[off[dn] + pos] = i;
  }
}

// -------- weight prep: bf16 transposed weights; h -> bf16 rows --------
// WpreT[224][64]: rows 0-111 = S-half [Wcfin_top | Wew_top | Wsem_top | 0],
//                 rows 112-223 = D-half.
__global__ void prep_kernel(const float* __restrict__ Wcfin, const float* __restrict__ Wcff,
                            const float* __restrict__ Wew, const float* __restrict__ Wsem,
                            const float* __restrict__ Wc1,
                            const float* __restrict__ Wpn1, const float* __restrict__ Wpn2,
                            const float* __restrict__ Wn1, const float* __restrict__ Wn2,
                            const float* __restrict__ h,
                            short* __restrict__ WpreT, short* __restrict__ WcffT,
                            short* __restrict__ WewBT, short* __restrict__ Wc1T,
                            short* __restrict__ Wpn1T, short* __restrict__ Wpn2T,
                            short* __restrict__ Wn1T, short* __restrict__ Wn2T,
                            short* __restrict__ h_bf) {
  int t = blockIdx.x * 256 + threadIdx.x;
  int stride = gridDim.x * 256;
  for (int i = t; i < 224 * 64; i += stride) {
    int n = i >> 6, k = i & 63;
    int half = (n >= 112) ? 1 : 0;
    int c = n - half * 112;
    float v = 0.f;
    if (c < 64)       v = Wcfin[(half * 64 + k) * 64 + c];
    else if (c < 96)  v = Wew[(half * 64 + k) * 32 + (c - 64)];
    else if (c == 96) v = Wsem[half * 64 + k];
    WpreT[i] = (short)f2bf(v);
  }
  for (int i = t; i < 64 * 64; i += stride) {
    int n = i >> 6, k = i & 63;
    WcffT[i] = (k < 50) ? (short)f2bf(Wcff[k * 64 + n]) : (short)0;
  }
  for (int i = t; i < 32 * 64; i += stride) {
    int n = i >> 6, k = i & 63;
    WewBT[i] = (short)f2bf(Wew[(128 + k) * 32 + n]);
  }
  for (int i = t; i < 64 * 64; i += stride) {
    int n = i >> 6, k = i & 63;
    Wc1T[i] = (short)f2bf(Wc1[k * 64 + n]);
  }
  for (int i = t; i < 64 * 32; i += stride) {
    int n = i >> 5, k = i & 31;
    Wpn1T[i] = (short)f2bf(Wpn1[k * 64 + n]);
  }
  for (int i = t; i < 64 * 64; i += stride) {
    int n = i >> 6, k = i & 63;
    Wpn2T[i] = (short)f2bf(Wpn2[k * 64 + n]);
  }
  for (int i = t; i < 64 * 192; i += stride) {
    int n = i / 192, k = i - n * 192;
    Wn1T[i] = (short)f2bf(Wn1[k * 64 + n]);
  }
  for (int i = t; i < 64 * 64; i += stride) {
    int n = i >> 6, k = i & 63;
    Wn2T[i] = (short)f2bf(Wn2[k * 64 + n]);
  }
  for (int i = t; i < (N_NODES * 64) / 4; i += stride) {
    float4 v = reinterpret_cast<const float4*>(h)[i];
    ushort4 u;
    u.x = f2bf(v.x); u.y = f2bf(v.y); u.z = f2bf(v.z); u.w = f2bf(v.w);
    reinterpret_cast<ushort4*>(h_bf)[i] = u;
  }
}

// ---- per-node precompute: pre{S,D}[n][96] = h[n] @ [lin(64)|ew(32)]; sem -> f32 ----
__global__ __launch_bounds__(256) void pre_node_kernel(
    const short* __restrict__ h_bf, const short* __restrict__ WpreT,
    short* __restrict__ preS, short* __restrict__ preD,
    float* __restrict__ semS, float* __restrict__ semD)
{
  __shared__ short hs[64][72];
  const int t = threadIdx.x;
  const int w = t >> 6, lane = t & 63;
  const int n0 = blockIdx.x * 64;
  const int rbase = w * 16;

  #pragma unroll
  for (int u = 0; u < 2; ++u) {
    int c = lane + u * 64;            // 0..127
    int riw = c >> 3, col8 = (c & 7) * 8;
    int node = n0 + rbase + riw; if (node >= N_NODES) node = N_NODES - 1;
    *reinterpret_cast<s16x8*>(&hs[rbase + riw][col8]) =
        *reinterpret_cast<const s16x8*>(&h_bf[(size_t)node * 64 + col8]);
  }

  const int lr = lane & 15, lg = lane >> 4;
  const int arow = rbase + lr;
  const int k8 = lg * 8;
  const f32x4 z = {0.f, 0.f, 0.f, 0.f};

  #pragma unroll
  for (int half = 0; half < 2; ++half) {
    short* out = half ? preD : preS;
    float* osem = half ? semD : semS;
    #pragma unroll
    for (int j = 0; j < 7; ++j) {
      f32x4 acc = z;
      #pragma unroll
      for (int kb = 0; kb < 64; kb += 32) {
        s16x8 a = *reinterpret_cast<const s16x8*>(&hs[arow][kb + k8]);
        s16x8 b = *reinterpret_cast<const s16x8*>(&WpreT[(half * 112 + j * 16 + lr) * 64 + kb + k8]);
        acc = __builtin_amdgcn_mfma_f32_16x16x32_bf16(a, b, acc, 0, 0, 0);
      }
      #pragma unroll
      for (int r = 0; r < 4; ++r) {
        int node = n0 + rbase + lg * 4 + r;
        if (node < N_NODES) {
          if (j < 6) out[(size_t)node * 96 + j * 16 + lr] = (short)f2bf(acc[r]);
          else if (lr == 0) osem[node] = acc[r];   // col 96
        }
      }
    }
  }
}

// ---- tot_kernel: per-node triple softmax -> fully-normalized weight tot[p] ----
__global__ __launch_bounds__(256) void tot_kernel(
    const int* __restrict__ off, const int* __restrict__ eperm,
    const int* __restrict__ src, const float* __restrict__ x,
    const float* __restrict__ semS, const float* __restrict__ semD,
    float* __restrict__ tot_un, float* __restrict__ tot_arr)
{
  __shared__ float tot_s[4][MAX_DEG];
  int w = threadIdx.x >> 6, lane = threadIdx.x & 63;
  int n = blockIdx.x * 4 + w;
  if (n >= N_NODES) return;
  int b = off[n], e = off[n + 1];
  const bool fits = (e - b) <= MAX_DEG;
  float xn0 = x[n * 3 + 0], xn1 = x[n * 3 + 1], xn2 = x[n * 3 + 2];
  float sdn = semD[n];

  float s1 = 0.f, s2 = 0.f;
  for (int p = b + lane; p < e; p += 64) {
    int sn = src[eperm[p]];
    float m0 = x[sn * 3 + 0] - xn0;
    float m1 = x[sn * 3 + 1] - xn1;
    float m2 = x[sn * 3 + 2] - xn2;
    float d = sqrtf(m0 * m0 + m1 * m1 + m2 * m2 + 1e-5f);
    float e1 = __expf(-d);
    float e2 = __expf(silu_f(semS[sn] + sdn));
    s1 += e1; s2 += e2;
    float pr = e1 * e2;
    if (fits) tot_s[w][p - b] = pr; else tot_un[p] = pr;
  }
  #pragma unroll
  for (int o = 32; o > 0; o >>= 1) { s1 += __shfl_xor(s1, o, 64); s2 += __shfl_xor(s2, o, 64); }
  float r12 = (1.f / s1) * (1.f / s2);

  float s3 = 0.f;
  for (int p = b + lane; p < e; p += 64) {
    float pr = fits ? tot_s[w][p - b] : tot_un[p];
    float ex = __expf(pr * r12);
    s3 += ex;
    if (fits) tot_s[w][p - b] = ex; else tot_un[p] = ex;
  }
  #pragma unroll
  for (int o = 32; o > 0; o >>= 1) s3 += __shfl_xor(s3, o, 64);
  float inv3 = 1.f / s3;

  for (int p = b + lane; p < e; p += 64)
    tot_arr[p] = (fits ? tot_s[w][p - b] : tot_un[p]) * inv3;
}

// ------- fused MFMA edge kernel: computes h_e/how/coef in LDS and segment-
// accumulates h_agg, x_att, x_new via f32 atomics (edges CSR-sorted by dst). -------
__global__ __launch_bounds__(256, 6) void edge_kernel(
    const float* __restrict__ x,
    const int* __restrict__ src, const int* __restrict__ dst,
    const int* __restrict__ eperm, const float* __restrict__ tot_arr,
    const short* __restrict__ preS, const short* __restrict__ preD,
    const float* __restrict__ b_cf_in,
    const short* __restrict__ WcffT, const float* __restrict__ b_cf_f,
    const short* __restrict__ WewBT, const float* __restrict__ b_ew,
    const short* __restrict__ Wc1T, const float* __restrict__ b_c1,
    const float* __restrict__ W_c2, const float* __restrict__ b_c2,
    float* __restrict__ hagg, float* __restrict__ xatt,
    float* __restrict__ x_out)
{
  __shared__ short hlin[64][72];   // lin sums -> h_e in place
  __shared__ short rbf_s[64][72];  // rbf
  __shared__ short ewsum[64][40];  // ew sums -> how in place
  __shared__ float coef_s[64];
  __shared__ float s_mx0[64], s_mx1[64], s_mx2[64], s_id2[64], s_tot[64];
  __shared__ int s_dn[64];

  const int t = threadIdx.x;
  const int p0 = blockIdx.x * 64;
  const int le = t >> 2, q = t & 3;   // 4 threads per edge
  const int p_edge = p0 + le;

  const int e = eperm[p_edge];
  const int sn = src[e], dn = dst[e];

  // ---- geometry + meta ----
  float mx0 = x[sn * 3 + 0] - x[dn * 3 + 0];
  float mx1 = x[sn * 3 + 1] - x[dn * 3 + 1];
  float mx2 = x[sn * 3 + 2] - x[dn * 3 + 2];
  float d2 = mx0 * mx0 + mx1 * mx1 + mx2 * mx2 + 1e-5f;
  float d = sqrtf(d2);
  if (q == 0) {
    s_mx0[le] = mx0; s_mx1[le] = mx1; s_mx2[le] = mx2;
    s_id2[le] = 1.0f / d2;
    s_dn[le] = dn;
    s_tot[le] = tot_arr[p_edge];
  }

  // ---- gather preS[src]+preD[dst]: chunks 0-7 -> hlin, 8-11 -> ewsum ----
  {
    const short* ps = preS + (size_t)sn * 96;
    const short* pd = preD + (size_t)dn * 96;
    #pragma unroll
    for (int ci = 0; ci < 3; ++ci) {
      int c = q * 3 + ci;               // 0..11
      s16x8 a = *reinterpret_cast<const s16x8*>(ps + c * 8);
      s16x8 b = *reinterpret_cast<const s16x8*>(pd + c * 8);
      s16x8 r;
      #pragma unroll
      for (int u = 0; u < 8; ++u) r[u] = (short)f2bf(bf2f(a[u]) + bf2f(b[u]));
      short* dstp = (c < 8) ? &hlin[le][c * 8] : &ewsum[le][(c - 8) * 8];
      *reinterpret_cast<s16x8*>(dstp) = r;
    }
  }

  // ---- RBF (bf16): q covers k = q*16 .. q*16+15 ----
  {
    int kb = q * 16;
    s16x8 lo, hi;
    #pragma unroll 16
    for (int u = 0; u < 16; ++u) {
      int k = kb + u;
      float mu = (float)k * (5.0f / 49.0f);
      float dd = d - mu;
      float val = (k < 50) ? __expf(-10.0f * dd * dd) : 0.0f;
      short sv = (short)f2bf(val);
      if (u < 8) lo[u] = sv; else hi[u - 8] = sv;
    }
    *reinterpret_cast<s16x8*>(&rbf_s[le][kb]) = lo;
    *reinterpret_cast<s16x8*>(&rbf_s[le][kb + 8]) = hi;
  }
  // no __syncthreads: all LDS producer/consumer pairs are wave-local

  const int w = t >> 6, lane = t & 63;
  const int lr = lane & 15, lg = lane >> 4;
  const int arow = w * 16 + lr;
  const int k8 = lg * 8;
  const f32x4 z = {0.f, 0.f, 0.f, 0.f};

  // ---- cf_f: filt = rbf @ W_cf_f (8 MFMAs) ----
  f32x4 fac[4] = {z, z, z, z};
  #pragma unroll
  for (int kb = 0; kb < 64; kb += 32) {
    s16x8 a = *reinterpret_cast<const s16x8*>(&rbf_s[arow][kb + k8]);
    #pragma unroll
    for (int j = 0; j < 4; ++j) {
      s16x8 b = *reinterpret_cast<const s16x8*>(&WcffT[(j * 16 + lr) * 64 + kb + k8]);
      fac[j] = __builtin_amdgcn_mfma_f32_16x16x32_bf16(a, b, fac[j], 0, 0, 0);
    }
  }

  // ---- h_e = (lin + b) * silu(filt + b), in place ----
  #pragma unroll
  for (int j = 0; j < 4; ++j) {
    int col = j * 16 + lr;
    float bi = b_cf_in[col], bf_ = b_cf_f[col];
    #pragma unroll
    for (int r = 0; r < 4; ++r) {
      int row = w * 16 + lg * 4 + r;
      float lin = bf2f(hlin[row][col]);
      float he = (lin + bi) * silu_f(fac[j][r] + bf_);
      hlin[row][col] = (short)f2bf(he);
    }
  }

  // ---- ew: C-init from gathered sums, + h_e @ W_ew_bot, tanh -> ewsum ----
  {
    f32x4 ew[2];
    #pragma unroll
    for (int j = 0; j < 2; ++j) {
      #pragma unroll
      for (int r = 0; r < 4; ++r)
        ew[j][r] = bf2f(ewsum[w * 16 + lg * 4 + r][j * 16 + lr]);
    }
    #pragma unroll
    for (int kb = 0; kb < 64; kb += 32) {
      s16x8 a = *reinterpret_cast<const s16x8*>(&hlin[arow][kb + k8]);
      #pragma unroll
      for (int j = 0; j < 2; ++j) {
        s16x8 b = *reinterpret_cast<const s16x8*>(&WewBT[(j * 16 + lr) * 64 + kb + k8]);
        ew[j] = __builtin_amdgcn_mfma_f32_16x16x32_bf16(a, b, ew[j], 0, 0, 0);
      }
    }
    #pragma unroll
    for (int j = 0; j < 2; ++j) {
      int col = j * 16 + lr;
      float be = b_ew[col];
      #pragma unroll
      for (int r = 0; r < 4; ++r)
        ewsum[w * 16 + lg * 4 + r][col] = (short)f2bf(tanh_f(ew[j][r] + be));
    }
  }

  // ---- coef: silu(h_e @ W_c1 + b) @ W_c2 + b -> coef_s (LDS) ----
  {
    f32x4 c[4] = {z, z, z, z};
    #pragma unroll
    for (int kb = 0; kb < 64; kb += 32) {
      s16x8 a = *reinterpret_cast<const s16x8*>(&hlin[arow][kb + k8]);
      #pragma unroll
      for (int j = 0; j < 4; ++j) {
        s16x8 b = *reinterpret_cast<const s16x8*>(&Wc1T[(j * 16 + lr) * 64 + kb + k8]);
        c[j] = __builtin_amdgcn_mfma_f32_16x16x32_bf16(a, b, c[j], 0, 0, 0);
      }
    }
    float p[4] = {0.f, 0.f, 0.f, 0.f};
    #pragma unroll
    for (int j = 0; j < 4; ++j) {
      int col = j * 16 + lr;
      float bc = b_c1[col], wc = W_c2[col];
      #pragma unroll
      for (int r = 0; r < 4; ++r) p[r] += silu_f(c[j][r] + bc) * wc;
    }
    #pragma unroll
    for (int r = 0; r < 4; ++r) {
      p[r] += __shfl_xor(p[r], 1, 64);
      p[r] += __shfl_xor(p[r], 2, 64);
      p[r] += __shfl_xor(p[r], 4, 64);
      p[r] += __shfl_xor(p[r], 8, 64);
    }
    if (lr == 0) {
      float bc2 = b_c2[0];
      #pragma unroll
      for (int r = 0; r < 4; ++r)
        coef_s[w * 16 + lg * 4 + r] = p[r] + bc2;
    }
  }

  // ---- segment reduction over this wave's 16 edges (dst-sorted) ----
  {
    const int c31 = lane & 31;
    const bool hi = lane >= 32;
    float acc_h = 0.f, acc_a = 0.f, acc_b = 0.f, acc_x = 0.f;
    int nid_prev = s_dn[w * 16];
    #pragma unroll
    for (int r = 0; r < 16; ++r) {
      int row = w * 16 + r;
      int nid = s_dn[row];
      if (nid != nid_prev) {
        atomAdd(&hagg[(size_t)nid_prev * 64 + lane], acc_h);
        atomAdd(&xatt[(size_t)nid_prev * 96 + (hi ? 32 : 0) + c31], acc_a);
        if (!hi) atomAdd(&xatt[(size_t)nid_prev * 96 + 64 + lane], acc_b);
        if (lane < 3) atomAdd(&x_out[nid_prev * 3 + lane], acc_x);
        acc_h = acc_a = acc_b = acc_x = 0.f;
        nid_prev = nid;
      }
      float tot = s_tot[row];
      acc_h += tot * bf2f(hlin[row][lane]);
      float id2 = s_id2[row];
      float m0 = s_mx0[row], m1 = s_mx1[row], m2 = s_mx2[row];
      float hw = bf2f(ewsum[row][c31]) * id2;
      acc_a += hw * (hi ? m1 : m0);
      if (!hi) acc_b += hw * m2;
      if (lane < 3) {
        float cf = coef_s[row];
        acc_x += cf * (lane == 0 ? m0 : (lane == 1 ? m1 : m2));
      }
    }
    atomAdd(&hagg[(size_t)nid_prev * 64 + lane], acc_h);
    atomAdd(&xatt[(size_t)nid_prev * 96 + (hi ? 32 : 0) + c31], acc_a);
    if (!hi) atomAdd(&xatt[(size_t)nid_prev * 96 + 64 + lane], acc_b);
    if (lane < 3) atomAdd(&x_out[nid_prev * 3 + lane], acc_x);
  }
}

// ---------- MFMA node MLP: 64 nodes / block, 4 waves, wave-local ----------
__global__ __launch_bounds__(256) void node_mlp_kernel(
    const short* __restrict__ h_bf, const float* __restrict__ hagg,
    const float* __restrict__ xatt,
    const short* __restrict__ Wpn1T, const float* __restrict__ b_pn1,
    const short* __restrict__ Wpn2T, const float* __restrict__ b_pn2,
    const short* __restrict__ Wn1T, const float* __restrict__ b_n1,
    const short* __restrict__ Wn2T, const float* __restrict__ b_n2,
    float* __restrict__ h_out)
{
  __shared__ short cat[64][200];   // [h | hagg | emb], +8 pad
  __shared__ short tbuf[64][72];   // nrm(cols 0..31) -> t1 -> t2 (wave-local alias)

  const int t = threadIdx.x;
  const int w = t >> 6, lane = t & 63;
  const int n0 = blockIdx.x * 64;
  const int rbase = w * 16;

  #pragma unroll
  for (int u = 0; u < 2; ++u) {
    int c = lane + u * 64;            // 0..127 -> 16 rows x 8 chunks
    int riw = c >> 3, col8 = (c & 7) * 8;
    int node = n0 + rbase + riw; if (node >= N_NODES) node = N_NODES - 1;
    *reinterpret_cast<s16x8*>(&cat[rbase + riw][col8]) =
        *reinterpret_cast<const s16x8*>(&h_bf[(size_t)node * 64 + col8]);
    float4 v0 = *reinterpret_cast<const float4*>(&hagg[(size_t)node * 64 + col8]);
    float4 v1 = *reinterpret_cast<const float4*>(&hagg[(size_t)node * 64 + col8 + 4]);
    s16x8 pk;
    pk[0] = (short)f2bf(v0.x); pk[1] = (short)f2bf(v0.y);
    pk[2] = (short)f2bf(v0.z); pk[3] = (short)f2bf(v0.w);
    pk[4] = (short)f2bf(v1.x); pk[5] = (short)f2bf(v1.y);
    pk[6] = (short)f2bf(v1.z); pk[7] = (short)f2bf(v1.w);
    *reinterpret_cast<s16x8*>(&cat[rbase + riw][64 + col8]) = pk;
  }
  {
    int riw = lane >> 2, col8 = (lane & 3) * 8;
    int node = n0 + rbase + riw; if (node >= N_NODES) node = N_NODES - 1;
    const float* xa = xatt + (size_t)node * 96;
    #pragma unroll
    for (int cc = 0; cc < 8; ++cc) {
      int c = col8 + cc;
      float a0 = xa[c], a1 = xa[32 + c], a2 = xa[64 + c];
      float nr = sqrtf(fmaxf(a0 * a0 + a1 * a1 + a2 * a2, 0.f) + 1e-5f);
      tbuf[rbase + riw][c] = (short)f2bf(nr);
    }
  }

  const int lr = lane & 15, lg = lane >> 4;
  const int arow = rbase + lr;
  const int k8 = lg * 8;
  const f32x4 z = {0.f, 0.f, 0.f, 0.f};

  // GEMM1: t1 = silu(nrm @ W_pn1 + b), K=32
  {
    f32x4 c1[4] = {z, z, z, z};
    s16x8 a = *reinterpret_cast<const s16x8*>(&tbuf[arow][k8]);
    #pragma unroll
    for (int j = 0; j < 4; ++j) {
      s16x8 b = *reinterpret_cast<const s16x8*>(&Wpn1T[(j * 16 + lr) * 32 + k8]);
      c1[j] = __builtin_amdgcn_mfma_f32_16x16x32_bf16(a, b, c1[j], 0, 0, 0);
    }
    #pragma unroll
    for (int j = 0; j < 4; ++j) {
      int col = j * 16 + lr; float bb = b_pn1[col];
      #pragma unroll
      for (int r = 0; r < 4; ++r)
        tbuf[rbase + lg * 4 + r][col] = (short)f2bf(silu_f(c1[j][r] + bb));
    }
  }
  // GEMM2: emb = t1 @ W_pn2 + b, K=64 -> cat cols 128..191
  {
    f32x4 c2[4] = {z, z, z, z};
    #pragma unroll
    for (int kb = 0; kb < 64; kb += 32) {
      s16x8 a = *reinterpret_cast<const s16x8*>(&tbuf[arow][kb + k8]);
      #pragma unroll
      for (int j = 0; j < 4; ++j) {
        s16x8 b = *reinterpret_cast<const s16x8*>(&Wpn2T[(j * 16 + lr) * 64 + kb + k8]);
        c2[j] = __builtin_amdgcn_mfma_f32_16x16x32_bf16(a, b, c2[j], 0, 0, 0);
      }
    }
    #pragma unroll
    for (int j = 0; j < 4; ++j) {
      int col = j * 16 + lr; float bb = b_pn2[col];
      #pragma unroll
      for (int r = 0; r < 4; ++r)
        cat[rbase + lg * 4 + r][128 + col] = (short)f2bf(c2[j][r] + bb);
    }
  }
  // GEMM3: t2 = silu([h|hagg|emb] @ W_n1 + b), K=192
  {
    f32x4 c3[4] = {z, z, z, z};
    #pragma unroll
    for (int kb = 0; kb < 192; kb += 32) {
      s16x8 a = *reinterpret_cast<const s16x8*>(&cat[arow][kb + k8]);
      #pragma unroll
      for (int j = 0; j < 4; ++j) {
        s16x8 b = *reinterpret_cast<const s16x8*>(&Wn1T[(j * 16 + lr) * 192 + kb + k8]);
        c3[j] = __builtin_amdgcn_mfma_f32_16x16x32_bf16(a, b, c3[j], 0, 0, 0);
      }
    }
    #pragma unroll
    for (int j = 0; j < 4; ++j) {
      int col = j * 16 + lr; float bb = b_n1[col];
      #pragma unroll
      for (int r = 0; r < 4; ++r)
        tbuf[rbase + lg * 4 + r][col] = (short)f2bf(silu_f(c3[j][r] + bb));
    }
  }
  // GEMM4: h_out = t2 @ W_n2 + b, K=64, f32 store
  {
    f32x4 c4[4] = {z, z, z, z};
    #pragma unroll
    for (int kb = 0; kb < 64; kb += 32) {
      s16x8 a = *reinterpret_cast<const s16x8*>(&tbuf[arow][kb + k8]);
      #pragma unroll
      for (int j = 0; j < 4; ++j) {
        s16x8 b = *reinterpret_cast<const s16x8*>(&Wn2T[(j * 16 + lr) * 64 + kb + k8]);
        c4[j] = __builtin_amdgcn_mfma_f32_16x16x32_bf16(a, b, c4[j], 0, 0, 0);
      }
    }
    #pragma unroll
    for (int j = 0; j < 4; ++j) {
      int col = j * 16 + lr; float bb = b_n2[col];
      #pragma unroll
      for (int r = 0; r < 4; ++r) {
        int node = n0 + rbase + lg * 4 + r;
        if (node < N_NODES) h_out[(size_t)node * 64 + col] = c4[j][r] + bb;
      }
    }
  }
}

// ---------------- launch ----------------
extern "C" void kernel_launch(void* const* d_in, const int* in_sizes, int n_in,
                              void* d_out, int out_size, void* d_ws, size_t ws_size,
                              hipStream_t stream) {
  const float* h      = (const float*)d_in[0];
  const float* x      = (const float*)d_in[1];
  const int*   src    = (const int*)d_in[2];
  const int*   dst    = (const int*)d_in[3];
  const float* W_cf_in = (const float*)d_in[4];
  const float* b_cf_in = (const float*)d_in[5];
  const float* W_cf_f  = (const float*)d_in[6];
  const float* b_cf_f  = (const float*)d_in[7];
  const float* W_sem   = (const float*)d_in[8];
  const float* W_ew    = (const float*)d_in[9];
  const float* b_ew    = (const float*)d_in[10];
  const float* W_pn1   = (const float*)d_in[11];
  const float* b_pn1   = (const float*)d_in[12];
  const float* W_pn2   = (const float*)d_in[13];
  const float* b_pn2   = (const float*)d_in[14];
  const float* W_n1    = (const float*)d_in[15];
  const float* b_n1    = (const float*)d_in[16];
  const float* W_n2    = (const float*)d_in[17];
  const float* b_n2    = (const float*)d_in[18];
  const float* W_c1    = (const float*)d_in[19];
  const float* b_c1    = (const float*)d_in[20];
  const float* W_c2    = (const float*)d_in[21];
  const float* b_c2    = (const float*)d_in[22];

  char* ws = (char*)d_ws;
  size_t o = 0;
  auto take = [&](size_t bytes) {
    void* p = ws + o;
    o = (o + bytes + 255) & ~(size_t)255;
    return p;
  };
  int* deg    = (int*)take((size_t)N_NODES * 4);
  int* off    = (int*)take((size_t)(N_NODES + 1) * 4);
  int* cur    = (int*)take((size_t)N_NODES * 4);
  int* eperm  = (int*)take((size_t)N_EDGES * 4);
  int* bsum   = (int*)take((size_t)SCAN_B * 4);
  int* bpre   = (int*)take((size_t)SCAN_B * 4);
  float* tot_un  = (float*)take((size_t)N_EDGES * 4);
  float* tot_arr = (float*)take((size_t)N_EDGES * 4);
  float* hagg = (float*)take((size_t)N_NODES * 64 * 4);
  float* xatt = (float*)take((size_t)N_NODES * 96 * 4);
  float* semS = (float*)take((size_t)N_NODES * 4);
  float* semD = (float*)take((size_t)N_NODES * 4);
  short* WpreT  = (short*)take((size_t)224 * 64 * 2);
  short* WcffT  = (short*)take((size_t)64 * 64 * 2);
  short* WewBT  = (short*)take((size_t)32 * 64 * 2);
  short* Wc1T   = (short*)take((size_t)64 * 64 * 2);
  short* Wpn1T  = (short*)take((size_t)64 * 32 * 2);
  short* Wpn2T  = (short*)take((size_t)64 * 64 * 2);
  short* Wn1T   = (short*)take((size_t)64 * 192 * 2);
  short* Wn2T   = (short*)take((size_t)64 * 64 * 2);
  short* h_bf   = (short*)take((size_t)N_NODES * 64 * 2);
  short* preS   = (short*)take((size_t)N_NODES * 96 * 2);
  short* preD   = (short*)take((size_t)N_NODES * 96 * 2);

  float* h_out = (float*)d_out;
  float* x_out = h_out + (size_t)N_NODES * 64;

  hipMemsetAsync(deg, 0, (size_t)N_NODES * 4, stream);
  hipMemsetAsync(cur, 0, (size_t)N_NODES * 4, stream);
  hipMemsetAsync(hagg, 0, (size_t)N_NODES * 64 * 4, stream);
  hipMemsetAsync(xatt, 0, (size_t)N_NODES * 96 * 4, stream);
  hipMemcpyAsync(x_out, x, (size_t)N_NODES * 3 * 4, hipMemcpyDeviceToDevice, stream);

  hist_kernel<<<N_EDGES / 256, 256, 0, stream>>>(dst, deg);
  scanA_kernel<<<SCAN_B, 256, 0, stream>>>(deg, bsum);
  scanB_kernel<<<1, 64, 0, stream>>>(bsum, bpre);
  scanC_kernel<<<SCAN_B, 256, 0, stream>>>(deg, bpre, off);
  scatter_kernel<<<N_EDGES / 256, 256, 0, stream>>>(dst, off, cur, eperm);
  prep_kernel<<<128, 256, 0, stream>>>(W_cf_in, W_cf_f, W_ew, W_sem, W_c1,
                                       W_pn1, W_pn2, W_n1, W_n2, h,
                                       WpreT, WcffT, WewBT, Wc1T,
                                       Wpn1T, Wpn2T, Wn1T, Wn2T, h_bf);
  pre_node_kernel<<<(N_NODES + 63) / 64, 256, 0, stream>>>(h_bf, WpreT, preS, preD,
                                                           semS, semD);
  tot_kernel<<<N_NODES / 4, 256, 0, stream>>>(off, eperm, src, x, semS, semD,
                                              tot_un, tot_arr);

  edge_kernel<<<N_EDGES / 64, 256, 0, stream>>>(
      x, src, dst, eperm, tot_arr, preS, preD,
      b_cf_in, WcffT, b_cf_f,
      WewBT, b_ew, Wc1T, b_c1, W_c2, b_c2,
      hagg, xatt, x_out);

  node_mlp_kernel<<<(N_NODES + 63) / 64, 256, 0, stream>>>(
      h_bf, hagg, xatt,
      Wpn1T, b_pn1, Wpn2T, b_pn2,
      Wn1T, b_n1, Wn2T, b_n2,
      h_out);
}